// Round 4
// baseline (596.757 us; speedup 1.0000x reference)
//
#include <hip/hip_runtime.h>
#include <stdint.h>
#include <math.h>

#define BB 4
#define NNODE 2048
#define NE 32768
#define DDIM 128
#define NL 3
#define NRELS 1000
#define MASKV -1000000000.0f

typedef unsigned short ushort_t;
typedef __attribute__((ext_vector_type(8))) short bfrag;   // 8 bf16 (4 VGPR)
typedef __attribute__((ext_vector_type(4))) float f4;

__device__ __forceinline__ float sigf(float x){ return 1.0f/(1.0f+expf(-x)); }

__device__ __forceinline__ float bf2f(ushort_t u){
  union { unsigned int i; float f; } v; v.i = ((unsigned int)u) << 16; return v.f;
}
__device__ __forceinline__ ushort_t f2bf(float x){
  union { float f; unsigned int u; } v; v.f = x;
  unsigned int r = (v.u + 0x7FFFu + ((v.u >> 16) & 1u)) >> 16;  // RNE
  return (ushort_t)r;
}
__device__ __forceinline__ float bflo(unsigned u){
  union{unsigned i;float f;}v; v.i=u<<16; return v.f;
}
__device__ __forceinline__ float bfhi(unsigned u){
  union{unsigned i;float f;}v; v.i=u&0xFFFF0000u; return v.f;
}
__device__ __forceinline__ unsigned pmul_bf(unsigned a, unsigned b){
  return (unsigned)f2bf(bflo(a)*bflo(b)) | ((unsigned)f2bf(bfhi(a)*bfhi(b))<<16);
}

// ------------------------------------------------------- mask dtype handling
__global__ void probe_mask_kernel(const void* cm_raw, int* flag){
  int t = threadIdx.x;                       // 64 threads
  const int* ip = (const int*)cm_raw;
  unsigned v = (unsigned)ip[t];
  bool i32ok = (v <= 1u);
  bool f32ok = (v == 0u) || (v == 0x3F800000u);
  unsigned long long bi = __ballot(i32ok);
  unsigned long long bf_ = __ballot(f32ok);
  if (t == 0){
    int f;
    if (bi == ~0ULL) f = 0;
    else if (bf_ == ~0ULL) f = 1;
    else f = 2;
    *flag = f;
  }
}

__global__ void decode_masks_kernel(const void* cm_raw, const void* em_raw,
                                    const int* flag,
                                    uint8_t* __restrict__ cm, uint8_t* __restrict__ em){
  int i = blockIdx.x*256 + threadIdx.x;      // B*E threads
  int f = *flag;
  uint8_t c, e;
  if (f == 0){
    c = ((const int*)cm_raw)[i] != 0;  e = ((const int*)em_raw)[i] != 0;
  } else if (f == 1){
    c = ((const float*)cm_raw)[i] != 0.0f;  e = ((const float*)em_raw)[i] != 0.0f;
  } else {
    c = ((const uint8_t*)cm_raw)[i] != 0;  e = ((const uint8_t*)em_raw)[i] != 0;
  }
  cm[i] = c; em[i] = e;
}

// ---------------------------------------------------------------- converts
__global__ void conv_bf16_kernel(const float* __restrict__ src,
                                 ushort_t* __restrict__ dst, int n4){
  int gid = blockIdx.x*256 + threadIdx.x;
  if (gid >= n4) return;
  float4 v = *(const float4*)&src[(size_t)gid*4];
  ushort4 o;
  o.x=f2bf(v.x); o.y=f2bf(v.y); o.z=f2bf(v.z); o.w=f2bf(v.w);
  *(ushort4*)&dst[(size_t)gid*4] = o;
}

// Weight LDS-images: transposed, bf16, chunk-contiguous, XOR-swizzled.
__global__ void build_wimg_kernel(const float* __restrict__ msgW,
                                  const float* __restrict__ denW1,
                                  ushort_t* __restrict__ img_msg,
                                  ushort_t* __restrict__ img_den){
  int e = blockIdx.x*256 + threadIdx.x;      // 36*8192 = 294912 threads
  int img_id = e >> 13;
  int ei = e & 8191;
  int j = ei >> 6;
  int kkb = ((ei & 63) << 1) ^ ((j & 7) << 4);
  int kk = kkb >> 1;
  if (img_id < 30){
    int layer = img_id / 10, ch = img_id % 10;
    float v = msgW[((size_t)layer*640 + ch*64 + kk)*128 + j];
    img_msg[(size_t)img_id*8192 + ei] = f2bf(v);
  } else {
    int ch = img_id - 30;
    float v = denW1[((size_t)ch*64 + kk)*128 + j];
    img_den[(size_t)ch*8192 + ei] = f2bf(v);
  }
}

// ---------------------------------------------------------------- init
__global__ void init_h_kernel(float* __restrict__ h, ushort_t* __restrict__ h_bf){
  int gid = blockIdx.x*256 + threadIdx.x;          // B*N*D threads
  int nd = gid & (NNODE*DDIM - 1);
  bool one = (nd < DDIM);
  h[gid] = one ? 1.0f : 0.0f;
  h_bf[gid] = one ? 0x3F80 : 0;
}

// ------------------------------------------------------------ CSR build
__global__ void csr_zero_kernel(int* __restrict__ deg){
  int gid = blockIdx.x*256 + threadIdx.x;          // BB*NNODE
  deg[gid] = 0;
}
__global__ void csr_hist_kernel(const int* __restrict__ edge_index, int* __restrict__ deg){
  int gid = blockIdx.x*256 + threadIdx.x;          // B*E
  int b = gid >> 15, e = gid & (NE-1);
  int tgt = edge_index[(b<<16) + NE + e];
  atomicAdd(&deg[(b<<11) + tgt], 1);
}
__global__ void csr_scan_kernel(const int* __restrict__ deg,
                                int* __restrict__ base, int* __restrict__ cursor){
  __shared__ int part[256];
  int t = threadIdx.x;                             // 256 threads, 1 block
  int loc[32]; int s = 0;
  #pragma unroll
  for (int i=0;i<32;++i){ loc[i] = deg[t*32+i]; s += loc[i]; }
  part[t] = s; __syncthreads();
  for (int off=1; off<256; off<<=1){
    int v = (t >= off) ? part[t-off] : 0;
    __syncthreads();
    part[t] += v;
    __syncthreads();
  }
  int ex = (t==0) ? 0 : part[t-1];
  #pragma unroll
  for (int i=0;i<32;++i){ base[t*32+i] = ex; cursor[t*32+i] = ex; ex += loc[i]; }
  if (t == 255) base[256*32] = ex;
}
__global__ void csr_scatter_kernel(const int* __restrict__ edge_index,
                                   int* __restrict__ cursor, int* __restrict__ eids){
  int gid = blockIdx.x*256 + threadIdx.x;          // B*E
  int b = gid >> 15, e = gid & (NE-1);
  int tgt = edge_index[(b<<16) + NE + e];
  int pos = atomicAdd(&cursor[(b<<11) + tgt], 1);
  eids[pos] = gid;
}

// ------------------------------------------------- per-rel / per-batch tables
__global__ void precomp_tables_kernel(
    const float* __restrict__ relt, const float* __restrict__ rq,
    const float* __restrict__ attW, const float* __restrict__ betaW,
    float* __restrict__ att_rel, float* __restrict__ att_rq,
    float* __restrict__ beta_rel, float* __restrict__ beta_rq)
{
  int wid = (blockIdx.x*256 + threadIdx.x) >> 6;
  int lane = threadIdx.x & 63;
  if (wid >= 3*NRELS + 3*BB + NRELS + BB) return;
  const float* vec; const float* w; float* dst; int di;
  if (wid < 3*NRELS){
    int k = wid/NRELS, rl = wid%NRELS;
    vec = relt + rl*DDIM; w = attW + k*384 + 128; dst = att_rel; di = wid;
  } else if (wid < 3*NRELS + 3*BB){
    int idx = wid - 3*NRELS; int k = idx/BB, b = idx%BB;
    vec = rq + b*DDIM; w = attW + k*384 + 256; dst = att_rq; di = idx;
  } else if (wid < 3*NRELS + 3*BB + NRELS){
    int rl = wid - (3*NRELS + 3*BB);
    vec = relt + rl*DDIM; w = betaW; dst = beta_rel; di = rl;
  } else {
    int b = wid - (3*NRELS + 3*BB + NRELS);
    vec = rq + b*DDIM; w = betaW; dst = beta_rq; di = b;
  }
  float s = vec[lane]*w[lane] + vec[lane+64]*w[lane+64];
  #pragma unroll
  for (int off=32; off; off>>=1) s += __shfl_xor(s, off, 64);
  if (lane == 0) dst[di] = s;
}

// ================================================= MFMA coef kernel (pipelined)
__global__ __launch_bounds__(256,2) void coef_mfma_kernel(
    const int* __restrict__ rels, const float* __restrict__ scores,
    const uint8_t* __restrict__ cm, const uint8_t* __restrict__ em,
    const ushort_t* __restrict__ relt_bf, const ushort_t* __restrict__ rq_bf,
    const ushort_t* __restrict__ conf_bf, const ushort_t* __restrict__ img_den,
    const float* __restrict__ denb1, const float* __restrict__ denW2,
    const float* __restrict__ denb2,
    const float* __restrict__ beta_rel, const float* __restrict__ beta_rq,
    const float* __restrict__ betab,
    float* __restrict__ coef)
{
  __shared__ char lds[32768];
  __shared__ float att_buf[2][128];
  __shared__ int rel_s[128];

  const int t = threadIdx.x;
  const int blk = blockIdx.x;               // 1024 blocks
  const int b = blk >> 8;
  const int e0 = (blk & 255) << 7;
  const int ge0 = b*NE + e0;
  if (t < 128) rel_s[t] = rels[ge0 + t];

  const int lane = t & 63, wid = t >> 6;
  const int wr = wid >> 1, wc = wid & 1;
  const int rbase = wr << 6, cbase = wc << 6;
  const int lr = lane & 15, lk = lane >> 4;
  const int swz = (lane & 7) << 4;
  const int g = t & 7;
  const int row0 = t >> 3;
  const int aswz = (g<<4) ^ ((row0&7)<<4);

  f4 acc[4][4];
  #pragma unroll
  for (int m=0;m<4;++m)
    #pragma unroll
    for (int n=0;n<4;++n)
      acc[m][n] = (f4){0.f,0.f,0.f,0.f};

  const uint4* imgp = (const uint4*)img_den;
  uint4 pa[4], pb[4];

  __syncthreads();   // rel_s ready

#define C_ISSUE(CH) { \
    const int region=(CH)>>1, d0=((CH)&1)<<6; \
    _Pragma("unroll") for (int i=0;i<4;++i){ \
      int row = row0 + (i<<5); \
      if (region==0)      pa[i]=*(const uint4*)&relt_bf[(((size_t)rel_s[row])<<7)+d0+(g<<3)]; \
      else if (region==1) pa[i]=*(const uint4*)&rq_bf[(b<<7)+d0+(g<<3)]; \
      else                pa[i]=*(const uint4*)&conf_bf[(((size_t)(ge0+row))<<7)+d0+(g<<3)]; } \
    _Pragma("unroll") for (int i=0;i<4;++i) pb[i]=imgp[(CH)*1024+(i<<8)+t]; }

  C_ISSUE(0);
  #pragma unroll
  for (int ch=0; ch<6; ++ch){
    #pragma unroll
    for (int i=0;i<4;++i){
      int row = row0 + (i<<5);
      *(uint4*)(lds + row*128 + aswz) = pa[i];
    }
    *(uint4*)(lds + 16384 + (t<<4))         = pb[0];
    *(uint4*)(lds + 16384 + (t<<4) + 4096)  = pb[1];
    *(uint4*)(lds + 16384 + (t<<4) + 8192)  = pb[2];
    *(uint4*)(lds + 16384 + (t<<4) + 12288) = pb[3];
    __syncthreads();
    if (ch < 5) C_ISSUE(ch+1);
    #pragma unroll
    for (int s=0;s<2;++s){
      bfrag af[4], bfr[4];
      #pragma unroll
      for (int m=0;m<4;++m)
        af[m] = *(const bfrag*)(lds + (rbase+(m<<4)+lr)*128 + (((s<<6)+(lk<<4)) ^ swz));
      #pragma unroll
      for (int n=0;n<4;++n)
        bfr[n] = *(const bfrag*)(lds + 16384 + (cbase+(n<<4)+lr)*128 + (((s<<6)+(lk<<4)) ^ swz));
      #pragma unroll
      for (int m=0;m<4;++m)
        #pragma unroll
        for (int n=0;n<4;++n)
          acc[m][n] = __builtin_amdgcn_mfma_f32_16x16x32_bf16(af[m], bfr[n], acc[m][n], 0,0,0);
    }
    __syncthreads();
  }
#undef C_ISSUE

  float b1v[4], w2[4];
  #pragma unroll
  for (int n=0;n<4;++n){
    int col = cbase + (n<<4) + lr;
    b1v[n] = denb1[col]; w2[n] = denW2[col];
  }
  float p[4][4];
  #pragma unroll
  for (int m=0;m<4;++m)
    #pragma unroll
    for (int q=0;q<4;++q) p[m][q] = 0.f;
  #pragma unroll
  for (int m=0;m<4;++m)
    #pragma unroll
    for (int n=0;n<4;++n)
      #pragma unroll
      for (int q=0;q<4;++q){
        float v = fmaxf(acc[m][n][q] + b1v[n], 0.f);
        p[m][q] = fmaf(v, w2[n], p[m][q]);
      }
  #pragma unroll
  for (int m=0;m<4;++m)
    #pragma unroll
    for (int q=0;q<4;++q){
      #pragma unroll
      for (int off=1; off<16; off<<=1) p[m][q] += __shfl_xor(p[m][q], off, 64);
    }
  if (lr == 0){
    #pragma unroll
    for (int m=0;m<4;++m)
      #pragma unroll
      for (int q=0;q<4;++q)
        att_buf[wc][rbase + (m<<4) + (lk<<2) + q] = p[m][q];
  }
  __syncthreads();
  if (t < 128){
    int ge = ge0 + t;
    float s = att_buf[0][t] + att_buf[1][t];
    float den = sigf(s + denb2[0]);
    float emv = em[ge] ? 1.0f : 0.0f;
    float beta = sigf(beta_rel[rel_s[t]] + beta_rq[b] + betab[0]);
    float gt = cm[ge] ? sigf((scores[ge]-beta)*10.0f) : 0.5f;
    coef[ge] = gt * den * emv;
  }
}

// ================================================= MFMA msg kernel (pipelined)
__global__ __launch_bounds__(256,2) void msg_mfma_kernel(
    const int* __restrict__ edge_index, const int* __restrict__ rels,
    const uint8_t* __restrict__ em,
    const ushort_t* __restrict__ relt_bf, const ushort_t* __restrict__ conf_bf,
    const ushort_t* __restrict__ h_bf, const ushort_t* __restrict__ img_msg,
    const float* __restrict__ msgb,
    const float* __restrict__ attW, const float* __restrict__ attb,
    const float* __restrict__ att_rel, const float* __restrict__ att_rq,
    ushort_t* __restrict__ raw, float* __restrict__ att, int layer)
{
  __shared__ char lds[32768];
  __shared__ float att_buf[2][128];
  __shared__ int src_s[128];
  __shared__ int rel_s[128];

  const int t = threadIdx.x;
  const int blk = blockIdx.x;               // 1024 blocks
  const int b = blk >> 8;
  const int e0 = (blk & 255) << 7;
  const int ge0 = b*NE + e0;
  if (t < 128) src_s[t] = edge_index[(b<<16) + e0 + t];
  else rel_s[t-128] = rels[ge0 + t - 128];

  const int lane = t & 63, wid = t >> 6;
  const int wr = wid >> 1, wc = wid & 1;
  const int rbase = wr << 6, cbase = wc << 6;
  const int lr = lane & 15, lk = lane >> 4;
  const int swz = (lane & 7) << 4;
  const int g = t & 7;
  const int row0 = t >> 3;
  const int aswz = (g<<4) ^ ((row0&7)<<4);

  f4 acc[4][4];
  #pragma unroll
  for (int m=0;m<4;++m)
    #pragma unroll
    for (int n=0;n<4;++n)
      acc[m][n] = (f4){0.f,0.f,0.f,0.f};

  const uint4* imgp = (const uint4*)(img_msg + (size_t)layer*10*8192);
  uint4 pa[4], pr[4], pb[4];

  __syncthreads();   // src_s/rel_s ready

#define M_ISSUE(CH) { \
    const int region=(CH)>>1, d0=((CH)&1)<<6; \
    _Pragma("unroll") for (int i=0;i<4;++i){ \
      int row = row0 + (i<<5); \
      if (region==0){ pa[i]=*(const uint4*)&h_bf[(((size_t)(b<<11)+src_s[row])<<7)+d0+(g<<3)]; \
                      pr[i]=*(const uint4*)&relt_bf[(((size_t)rel_s[row])<<7)+d0+(g<<3)]; } \
      else if (region==1){ pa[i]=*(const uint4*)&h_bf[(((size_t)(b<<11)+src_s[row])<<7)+d0+(g<<3)]; } \
      else if (region==2){ unsigned o=(src_s[row]==0)?0x3F803F80u:0u; pa[i].x=o; pa[i].y=o; pa[i].z=o; pa[i].w=o; } \
      else if (region==3){ pa[i]=*(const uint4*)&relt_bf[(((size_t)rel_s[row])<<7)+d0+(g<<3)]; } \
      else { pa[i]=*(const uint4*)&conf_bf[(((size_t)(ge0+row))<<7)+d0+(g<<3)]; } } \
    _Pragma("unroll") for (int i=0;i<4;++i) pb[i]=imgp[(CH)*1024+(i<<8)+t]; }

  M_ISSUE(0);
  #pragma unroll
  for (int ch=0; ch<10; ++ch){
    const int region = ch >> 1;
    #pragma unroll
    for (int i=0;i<4;++i){
      int row = row0 + (i<<5);
      uint4 val = pa[i];
      if (region == 0){
        val.x = pmul_bf(pa[i].x, pr[i].x); val.y = pmul_bf(pa[i].y, pr[i].y);
        val.z = pmul_bf(pa[i].z, pr[i].z); val.w = pmul_bf(pa[i].w, pr[i].w);
      }
      *(uint4*)(lds + row*128 + aswz) = val;
    }
    *(uint4*)(lds + 16384 + (t<<4))         = pb[0];
    *(uint4*)(lds + 16384 + (t<<4) + 4096)  = pb[1];
    *(uint4*)(lds + 16384 + (t<<4) + 8192)  = pb[2];
    *(uint4*)(lds + 16384 + (t<<4) + 12288) = pb[3];
    __syncthreads();
    if (ch < 9) M_ISSUE(ch+1);
    #pragma unroll
    for (int s=0;s<2;++s){
      bfrag af[4], bfr[4];
      #pragma unroll
      for (int m=0;m<4;++m)
        af[m] = *(const bfrag*)(lds + (rbase+(m<<4)+lr)*128 + (((s<<6)+(lk<<4)) ^ swz));
      #pragma unroll
      for (int n=0;n<4;++n)
        bfr[n] = *(const bfrag*)(lds + 16384 + (cbase+(n<<4)+lr)*128 + (((s<<6)+(lk<<4)) ^ swz));
      #pragma unroll
      for (int m=0;m<4;++m)
        #pragma unroll
        for (int n=0;n<4;++n)
          acc[m][n] = __builtin_amdgcn_mfma_f32_16x16x32_bf16(af[m], bfr[n], acc[m][n], 0,0,0);
    }
    __syncthreads();
  }
#undef M_ISSUE

  // ---- epilogue: relu+bias, att partials, raw->LDS (swizzled transpose)
  float bias[4], aw[4];
  #pragma unroll
  for (int n=0;n<4;++n){
    int col = cbase + (n<<4) + lr;
    bias[n] = msgb[layer*DDIM + col];
    aw[n]   = attW[layer*3*DDIM + col];
  }
  float p[4][4];
  #pragma unroll
  for (int m=0;m<4;++m)
    #pragma unroll
    for (int q=0;q<4;++q) p[m][q] = 0.f;
  #pragma unroll
  for (int m=0;m<4;++m)
    #pragma unroll
    for (int n=0;n<4;++n)
      #pragma unroll
      for (int q=0;q<4;++q){
        float v = fmaxf(acc[m][n][q] + bias[n], 0.f);
        p[m][q] = fmaf(v, aw[n], p[m][q]);
        int row = rbase + (m<<4) + (lk<<2) + q;
        int col = cbase + (n<<4) + lr;
        *(ushort_t*)(lds + (row<<8) + ((col<<1) ^ ((row&7)<<4))) = f2bf(v);
      }
  #pragma unroll
  for (int m=0;m<4;++m)
    #pragma unroll
    for (int q=0;q<4;++q){
      #pragma unroll
      for (int off=1; off<16; off<<=1) p[m][q] += __shfl_xor(p[m][q], off, 64);
    }
  if (lr == 0){
    #pragma unroll
    for (int m=0;m<4;++m)
      #pragma unroll
      for (int q=0;q<4;++q)
        att_buf[wc][rbase + (m<<4) + (lk<<2) + q] = p[m][q];
  }
  __syncthreads();

  // coalesced raw writeout (un-swizzle: 16B groups within a 256B row)
  #pragma unroll
  for (int i=0;i<8;++i){
    int u = t + (i<<8);                 // 2048 units of 16B
    int row = u >> 4, gg = u & 15;
    uint4 v = *(const uint4*)(lds + (row<<8) + ((gg<<4) ^ ((row&7)<<4)));
    *(uint4*)&raw[(((size_t)(ge0+row))<<7) + (gg<<3)] = v;
  }
  // att finalize (no atomics; node_agg does softmax)
  if (t < 128){
    int ge = ge0 + t;
    float ap = att_buf[0][t] + att_buf[1][t];
    float a = ap + att_rel[layer*NRELS + rel_s[t]] + att_rq[layer*BB + b] + attb[layer];
    a = (a >= 0.f) ? a : 0.01f*a;
    a = (em[ge] != 0) ? a : MASKV;
    att[ge] = a;
  }
}

// --------------------------- per-node softmax + weighted gather-aggregate
__global__ __launch_bounds__(128) void node_agg_kernel(
    const int* __restrict__ base, const int* __restrict__ eids,
    const float* __restrict__ att, const float* __restrict__ coef,
    const ushort_t* __restrict__ raw, float* __restrict__ aggr)
{
  const int n = blockIdx.x;              // BB*NNODE
  const int t = threadIdx.x;             // 128
  const int b0 = base[n], b1 = base[n+1];
  float mx = MASKV;
  for (int j=b0; j<b1; ++j) mx = fmaxf(mx, att[eids[j]]);
  float sm = 0.f;
  for (int j=b0; j<b1; ++j) sm += expf(att[eids[j]] - mx);
  const float inv = 1.0f/(sm + 1e-8f);
  float acc = 0.f;
  for (int j=b0; j<b1; ++j){
    int e = eids[j];
    float w = coef[e] * expf(att[e] - mx) * inv;
    acc = fmaf(w, bf2f(raw[((size_t)e<<7) + t]), acc);
  }
  aggr[((size_t)n<<7) + t] = acc;
}

// --------------------------------------------- h = LN(h + aggr@updW + updb)
#define FMA4(acc, a, bv) do { \
    acc.x = fmaf(a, bv.x, acc.x); \
    acc.y = fmaf(a, bv.y, acc.y); \
    acc.z = fmaf(a, bv.z, acc.z); \
    acc.w = fmaf(a, bv.w, acc.w); } while(0)

__global__ __launch_bounds__(256,2) void update_kernel(
    const float* __restrict__ aggr, const float* __restrict__ updW,
    const float* __restrict__ updb,
    const float* __restrict__ lng, const float* __restrict__ lnb,
    float* __restrict__ h, ushort_t* __restrict__ h_bf,
    float* __restrict__ out, int layer)
{
  __shared__ float As[64*65];
  __shared__ float Bs[64*128];
  const int t = threadIdx.x, blk = blockIdx.x;   // 128 blocks
  const int n0 = blk << 6;
  const int c = t & 15, r = t >> 4;
  float4 acc0[4], acc1[4];
  #pragma unroll
  for (int i=0;i<4;++i){ acc0[i]=make_float4(0,0,0,0); acc1[i]=make_float4(0,0,0,0); }
  const float* wbase = updW + (size_t)layer*DDIM*DDIM;

  for (int ch=0; ch<2; ++ch){
    __syncthreads();
    #pragma unroll
    for (int l=0;l<16;++l){
      int idx=(l<<8)+t, ei=idx>>6, kk=idx&63;
      As[ei*65+kk] = aggr[(size_t)(n0+ei)*DDIM + (ch<<6) + kk];
    }
    #pragma unroll
    for (int l=0;l<32;++l){
      int idx=(l<<8)+t, kk=idx>>7, j=idx&127;
      Bs[(kk<<7)+j] = wbase[((ch<<6)+kk)*DDIM + j];
    }
    __syncthreads();
    #pragma unroll 4
    for (int kk=0;kk<64;++kk){
      const float4 b0 = *(const float4*)&Bs[(kk<<7) + (c<<2)];
      const float4 b1 = *(const float4*)&Bs[(kk<<7) + 64 + (c<<2)];
      #pragma unroll
      for (int i=0;i<4;++i){
        const float a = As[((r<<2)+i)*65 + kk];
        FMA4(acc0[i], a, b0);
        FMA4(acc1[i], a, b1);
      }
    }
  }

  const int col0 = c << 2;
  float ub0[4], ub1[4], g0[4], g1[4], lb0[4], lb1[4];
  #pragma unroll
  for (int q=0;q<4;++q){
    ub0[q] = updb[layer*DDIM + col0+q];  ub1[q] = updb[layer*DDIM + 64+col0+q];
    g0[q]  = lng[col0+q];                g1[q]  = lng[64+col0+q];
    lb0[q] = lnb[col0+q];                lb1[q] = lnb[64+col0+q];
  }

  #pragma unroll
  for (int i=0;i<4;++i){
    const int row = n0 + (r<<2) + i;
    float* hrow = h + (size_t)row*DDIM;
    float4 h0 = *(float4*)&hrow[col0];
    float4 h1 = *(float4*)&hrow[64+col0];
    float x0[4], x1[4];
    x0[0] = h0.x + acc0[i].x + ub0[0];
    x0[1] = h0.y + acc0[i].y + ub0[1];
    x0[2] = h0.z + acc0[i].z + ub0[2];
    x0[3] = h0.w + acc0[i].w + ub0[3];
    x1[0] = h1.x + acc1[i].x + ub1[0];
    x1[1] = h1.y + acc1[i].y + ub1[1];
    x1[2] = h1.z + acc1[i].z + ub1[2];
    x1[3] = h1.w + acc1[i].w + ub1[3];
    float s = 0.f, s2 = 0.f;
    #pragma unroll
    for (int q=0;q<4;++q){ s += x0[q]+x1[q]; s2 += x0[q]*x0[q] + x1[q]*x1[q]; }
    #pragma unroll
    for (int off=1; off<16; off<<=1){
      s  += __shfl_xor(s,  off, 16);
      s2 += __shfl_xor(s2, off, 16);
    }
    const float mu = s * (1.0f/128.0f);
    const float var = s2 * (1.0f/128.0f) - mu*mu;
    const float rstd = rsqrtf(var + 1e-5f);
    float4 y0, y1;
    y0.x = (x0[0]-mu)*rstd*g0[0] + lb0[0];
    y0.y = (x0[1]-mu)*rstd*g0[1] + lb0[1];
    y0.z = (x0[2]-mu)*rstd*g0[2] + lb0[2];
    y0.w = (x0[3]-mu)*rstd*g0[3] + lb0[3];
    y1.x = (x1[0]-mu)*rstd*g1[0] + lb1[0];
    y1.y = (x1[1]-mu)*rstd*g1[1] + lb1[1];
    y1.z = (x1[2]-mu)*rstd*g1[2] + lb1[2];
    y1.w = (x1[3]-mu)*rstd*g1[3] + lb1[3];
    *(float4*)&hrow[col0] = y0;
    *(float4*)&hrow[64+col0] = y1;
    ushort4 z0, z1;
    z0.x=f2bf(y0.x); z0.y=f2bf(y0.y); z0.z=f2bf(y0.z); z0.w=f2bf(y0.w);
    z1.x=f2bf(y1.x); z1.y=f2bf(y1.y); z1.z=f2bf(y1.z); z1.w=f2bf(y1.w);
    *(ushort4*)&h_bf[(size_t)row*DDIM + col0] = z0;
    *(ushort4*)&h_bf[(size_t)row*DDIM + 64 + col0] = z1;
    if ((row & (NNODE-1)) == 0){
      const int bb_ = row >> 11;
      float* op = out + (size_t)(bb_*NL + layer)*DDIM;
      *(float4*)&op[col0] = y0;
      *(float4*)&op[64+col0] = y1;
    }
  }
}

// ------------------------------------------------------------------ launcher
extern "C" void kernel_launch(void* const* d_in, const int* in_sizes, int n_in,
                              void* d_out, int out_size, void* d_ws, size_t ws_size,
                              hipStream_t stream) {
  const int*   edge_index = (const int*)d_in[0];
  const int*   rels       = (const int*)d_in[1];
  const float* scores     = (const float*)d_in[2];
  const void*  cm_raw     = d_in[3];
  const void*  em_raw     = d_in[4];
  const float* rq    = (const float*)d_in[6];
  const float* conf  = (const float*)d_in[7];
  const float* relt  = (const float*)d_in[8];
  const float* betaW = (const float*)d_in[9];
  const float* betab = (const float*)d_in[10];
  const float* msgW  = (const float*)d_in[11];
  const float* msgb  = (const float*)d_in[12];
  const float* updW  = (const float*)d_in[13];
  const float* updb  = (const float*)d_in[14];
  const float* lng   = (const float*)d_in[15];
  const float* lnb   = (const float*)d_in[16];
  const float* attW  = (const float*)d_in[17];
  const float* attb  = (const float*)d_in[18];
  const float* denW1 = (const float*)d_in[19];
  const float* denb1 = (const float*)d_in[20];
  const float* denW2 = (const float*)d_in[21];
  const float* denb2 = (const float*)d_in[22];
  float* out = (float*)d_out;
  char* ws = (char*)d_ws;

  size_t off = 0;
  float* h        = (float*)(ws + off); off += (size_t)BB*NNODE*DDIM*4;      //  4 MB
  ushort_t* h_bf  = (ushort_t*)(ws + off); off += (size_t)BB*NNODE*DDIM*2;   //  2 MB
  float* aggr     = (float*)(ws + off); off += (size_t)BB*NNODE*DDIM*4;      //  4 MB
  ushort_t* raw   = (ushort_t*)(ws + off); off += (size_t)BB*NE*DDIM*2;      // 32 MB
  ushort_t* conf_bf = (ushort_t*)(ws + off); off += (size_t)BB*NE*DDIM*2;    // 32 MB
  ushort_t* relt_bf = (ushort_t*)(ws + off); off += (size_t)NRELS*DDIM*2 + 64;
  ushort_t* rq_bf   = (ushort_t*)(ws + off); off += (size_t)BB*DDIM*2 + 64;
  ushort_t* img_msg = (ushort_t*)(ws + off); off += (size_t)30*8192*2;       // 480 KB
  ushort_t* img_den = (ushort_t*)(ws + off); off += (size_t)6*8192*2;        //  96 KB
  float* coef     = (float*)(ws + off); off += (size_t)BB*NE*4;              // 512 KB
  float* att      = (float*)(ws + off); off += (size_t)BB*NE*4;              // 512 KB
  int* deg        = (int*)(ws + off); off += (size_t)BB*NNODE*4;
  int* base       = (int*)(ws + off); off += (size_t)(BB*NNODE+16)*4;
  int* cursor     = (int*)(ws + off); off += (size_t)BB*NNODE*4;
  int* eids       = (int*)(ws + off); off += (size_t)BB*NE*4;                // 512 KB
  float* att_rel  = (float*)(ws + off); off += 3*NRELS*4 + 32;
  float* att_rq   = (float*)(ws + off); off += 64;
  float* beta_rel = (float*)(ws + off); off += NRELS*4 + 32;
  float* beta_rq  = (float*)(ws + off); off += 64;
  uint8_t* cm_dec = (uint8_t*)(ws + off); off += (size_t)BB*NE;
  uint8_t* em_dec = (uint8_t*)(ws + off); off += (size_t)BB*NE;
  int* flag       = (int*)(ws + off); off += 64;

  probe_mask_kernel<<<1, 64, 0, stream>>>(cm_raw, flag);
  decode_masks_kernel<<<512, 256, 0, stream>>>(cm_raw, em_raw, flag, cm_dec, em_dec);
  conv_bf16_kernel<<<16384, 256, 0, stream>>>(conf, conf_bf, BB*NE*DDIM/4);
  conv_bf16_kernel<<<125, 256, 0, stream>>>(relt, relt_bf, NRELS*DDIM/4);
  conv_bf16_kernel<<<1, 256, 0, stream>>>(rq, rq_bf, BB*DDIM/4);
  build_wimg_kernel<<<1152, 256, 0, stream>>>(msgW, denW1, img_msg, img_den);
  init_h_kernel<<<4096, 256, 0, stream>>>(h, h_bf);
  csr_zero_kernel<<<32, 256, 0, stream>>>(deg);
  csr_hist_kernel<<<512, 256, 0, stream>>>(edge_index, deg);
  csr_scan_kernel<<<1, 256, 0, stream>>>(deg, base, cursor);
  csr_scatter_kernel<<<512, 256, 0, stream>>>(edge_index, cursor, eids);
  precomp_tables_kernel<<<1004, 256, 0, stream>>>(relt, rq, attW, betaW,
                                                  att_rel, att_rq, beta_rel, beta_rq);
  coef_mfma_kernel<<<1024, 256, 0, stream>>>(rels, scores, cm_dec, em_dec,
                                             relt_bf, rq_bf, conf_bf, img_den,
                                             denb1, denW2, denb2,
                                             beta_rel, beta_rq, betab, coef);
  for (int k = 0; k < NL; ++k){
    msg_mfma_kernel<<<1024, 256, 0, stream>>>(edge_index, rels, em_dec,
                                              relt_bf, conf_bf, h_bf, img_msg,
                                              msgb, attW, attb, att_rel, att_rq,
                                              raw, att, k);
    node_agg_kernel<<<BB*NNODE, 128, 0, stream>>>(base, eids, att, coef, raw, aggr);
    update_kernel<<<128, 256, 0, stream>>>(aggr, updW, updb, lng, lnb, h, h_bf, out, k);
  }
}

// Round 5
// 413.255 us; speedup vs baseline: 1.4440x; 1.4440x over previous
//
#include <hip/hip_runtime.h>
#include <stdint.h>
#include <math.h>

#define BB 4
#define NNODE 2048
#define NE 32768
#define DDIM 128
#define NL 3
#define NRELS 1000
#define MASKV -1000000000.0f

typedef unsigned short ushort_t;
typedef __attribute__((ext_vector_type(8))) short bfrag;   // 8 bf16 (4 VGPR)
typedef __attribute__((ext_vector_type(4))) float f4;

__device__ __forceinline__ float sigf(float x){ return 1.0f/(1.0f+expf(-x)); }

__device__ __forceinline__ float bf2f(ushort_t u){
  union { unsigned int i; float f; } v; v.i = ((unsigned int)u) << 16; return v.f;
}
__device__ __forceinline__ ushort_t f2bf(float x){
  union { float f; unsigned int u; } v; v.f = x;
  unsigned int r = (v.u + 0x7FFFu + ((v.u >> 16) & 1u)) >> 16;  // RNE
  return (ushort_t)r;
}
__device__ __forceinline__ float bflo(unsigned u){
  union{unsigned i;float f;}v; v.i=u<<16; return v.f;
}
__device__ __forceinline__ float bfhi(unsigned u){
  union{unsigned i;float f;}v; v.i=u&0xFFFF0000u; return v.f;
}
__device__ __forceinline__ unsigned pmul_bf(unsigned a, unsigned b){
  return (unsigned)f2bf(bflo(a)*bflo(b)) | ((unsigned)f2bf(bfhi(a)*bfhi(b))<<16);
}
__device__ __forceinline__ unsigned packbf(float a, float b){
  return (unsigned)f2bf(a) | ((unsigned)f2bf(b)<<16);
}

// ------------------------------------------------------- mask dtype probe
__global__ void probe_mask_kernel(const void* cm_raw, int* flag){
  int t = threadIdx.x;                       // 64 threads
  const int* ip = (const int*)cm_raw;
  unsigned v = (unsigned)ip[t];
  bool i32ok = (v <= 1u);
  bool f32ok = (v == 0u) || (v == 0x3F800000u);
  unsigned long long bi = __ballot(i32ok);
  unsigned long long bf_ = __ballot(f32ok);
  if (t == 0){
    int f;
    if (bi == ~0ULL) f = 0;
    else if (bf_ == ~0ULL) f = 1;
    else f = 2;
    *flag = f;
  }
}

// ---------------- fused prep: masks, deg=0, relt/rq->bf16, compact defaults, h init
__global__ void prep_kernel(const void* cm_raw, const void* em_raw, const int* __restrict__ flag,
    uint8_t* __restrict__ cm, uint8_t* __restrict__ em, int* __restrict__ deg,
    const float* __restrict__ relt, ushort_t* __restrict__ relt_bf,
    const float* __restrict__ rq, ushort_t* __restrict__ rq_bf,
    int* __restrict__ src_c, int* __restrict__ rel_c, int* __restrict__ ge_c,
    float* __restrict__ h, ushort_t* __restrict__ h_bf)
{
  int gid = blockIdx.x*256 + threadIdx.x;    // 262144 threads
  if (gid < BB*NE){
    int f = *flag; uint8_t c, e;
    if (f == 0){ c = ((const int*)cm_raw)[gid]!=0;   e = ((const int*)em_raw)[gid]!=0; }
    else if (f == 1){ c = ((const float*)cm_raw)[gid]!=0.0f; e = ((const float*)em_raw)[gid]!=0.0f; }
    else { c = ((const uint8_t*)cm_raw)[gid]!=0; e = ((const uint8_t*)em_raw)[gid]!=0; }
    cm[gid]=c; em[gid]=e;
    src_c[gid]=0; rel_c[gid]=0; ge_c[gid]=0;
  }
  if (gid < BB*NNODE) deg[gid]=0;
  if (gid < NRELS*DDIM/4){
    float4 v = *(const float4*)&relt[gid*4];
    ushort4 o; o.x=f2bf(v.x); o.y=f2bf(v.y); o.z=f2bf(v.z); o.w=f2bf(v.w);
    *(ushort4*)&relt_bf[gid*4] = o;
  }
  if (gid < BB*DDIM/4){
    float4 v = *(const float4*)&rq[gid*4];
    ushort4 o; o.x=f2bf(v.x); o.y=f2bf(v.y); o.z=f2bf(v.z); o.w=f2bf(v.w);
    *(ushort4*)&rq_bf[gid*4] = o;
  }
  {
    int base = gid*4;                        // h init: 1048576 floats
    int nd = base & (NNODE*DDIM - 1);
    bool one = (nd < DDIM);
    float4 hv = one ? (float4){1.f,1.f,1.f,1.f} : (float4){0.f,0.f,0.f,0.f};
    ushort4 hb = one ? (ushort4){0x3F80,0x3F80,0x3F80,0x3F80} : (ushort4){0,0,0,0};
    *(float4*)&h[base] = hv;
    *(ushort4*)&h_bf[base] = hb;
  }
}

// ------------------------------------------------------------ CSR build (filtered)
__global__ void csr_hist_kernel(const int* __restrict__ edge_index,
                                const uint8_t* __restrict__ em, int* __restrict__ deg){
  int gid = blockIdx.x*256 + threadIdx.x;          // B*E
  if (!em[gid]) return;
  int b = gid >> 15, e = gid & (NE-1);
  int tgt = edge_index[(b<<16) + NE + e];
  atomicAdd(&deg[(b<<11) + tgt], 1);
}
__global__ void csr_scan_kernel(const int* __restrict__ deg,
                                int* __restrict__ base, int* __restrict__ cursor){
  __shared__ int part[256];
  int t = threadIdx.x;                             // 256 threads, 1 block
  int loc[32]; int s = 0;
  #pragma unroll
  for (int i=0;i<32;++i){ loc[i] = deg[t*32+i]; s += loc[i]; }
  part[t] = s; __syncthreads();
  for (int off=1; off<256; off<<=1){
    int v = (t >= off) ? part[t-off] : 0;
    __syncthreads();
    part[t] += v;
    __syncthreads();
  }
  int ex = (t==0) ? 0 : part[t-1];
  #pragma unroll
  for (int i=0;i<32;++i){ base[t*32+i] = ex; cursor[t*32+i] = ex; ex += loc[i]; }
  if (t == 255) base[256*32] = ex;       // nact
}
__global__ void csr_scatter_kernel(const int* __restrict__ edge_index,
                                   const int* __restrict__ rels,
                                   const uint8_t* __restrict__ em,
                                   int* __restrict__ cursor,
                                   int* __restrict__ src_c, int* __restrict__ rel_c,
                                   int* __restrict__ ge_c){
  int gid = blockIdx.x*256 + threadIdx.x;          // B*E
  if (!em[gid]) return;
  int b = gid >> 15, e = gid & (NE-1);
  int tgt = edge_index[(b<<16) + NE + e];
  int src = edge_index[(b<<16) + e];
  int pos = atomicAdd(&cursor[(b<<11) + tgt], 1);
  src_c[pos] = (b<<11) | src;
  rel_c[pos] = rels[gid];
  ge_c[pos]  = gid;
}

// ------------------------------------------------- scalar tables (att/beta)
__global__ void precomp_tables_kernel(
    const float* __restrict__ relt, const float* __restrict__ rq,
    const float* __restrict__ attW, const float* __restrict__ betaW,
    float* __restrict__ att_rel, float* __restrict__ att_rq,
    float* __restrict__ beta_rel, float* __restrict__ beta_rq)
{
  int wid = (blockIdx.x*256 + threadIdx.x) >> 6;
  int lane = threadIdx.x & 63;
  if (wid >= 3*NRELS + 3*BB + NRELS + BB) return;
  const float* vec; const float* w; float* dst; int di;
  if (wid < 3*NRELS){
    int k = wid/NRELS, rl = wid%NRELS;
    vec = relt + rl*DDIM; w = attW + k*384 + 128; dst = att_rel; di = wid;
  } else if (wid < 3*NRELS + 3*BB){
    int idx = wid - 3*NRELS; int k = idx/BB, b = idx%BB;
    vec = rq + b*DDIM; w = attW + k*384 + 256; dst = att_rq; di = idx;
  } else if (wid < 3*NRELS + 3*BB + NRELS){
    int rl = wid - (3*NRELS + 3*BB);
    vec = relt + rl*DDIM; w = betaW; dst = beta_rel; di = rl;
  } else {
    int b = wid - (3*NRELS + 3*BB + NRELS);
    vec = rq + b*DDIM; w = betaW; dst = beta_rq; di = b;
  }
  float s = vec[lane]*w[lane] + vec[lane+64]*w[lane+64];
  #pragma unroll
  for (int off=32; off; off>>=1) s += __shfl_xor(s, off, 64);
  if (lane == 0) dst[di] = s;
}

// ------------------------------------- vector tables (hoisted GEMM regions)
// wave per output row; lane handles cols lane, lane+64
__global__ void vtables_kernel(const float* __restrict__ relt, const float* __restrict__ rq,
    const float* __restrict__ msgW, const float* __restrict__ msgb,
    const float* __restrict__ denW1, const float* __restrict__ denb1,
    float* __restrict__ relmsg, float* __restrict__ relhh0,
    float* __restrict__ denrel, float* __restrict__ denrq,
    float* __restrict__ initvec, float* __restrict__ src0vec)
{
  int wv = (blockIdx.x*256 + threadIdx.x) >> 6;
  int lane = threadIdx.x & 63;
  if (wv >= 5008) return;
  const float* A = nullptr; const float* W; int K = 128; float* out; const float* bias = nullptr;
  if (wv < 3000){ int k=wv/1000, rl=wv%1000;
    A=relt+rl*128; W=msgW+(size_t)k*81920+49152; out=relmsg+(size_t)wv*128; bias=msgb+k*128; }
  else if (wv < 4000){ int rl=wv-3000;
    A=relt+rl*128; W=msgW; out=relhh0+(size_t)rl*128; }
  else if (wv < 5000){ int rl=wv-4000;
    A=relt+rl*128; W=denW1; out=denrel+(size_t)rl*128; }
  else if (wv < 5004){ int b=wv-5000;
    A=rq+b*128; W=denW1+16384; out=denrq+b*128; bias=denb1; }
  else if (wv < 5007){ int k=wv-5004;
    W=msgW+(size_t)k*81920+32768; out=initvec+k*128; }
  else { W=msgW+16384; K=256; out=src0vec; }
  float a0=0.f, a1=0.f;
  for (int kk=0; kk<K; ++kk){
    float av = A ? A[kk] : 1.0f;
    a0 = fmaf(av, W[kk*128+lane],    a0);
    a1 = fmaf(av, W[kk*128+lane+64], a1);
  }
  if (bias){ a0 += bias[lane]; a1 += bias[lane+64]; }
  out[lane]=a0; out[lane+64]=a1;
}

// ------------------------- weight LDS-images (transposed, swizzled, bf16)
// img_msg[k][c][8192]: c 0,1 = hh rows 0..127; c 2,3 = conf rows 512..639
// img_den[c][8192]: conf rows 256..383 of den_W1
__global__ void build_wimg_kernel(const float* __restrict__ msgW,
                                  const float* __restrict__ denW1,
                                  ushort_t* __restrict__ img_msg,
                                  ushort_t* __restrict__ img_den){
  int e = blockIdx.x*256 + threadIdx.x;      // 14*8192 = 114688
  if (e >= 14*8192) return;
  int img_id = e >> 13;
  int ei = e & 8191;
  int j = ei >> 6;
  int kk = (((ei & 63) << 1) ^ ((j & 7) << 4)) >> 1;
  if (img_id < 12){
    int k = img_id >> 2, c = img_id & 3;
    int rowbase = (c < 2) ? c*64 : 512 + (c-2)*64;
    img_msg[(size_t)img_id*8192 + ei] = f2bf(msgW[(size_t)k*81920 + (rowbase+kk)*128 + j]);
  } else {
    int c = img_id - 12;
    int rowbase = 256 + c*64;
    img_den[(size_t)c*8192 + ei] = f2bf(denW1[(size_t)(rowbase+kk)*128 + j]);
  }
}

// ================================================= MFMA coef kernel (K=128, compact)
__global__ __launch_bounds__(256,2) void coef_mfma_kernel(
    const int* __restrict__ nact_p,
    const int* __restrict__ rel_c, const int* __restrict__ ge_c,
    const float* __restrict__ conf, const ushort_t* __restrict__ img_den,
    const float* __restrict__ denrel, const float* __restrict__ denrq,
    const float* __restrict__ denW2, const float* __restrict__ denb2,
    const float* __restrict__ scores, const uint8_t* __restrict__ cm,
    const float* __restrict__ beta_rel, const float* __restrict__ beta_rq,
    const float* __restrict__ betab,
    float* __restrict__ coef_c)
{
  __shared__ char lds[32768];
  __shared__ int rel_s[128], ge_s[128];
  __shared__ float w2_s[128];

  const int blk = blockIdx.x;
  const int ci0 = blk << 7;
  const int nact = *nact_p;
  if (ci0 >= nact) return;
  const int t = threadIdx.x;
  if (t < 128){ rel_s[t]=rel_c[ci0+t]; ge_s[t]=ge_c[ci0+t]; w2_s[t]=denW2[t]; }

  const int lane=t&63, wid=t>>6;
  const int wr=wid>>1, wc=wid&1;
  const int rbase=wr<<6, cbase=wc<<6;
  const int lr=lane&15, lk=lane>>4;
  const int swz=(lane&7)<<4;
  const int g=t&7, row0=t>>3;
  const int aswz=(g<<4)^((row0&7)<<4);

  f4 acc[4][4];
  #pragma unroll
  for (int m=0;m<4;++m)
    #pragma unroll
    for (int n=0;n<4;++n) acc[m][n]=(f4){0.f,0.f,0.f,0.f};

  const uint4* imgp = (const uint4*)img_den;
  float4 pf0[4], pf1[4];
  uint4 pb[4];
  __syncthreads();

  auto issueA = [&](int ch){
    const int d0=(ch&1)<<6;
    #pragma unroll
    for (int i=0;i<4;++i){
      int row=row0+(i<<5);
      const float* cp = conf + (((size_t)ge_s[row])<<7) + d0 + (g<<3);
      pf0[i]=*(const float4*)cp; pf1[i]=*(const float4*)(cp+4);
    }
    #pragma unroll
    for (int i=0;i<4;++i) pb[i]=imgp[ch*1024+(i<<8)+t];
  };

  issueA(0);
  #pragma unroll
  for (int ch=0; ch<2; ++ch){
    #pragma unroll
    for (int i=0;i<4;++i){
      int row=row0+(i<<5);
      uint4 val;
      val.x=packbf(pf0[i].x,pf0[i].y); val.y=packbf(pf0[i].z,pf0[i].w);
      val.z=packbf(pf1[i].x,pf1[i].y); val.w=packbf(pf1[i].z,pf1[i].w);
      *(uint4*)(lds + row*128 + aswz) = val;
    }
    *(uint4*)(lds+16384+(t<<4))        = pb[0];
    *(uint4*)(lds+16384+(t<<4)+4096)   = pb[1];
    *(uint4*)(lds+16384+(t<<4)+8192)   = pb[2];
    *(uint4*)(lds+16384+(t<<4)+12288)  = pb[3];
    __syncthreads();
    if (ch < 1) issueA(ch+1);
    #pragma unroll
    for (int s=0;s<2;++s){
      bfrag af[4], bfr[4];
      #pragma unroll
      for (int m=0;m<4;++m)
        af[m] = *(const bfrag*)(lds + (rbase+(m<<4)+lr)*128 + (((s<<6)+(lk<<4)) ^ swz));
      #pragma unroll
      for (int n=0;n<4;++n)
        bfr[n] = *(const bfrag*)(lds + 16384 + (cbase+(n<<4)+lr)*128 + (((s<<6)+(lk<<4)) ^ swz));
      #pragma unroll
      for (int m=0;m<4;++m)
        #pragma unroll
        for (int n=0;n<4;++n)
          acc[m][n] = __builtin_amdgcn_mfma_f32_16x16x32_bf16(af[m], bfr[n], acc[m][n], 0,0,0);
    }
    __syncthreads();
  }

  // transpose-store acc -> LDS bf16 (no bias yet)
  #pragma unroll
  for (int m=0;m<4;++m)
    #pragma unroll
    for (int n=0;n<4;++n)
      #pragma unroll
      for (int q=0;q<4;++q){
        int row=rbase+(m<<4)+(lk<<2)+q;
        int col=cbase+(n<<4)+lr;
        *(ushort_t*)(lds+(row<<8)+((col<<1)^((row&7)<<4))) = f2bf(acc[m][n][q]);
      }
  __syncthreads();

  #pragma unroll
  for (int i=0;i<8;++i){
    int u=t+(i<<8), row=u>>4, gg=u&15, c0=gg<<3;
    uint4 v = *(const uint4*)(lds+(row<<8)+((gg<<4)^((row&7)<<4)));
    float vv[8] = {bflo(v.x),bfhi(v.x),bflo(v.y),bfhi(v.y),
                   bflo(v.z),bfhi(v.z),bflo(v.w),bfhi(v.w)};
    int rel=rel_s[row], ge=ge_s[row], b=ge>>15;
    const float* dr = denrel + ((size_t)rel<<7) + c0;
    const float* dq = denrq + (b<<7) + c0;
    float part=0.f;
    #pragma unroll
    for (int j=0;j<8;++j){
      float m = fmaxf(vv[j] + dr[j] + dq[j], 0.f);
      part = fmaf(m, w2_s[c0+j], part);
    }
    #pragma unroll
    for (int off=1; off<16; off<<=1) part += __shfl_xor(part, off, 16);
    if (gg == 0){
      float den = sigf(part + denb2[0]);
      float beta = sigf(beta_rel[rel] + beta_rq[b] + betab[0]);
      float gt = cm[ge] ? sigf((scores[ge]-beta)*10.0f) : 0.5f;
      coef_c[ci0+row] = gt * den;
    }
  }
}

// ================================================= MFMA msg kernel (compact)
// !L0: K=256: [h*h_r (2 ch) | conf (2 ch)]; epilogue bias = H1[src]+relmsg+init
//  L0: K=128: [conf]; bias = relmsg0 + (src==0)*(relhh0+src0vec)
template<bool L0>
__global__ __launch_bounds__(256,2) void msg_mfma_kernel(
    const int* __restrict__ nact_p,
    const int* __restrict__ src_c, const int* __restrict__ rel_c,
    const int* __restrict__ ge_c,
    const ushort_t* __restrict__ relt_bf, const float* __restrict__ conf,
    const ushort_t* __restrict__ h_bf, const float* __restrict__ H1,
    const ushort_t* __restrict__ img_msg,
    const float* __restrict__ relmsg, const float* __restrict__ relhh0,
    const float* __restrict__ src0vec, const float* __restrict__ initvec,
    const float* __restrict__ attW, const float* __restrict__ attb,
    const float* __restrict__ att_rel, const float* __restrict__ att_rq,
    ushort_t* __restrict__ raw_c, float* __restrict__ att_c, int layer)
{
  constexpr int NCH = L0 ? 2 : 4;
  __shared__ char lds[32768];
  __shared__ int src_s[128], rel_s[128], ge_s[128];
  __shared__ float attw_s[128];

  const int blk = blockIdx.x;
  const int ci0 = blk << 7;
  const int nact = *nact_p;
  if (ci0 >= nact) return;
  const int t = threadIdx.x;
  if (t < 128){
    src_s[t]=src_c[ci0+t]; rel_s[t]=rel_c[ci0+t]; ge_s[t]=ge_c[ci0+t];
    attw_s[t]=attW[layer*384+t];
  }

  const int lane=t&63, wid=t>>6;
  const int wr=wid>>1, wc=wid&1;
  const int rbase=wr<<6, cbase=wc<<6;
  const int lr=lane&15, lk=lane>>4;
  const int swz=(lane&7)<<4;
  const int g=t&7, row0=t>>3;
  const int aswz=(g<<4)^((row0&7)<<4);

  f4 acc[4][4];
  #pragma unroll
  for (int m=0;m<4;++m)
    #pragma unroll
    for (int n=0;n<4;++n) acc[m][n]=(f4){0.f,0.f,0.f,0.f};

  const uint4* imgp = (const uint4*)(img_msg + (size_t)layer*4*8192);
  uint4 pa[4], pr[4], pb[4];
  float4 pf0[4], pf1[4];
  __syncthreads();

  auto issueA = [&](int ch){
    const int d0=(ch&1)<<6;
    const bool cf = L0 || (ch>=2);
    #pragma unroll
    for (int i=0;i<4;++i){
      int row=row0+(i<<5);
      if (cf){
        const float* cp = conf + (((size_t)ge_s[row])<<7) + d0 + (g<<3);
        pf0[i]=*(const float4*)cp; pf1[i]=*(const float4*)(cp+4);
      } else {
        pa[i]=*(const uint4*)&h_bf[(((size_t)src_s[row])<<7)+d0+(g<<3)];
        pr[i]=*(const uint4*)&relt_bf[(((size_t)rel_s[row])<<7)+d0+(g<<3)];
      }
    }
    int ic = L0 ? ch+2 : ch;
    #pragma unroll
    for (int i=0;i<4;++i) pb[i]=imgp[ic*1024+(i<<8)+t];
  };

  issueA(0);
  #pragma unroll
  for (int ch=0; ch<NCH; ++ch){
    const bool cf = L0 || (ch>=2);
    #pragma unroll
    for (int i=0;i<4;++i){
      int row=row0+(i<<5);
      uint4 val;
      if (cf){
        val.x=packbf(pf0[i].x,pf0[i].y); val.y=packbf(pf0[i].z,pf0[i].w);
        val.z=packbf(pf1[i].x,pf1[i].y); val.w=packbf(pf1[i].z,pf1[i].w);
      } else {
        val.x=pmul_bf(pa[i].x,pr[i].x); val.y=pmul_bf(pa[i].y,pr[i].y);
        val.z=pmul_bf(pa[i].z,pr[i].z); val.w=pmul_bf(pa[i].w,pr[i].w);
      }
      *(uint4*)(lds + row*128 + aswz) = val;
    }
    *(uint4*)(lds+16384+(t<<4))        = pb[0];
    *(uint4*)(lds+16384+(t<<4)+4096)   = pb[1];
    *(uint4*)(lds+16384+(t<<4)+8192)   = pb[2];
    *(uint4*)(lds+16384+(t<<4)+12288)  = pb[3];
    __syncthreads();
    if (ch < NCH-1) issueA(ch+1);
    #pragma unroll
    for (int s=0;s<2;++s){
      bfrag af[4], bfr[4];
      #pragma unroll
      for (int m=0;m<4;++m)
        af[m] = *(const bfrag*)(lds + (rbase+(m<<4)+lr)*128 + (((s<<6)+(lk<<4)) ^ swz));
      #pragma unroll
      for (int n=0;n<4;++n)
        bfr[n] = *(const bfrag*)(lds + 16384 + (cbase+(n<<4)+lr)*128 + (((s<<6)+(lk<<4)) ^ swz));
      #pragma unroll
      for (int m=0;m<4;++m)
        #pragma unroll
        for (int n=0;n<4;++n)
          acc[m][n] = __builtin_amdgcn_mfma_f32_16x16x32_bf16(af[m], bfr[n], acc[m][n], 0,0,0);
    }
    __syncthreads();
  }

  // transpose-store raw GEMM result -> LDS bf16 (bias/relu applied in pass 2)
  #pragma unroll
  for (int m=0;m<4;++m)
    #pragma unroll
    for (int n=0;n<4;++n)
      #pragma unroll
      for (int q=0;q<4;++q){
        int row=rbase+(m<<4)+(lk<<2)+q;
        int col=cbase+(n<<4)+lr;
        *(ushort_t*)(lds+(row<<8)+((col<<1)^((row&7)<<4))) = f2bf(acc[m][n][q]);
      }
  __syncthreads();

  #pragma unroll
  for (int i=0;i<8;++i){
    int u=t+(i<<8), row=u>>4, gg=u&15, c0=gg<<3;
    uint4 v = *(const uint4*)(lds+(row<<8)+((gg<<4)^((row&7)<<4)));
    float vv[8] = {bflo(v.x),bfhi(v.x),bflo(v.y),bfhi(v.y),
                   bflo(v.z),bfhi(v.z),bflo(v.w),bfhi(v.w)};
    int rel=rel_s[row], sc=src_s[row], ge=ge_s[row], b=ge>>15;
    const float* rm = relmsg + (((size_t)(layer*1000+rel))<<7) + c0;
    float bias[8];
    #pragma unroll
    for (int j=0;j<8;++j) bias[j] = rm[j];
    if (!L0){
      const float* hp = H1 + (((size_t)sc)<<7) + c0;
      #pragma unroll
      for (int j=0;j<8;++j) bias[j] += hp[j];
      if ((sc & (NNODE-1)) == 0){
        const float* iv = initvec + layer*128 + c0;
        #pragma unroll
        for (int j=0;j<8;++j) bias[j] += iv[j];
      }
    } else {
      if ((sc & (NNODE-1)) == 0){
        const float* rh = relhh0 + ((size_t)rel<<7) + c0;
        const float* sv = src0vec + c0;
        #pragma unroll
        for (int j=0;j<8;++j) bias[j] += rh[j] + sv[j];
      }
    }
    float part=0.f;
    unsigned o0,o1,o2,o3;
    {
      float m0=fmaxf(vv[0]+bias[0],0.f), m1=fmaxf(vv[1]+bias[1],0.f);
      float m2=fmaxf(vv[2]+bias[2],0.f), m3=fmaxf(vv[3]+bias[3],0.f);
      float m4=fmaxf(vv[4]+bias[4],0.f), m5=fmaxf(vv[5]+bias[5],0.f);
      float m6=fmaxf(vv[6]+bias[6],0.f), m7=fmaxf(vv[7]+bias[7],0.f);
      part = m0*attw_s[c0] + m1*attw_s[c0+1] + m2*attw_s[c0+2] + m3*attw_s[c0+3]
           + m4*attw_s[c0+4] + m5*attw_s[c0+5] + m6*attw_s[c0+6] + m7*attw_s[c0+7];
      o0=packbf(m0,m1); o1=packbf(m2,m3); o2=packbf(m4,m5); o3=packbf(m6,m7);
    }
    uint4 ov; ov.x=o0; ov.y=o1; ov.z=o2; ov.w=o3;
    *(uint4*)&raw_c[(((size_t)(ci0+row))<<7) + c0] = ov;
    #pragma unroll
    for (int off=1; off<16; off<<=1) part += __shfl_xor(part, off, 16);
    if (gg == 0){
      float a = part + att_rel[layer*NRELS+rel] + att_rq[layer*BB+b] + attb[layer];
      a = (a >= 0.f) ? a : 0.01f*a;
      att_c[ci0+row] = a;
    }
  }
}

// ------------------------------------- per-layer node GEMM: H1 = h @ W1region
#define FMA4(acc, a, bv) do { \
    acc.x = fmaf(a, bv.x, acc.x); \
    acc.y = fmaf(a, bv.y, acc.y); \
    acc.z = fmaf(a, bv.z, acc.z); \
    acc.w = fmaf(a, bv.w, acc.w); } while(0)

__global__ __launch_bounds__(256,2) void h1_gemm_kernel(
    const float* __restrict__ h, const float* __restrict__ msgW,
    float* __restrict__ H1, int layer)
{
  __shared__ float As[64*65];
  __shared__ float Bs[64*128];
  const int t = threadIdx.x, blk = blockIdx.x;   // 128 blocks
  const int n0 = blk << 6;
  const int c = t & 15, r = t >> 4;
  float4 acc0[4], acc1[4];
  #pragma unroll
  for (int i=0;i<4;++i){ acc0[i]=make_float4(0,0,0,0); acc1[i]=make_float4(0,0,0,0); }
  const float* wbase = msgW + (size_t)layer*81920 + 16384;   // rows 128..255

  for (int ch=0; ch<2; ++ch){
    __syncthreads();
    #pragma unroll
    for (int l=0;l<16;++l){
      int idx=(l<<8)+t, ei=idx>>6, kk=idx&63;
      As[ei*65+kk] = h[(size_t)(n0+ei)*DDIM + (ch<<6) + kk];
    }
    #pragma unroll
    for (int l=0;l<32;++l){
      int idx=(l<<8)+t, kk=idx>>7, j=idx&127;
      Bs[(kk<<7)+j] = wbase[((ch<<6)+kk)*DDIM + j];
    }
    __syncthreads();
    #pragma unroll 4
    for (int kk=0;kk<64;++kk){
      const float4 b0 = *(const float4*)&Bs[(kk<<7) + (c<<2)];
      const float4 b1 = *(const float4*)&Bs[(kk<<7) + 64 + (c<<2)];
      #pragma unroll
      for (int i=0;i<4;++i){
        const float a = As[((r<<2)+i)*65 + kk];
        FMA4(acc0[i], a, b0);
        FMA4(acc1[i], a, b1);
      }
    }
  }
  const int col0 = c << 2;
  #pragma unroll
  for (int i=0;i<4;++i){
    const int row = n0 + (r<<2) + i;
    *(float4*)&H1[(size_t)row*DDIM + col0]      = make_float4(acc0[i].x,acc0[i].y,acc0[i].z,acc0[i].w);
    *(float4*)&H1[(size_t)row*DDIM + 64 + col0] = make_float4(acc1[i].x,acc1[i].y,acc1[i].z,acc1[i].w);
  }
}

// --------------------------- per-node softmax + weighted aggregate (contiguous)
__global__ __launch_bounds__(128) void node_agg_kernel(
    const int* __restrict__ base,
    const float* __restrict__ att_c, const float* __restrict__ coef_c,
    const ushort_t* __restrict__ raw_c, float* __restrict__ aggr)
{
  const int n = blockIdx.x;              // BB*NNODE
  const int t = threadIdx.x;             // 128
  const int b0 = base[n], b1 = base[n+1];
  const int deg = b1 - b0;
  if (deg == 0){ aggr[((size_t)n<<7)+t] = 0.f; return; }
  __shared__ float w_s[128];
  __shared__ float red[4];
  float mx = -3.0e38f;
  for (int j=t; j<deg; j+=128) mx = fmaxf(mx, att_c[b0+j]);
  #pragma unroll
  for (int o=1;o<64;o<<=1) mx = fmaxf(mx, __shfl_xor(mx, o, 64));
  if ((t&63)==0) red[t>>6] = mx;
  __syncthreads();
  mx = fmaxf(red[0], red[1]);
  float s = 0.f;
  for (int j=t; j<deg; j+=128) s += expf(att_c[b0+j]-mx);
  #pragma unroll
  for (int o=1;o<64;o<<=1) s += __shfl_xor(s, o, 64);
  if ((t&63)==0) red[2+(t>>6)] = s;
  __syncthreads();
  const float inv = 1.0f/((red[2]+red[3]) + 1e-8f);
  float accv = 0.f;
  for (int jb=0; jb<deg; jb+=128){
    int jj = jb + t;
    __syncthreads();
    if (jj < deg) w_s[t] = coef_c[b0+jj] * expf(att_c[b0+jj]-mx) * inv;
    __syncthreads();
    int lim = min(128, deg-jb);
    for (int j=0; j<lim; ++j)
      accv = fmaf(w_s[j], bf2f(raw_c[(((size_t)(b0+jb+j))<<7)+t]), accv);
  }
  aggr[((size_t)n<<7)+t] = accv;
}

// --------------------------------------------- h = LN(h + aggr@updW + updb)
__global__ __launch_bounds__(256,2) void update_kernel(
    const float* __restrict__ aggr, const float* __restrict__ updW,
    const float* __restrict__ updb,
    const float* __restrict__ lng, const float* __restrict__ lnb,
    float* __restrict__ h, ushort_t* __restrict__ h_bf,
    float* __restrict__ out, int layer)
{
  __shared__ float As[64*65];
  __shared__ float Bs[64*128];
  const int t = threadIdx.x, blk = blockIdx.x;   // 128 blocks
  const int n0 = blk << 6;
  const int c = t & 15, r = t >> 4;
  float4 acc0[4], acc1[4];
  #pragma unroll
  for (int i=0;i<4;++i){ acc0[i]=make_float4(0,0,0,0); acc1[i]=make_float4(0,0,0,0); }
  const float* wbase = updW + (size_t)layer*DDIM*DDIM;

  for (int ch=0; ch<2; ++ch){
    __syncthreads();
    #pragma unroll
    for (int l=0;l<16;++l){
      int idx=(l<<8)+t, ei=idx>>6, kk=idx&63;
      As[ei*65+kk] = aggr[(size_t)(n0+ei)*DDIM + (ch<<6) + kk];
    }
    #pragma unroll
    for (int l=0;l<32;++l){
      int idx=(l<<8)+t, kk=idx>>7, j=idx&127;
      Bs[(kk<<7)+j] = wbase[((ch<<6)+kk)*DDIM + j];
    }
    __syncthreads();
    #pragma unroll 4
    for (int kk=0;kk<64;++kk){
      const float4 b0 = *(const float4*)&Bs[(kk<<7) + (c<<2)];
      const float4 b1 = *(const float4*)&Bs[(kk<<7) + 64 + (c<<2)];
      #pragma unroll
      for (int i=0;i<4;++i){
        const float a = As[((r<<2)+i)*65 + kk];
        FMA4(acc0[i], a, b0);
        FMA4(acc1[i], a, b1);
      }
    }
  }

  const int col0 = c << 2;
  float ub0[4], ub1[4], g0[4], g1[4], lb0[4], lb1[4];
  #pragma unroll
  for (int q=0;q<4;++q){
    ub0[q] = updb[layer*DDIM + col0+q];  ub1[q] = updb[layer*DDIM + 64+col0+q];
    g0[q]  = lng[col0+q];                g1[q]  = lng[64+col0+q];
    lb0[q] = lnb[col0+q];                lb1[q] = lnb[64+col0+q];
  }

  #pragma unroll
  for (int i=0;i<4;++i){
    const int row = n0 + (r<<2) + i;
    float* hrow = h + (size_t)row*DDIM;
    float4 h0 = *(float4*)&hrow[col0];
    float4 h1 = *(float4*)&hrow[64+col0];
    float x0[4], x1[4];
    x0[0] = h0.x + acc0[i].x + ub0[0];
    x0[1] = h0.y + acc0[i].y + ub0[1];
    x0[2] = h0.z + acc0[i].z + ub0[2];
    x0[3] = h0.w + acc0[i].w + ub0[3];
    x1[0] = h1.x + acc1[i].x + ub1[0];
    x1[1] = h1.y + acc1[i].y + ub1[1];
    x1[2] = h1.z + acc1[i].z + ub1[2];
    x1[3] = h1.w + acc1[i].w + ub1[3];
    float s = 0.f, s2 = 0.f;
    #pragma unroll
    for (int q=0;q<4;++q){ s += x0[q]+x1[q]; s2 += x0[q]*x0[q] + x1[q]*x1[q]; }
    #pragma unroll
    for (int off=1; off<16; off<<=1){
      s  += __shfl_xor(s,  off, 16);
      s2 += __shfl_xor(s2, off, 16);
    }
    const float mu = s * (1.0f/128.0f);
    const float var = s2 * (1.0f/128.0f) - mu*mu;
    const float rstd = rsqrtf(var + 1e-5f);
    float4 y0, y1;
    y0.x = (x0[0]-mu)*rstd*g0[0] + lb0[0];
    y0.y = (x0[1]-mu)*rstd*g0[1] + lb0[1];
    y0.z = (x0[2]-mu)*rstd*g0[2] + lb0[2];
    y0.w = (x0[3]-mu)*rstd*g0[3] + lb0[3];
    y1.x = (x1[0]-mu)*rstd*g1[0] + lb1[0];
    y1.y = (x1[1]-mu)*rstd*g1[1] + lb1[1];
    y1.z = (x1[2]-mu)*rstd*g1[2] + lb1[2];
    y1.w = (x1[3]-mu)*rstd*g1[3] + lb1[3];
    *(float4*)&hrow[col0] = y0;
    *(float4*)&hrow[64+col0] = y1;
    ushort4 z0, z1;
    z0.x=f2bf(y0.x); z0.y=f2bf(y0.y); z0.z=f2bf(y0.z); z0.w=f2bf(y0.w);
    z1.x=f2bf(y1.x); z1.y=f2bf(y1.y); z1.z=f2bf(y1.z); z1.w=f2bf(y1.w);
    *(ushort4*)&h_bf[(size_t)row*DDIM + col0] = z0;
    *(ushort4*)&h_bf[(size_t)row*DDIM + 64 + col0] = z1;
    if ((row & (NNODE-1)) == 0){
      const int bb_ = row >> 11;
      float* op = out + (size_t)(bb_*NL + layer)*DDIM;
      *(float4*)&op[col0] = y0;
      *(float4*)&op[64+col0] = y1;
    }
  }
}

// ------------------------------------------------------------------ launcher
extern "C" void kernel_launch(void* const* d_in, const int* in_sizes, int n_in,
                              void* d_out, int out_size, void* d_ws, size_t ws_size,
                              hipStream_t stream) {
  const int*   edge_index = (const int*)d_in[0];
  const int*   rels       = (const int*)d_in[1];
  const float* scores     = (const float*)d_in[2];
  const void*  cm_raw     = d_in[3];
  const void*  em_raw     = d_in[4];
  const float* rq    = (const float*)d_in[6];
  const float* conf  = (const float*)d_in[7];
  const float* relt  = (const float*)d_in[8];
  const float* betaW = (const float*)d_in[9];
  const float* betab = (const float*)d_in[10];
  const float* msgW  = (const float*)d_in[11];
  const float* msgb  = (const float*)d_in[12];
  const float* updW  = (const float*)d_in[13];
  const float* updb  = (const float*)d_in[14];
  const float* lng   = (const float*)d_in[15];
  const float* lnb   = (const float*)d_in[16];
  const float* attW  = (const float*)d_in[17];
  const float* attb  = (const float*)d_in[18];
  const float* denW1 = (const float*)d_in[19];
  const float* denb1 = (const float*)d_in[20];
  const float* denW2 = (const float*)d_in[21];
  const float* denb2 = (const float*)d_in[22];
  float* out = (float*)d_out;
  char* ws = (char*)d_ws;

  size_t off = 0;
  float* h        = (float*)(ws + off); off += (size_t)BB*NNODE*DDIM*4;      //  4 MB
  ushort_t* h_bf  = (ushort_t*)(ws + off); off += (size_t)BB*NNODE*DDIM*2;   //  2 MB
  float* aggr     = (float*)(ws + off); off += (size_t)BB*NNODE*DDIM*4;      //  4 MB
  float* H1       = (float*)(ws + off); off += (size_t)BB*NNODE*DDIM*4;      //  4 MB
  ushort_t* raw_c = (ushort_t*)(ws + off); off += (size_t)BB*NE*DDIM*2;      // 32 MB
  float* att_c    = (float*)(ws + off); off += (size_t)BB*NE*4;              // 512 KB
  float* coef_c   = (float*)(ws + off); off += (size_t)BB*NE*4;              // 512 KB
  int* src_c      = (int*)(ws + off); off += (size_t)BB*NE*4;
  int* rel_c      = (int*)(ws + off); off += (size_t)BB*NE*4;
  int* ge_c       = (int*)(ws + off); off += (size_t)BB*NE*4;
  int* deg        = (int*)(ws + off); off += (size_t)BB*NNODE*4;
  int* base       = (int*)(ws + off); off += (size_t)(BB*NNODE+16)*4;
  int* cursor     = (int*)(ws + off); off += (size_t)BB*NNODE*4;
  ushort_t* relt_bf = (ushort_t*)(ws + off); off += (size_t)NRELS*DDIM*2 + 64;
  ushort_t* rq_bf   = (ushort_t*)(ws + off); off += (size_t)BB*DDIM*2 + 64;
  ushort_t* img_msg = (ushort_t*)(ws + off); off += (size_t)12*8192*2;       // 192 KB
  ushort_t* img_den = (ushort_t*)(ws + off); off += (size_t)2*8192*2;        //  32 KB
  float* relmsg   = (float*)(ws + off); off += (size_t)3*NRELS*DDIM*4;       // 1.5 MB
  float* relhh0   = (float*)(ws + off); off += (size_t)NRELS*DDIM*4;         // 512 KB
  float* denrel   = (float*)(ws + off); off += (size_t)NRELS*DDIM*4;         // 512 KB
  float* denrq    = (float*)(ws + off); off += (size_t)BB*DDIM*4;
  float* initvec  = (float*)(ws + off); off += 3*DDIM*4;
  float* src0vec  = (float*)(ws + off); off += DDIM*4;
  float* att_rel  = (float*)(ws + off); off += 3*NRELS*4 + 32;
  float* att_rq   = (float*)(ws + off); off += 64;
  float* beta_rel = (float*)(ws + off); off += NRELS*4 + 32;
  float* beta_rq  = (float*)(ws + off); off += 64;
  uint8_t* cm_dec = (uint8_t*)(ws + off); off += (size_t)BB*NE;
  uint8_t* em_dec = (uint8_t*)(ws + off); off += (size_t)BB*NE;
  int* flag       = (int*)(ws + off); off += 64;

  probe_mask_kernel<<<1, 64, 0, stream>>>(cm_raw, flag);
  prep_kernel<<<1024, 256, 0, stream>>>(cm_raw, em_raw, flag, cm_dec, em_dec, deg,
                                        relt, relt_bf, rq, rq_bf,
                                        src_c, rel_c, ge_c, h, h_bf);
  csr_hist_kernel<<<512, 256, 0, stream>>>(edge_index, em_dec, deg);
  csr_scan_kernel<<<1, 256, 0, stream>>>(deg, base, cursor);
  csr_scatter_kernel<<<512, 256, 0, stream>>>(edge_index, rels, em_dec, cursor,
                                              src_c, rel_c, ge_c);
  precomp_tables_kernel<<<1004, 256, 0, stream>>>(relt, rq, attW, betaW,
                                                  att_rel, att_rq, beta_rel, beta_rq);
  vtables_kernel<<<1252, 256, 0, stream>>>(relt, rq, msgW, msgb, denW1, denb1,
                                           relmsg, relhh0, denrel, denrq,
                                           initvec, src0vec);
  build_wimg_kernel<<<448, 256, 0, stream>>>(msgW, denW1, img_msg, img_den);
  coef_mfma_kernel<<<1024, 256, 0, stream>>>(base + BB*NNODE, rel_c, ge_c, conf, img_den,
                                             denrel, denrq, denW2, denb2,
                                             scores, cm_dec, beta_rel, beta_rq, betab,
                                             coef_c);
  for (int k = 0; k < NL; ++k){
    if (k == 0){
      msg_mfma_kernel<true><<<1024, 256, 0, stream>>>(base + BB*NNODE, src_c, rel_c, ge_c,
          relt_bf, conf, h_bf, H1, img_msg, relmsg, relhh0, src0vec, initvec,
          attW, attb, att_rel, att_rq, raw_c, att_c, k);
    } else {
      h1_gemm_kernel<<<128, 256, 0, stream>>>(h, msgW, H1, k);
      msg_mfma_kernel<false><<<1024, 256, 0, stream>>>(base + BB*NNODE, src_c, rel_c, ge_c,
          relt_bf, conf, h_bf, H1, img_msg, relmsg, relhh0, src0vec, initvec,
          attW, attb, att_rel, att_rq, raw_c, att_c, k);
    }
    node_agg_kernel<<<BB*NNODE, 128, 0, stream>>>(base, att_c, coef_c, raw_c, aggr);
    update_kernel<<<128, 256, 0, stream>>>(aggr, updW, updb, lng, lnb, h, h_bf, out, k);
  }
}

// Round 7
// 382.742 us; speedup vs baseline: 1.5592x; 1.0797x over previous
//
#include <hip/hip_runtime.h>
#include <stdint.h>
#include <math.h>

#define BB 4
#define NNODE 2048
#define NE 32768
#define DDIM 128
#define NL 3
#define NRELS 1000
#define MASKV -1000000000.0f

typedef unsigned short ushort_t;
typedef __attribute__((ext_vector_type(8))) short bfrag;   // 8 bf16 (4 VGPR)
typedef __attribute__((ext_vector_type(4))) float f4;

__device__ __forceinline__ float sigf(float x){ return 1.0f/(1.0f+expf(-x)); }

__device__ __forceinline__ float bf2f(ushort_t u){
  union { unsigned int i; float f; } v; v.i = ((unsigned int)u) << 16; return v.f;
}
__device__ __forceinline__ ushort_t f2bf(float x){
  union { float f; unsigned int u; } v; v.f = x;
  unsigned int r = (v.u + 0x7FFFu + ((v.u >> 16) & 1u)) >> 16;  // RNE
  return (ushort_t)r;
}
__device__ __forceinline__ float bflo(unsigned u){
  union{unsigned i;float f;}v; v.i=u<<16; return v.f;
}
__device__ __forceinline__ float bfhi(unsigned u){
  union{unsigned i;float f;}v; v.i=u&0xFFFF0000u; return v.f;
}
__device__ __forceinline__ unsigned pmul_bf(unsigned a, unsigned b){
  return (unsigned)f2bf(bflo(a)*bflo(b)) | ((unsigned)f2bf(bfhi(a)*bfhi(b))<<16);
}
__device__ __forceinline__ unsigned packbf(float a, float b){
  return (unsigned)f2bf(a) | ((unsigned)f2bf(b)<<16);
}

// ---------------- fused prep: inline mask-probe, masks, deg=0, bf16 tables,
// compact-array defaults, h init
__global__ void prep_kernel(const void* cm_raw, const void* em_raw,
    uint8_t* __restrict__ cm, uint8_t* __restrict__ em, int* __restrict__ deg,
    const float* __restrict__ relt, ushort_t* __restrict__ relt_bf,
    const float* __restrict__ rq, ushort_t* __restrict__ rq_bf,
    int* __restrict__ src_c, int* __restrict__ rel_c, int* __restrict__ ge_c,
    float* __restrict__ h, ushort_t* __restrict__ h_bf)
{
  __shared__ int flag_s;
  if (threadIdx.x < 64){
    unsigned v = ((const unsigned*)cm_raw)[threadIdx.x];
    bool i32ok = (v <= 1u);
    bool f32ok = (v == 0u) || (v == 0x3F800000u);
    unsigned long long bi = __ballot(i32ok);
    unsigned long long bf_ = __ballot(f32ok);
    if (threadIdx.x == 0) flag_s = (bi==~0ULL) ? 0 : ((bf_==~0ULL) ? 1 : 2);
  }
  __syncthreads();
  const int f = flag_s;
  int gid = blockIdx.x*256 + threadIdx.x;    // 262144 threads
  if (gid < BB*NE){
    uint8_t c, e;
    if (f == 0){ c = ((const int*)cm_raw)[gid]!=0;   e = ((const int*)em_raw)[gid]!=0; }
    else if (f == 1){ c = ((const float*)cm_raw)[gid]!=0.0f; e = ((const float*)em_raw)[gid]!=0.0f; }
    else { c = ((const uint8_t*)cm_raw)[gid]!=0; e = ((const uint8_t*)em_raw)[gid]!=0; }
    cm[gid]=c; em[gid]=e;
    src_c[gid]=0; rel_c[gid]=0; ge_c[gid]=0;
  }
  if (gid < BB*NNODE) deg[gid]=0;
  if (gid < NRELS*DDIM/4){
    float4 v = *(const float4*)&relt[gid*4];
    ushort4 o; o.x=f2bf(v.x); o.y=f2bf(v.y); o.z=f2bf(v.z); o.w=f2bf(v.w);
    *(ushort4*)&relt_bf[gid*4] = o;
  }
  if (gid < BB*DDIM/4){
    float4 v = *(const float4*)&rq[gid*4];
    ushort4 o; o.x=f2bf(v.x); o.y=f2bf(v.y); o.z=f2bf(v.z); o.w=f2bf(v.w);
    *(ushort4*)&rq_bf[gid*4] = o;
  }
  {
    int base = gid*4;                        // h init: 1048576 floats
    int nd = base & (NNODE*DDIM - 1);
    bool one = (nd < DDIM);
    float4 hv = one ? (float4){1.f,1.f,1.f,1.f} : (float4){0.f,0.f,0.f,0.f};
    ushort4 hb = one ? (ushort4){0x3F80,0x3F80,0x3F80,0x3F80} : (ushort4){0,0,0,0};
    *(float4*)&h[base] = hv;
    *(ushort4*)&h_bf[base] = hb;
  }
}

// ------------------------------------------------------------ CSR build (filtered)
__global__ void csr_hist_kernel(const int* __restrict__ edge_index,
                                const uint8_t* __restrict__ em, int* __restrict__ deg){
  int gid = blockIdx.x*256 + threadIdx.x;          // B*E
  if (!em[gid]) return;
  int b = gid >> 15, e = gid & (NE-1);
  int tgt = edge_index[(b<<16) + NE + e];
  atomicAdd(&deg[(b<<11) + tgt], 1);
}
__global__ void csr_scan_kernel(const int* __restrict__ deg,
                                int* __restrict__ base, int* __restrict__ cursor){
  __shared__ int part[256];
  int t = threadIdx.x;                             // 256 threads, 1 block
  int loc[32]; int s = 0;
  #pragma unroll
  for (int i=0;i<32;++i){ loc[i] = deg[t*32+i]; s += loc[i]; }
  part[t] = s; __syncthreads();
  for (int off=1; off<256; off<<=1){
    int v = (t >= off) ? part[t-off] : 0;
    __syncthreads();
    part[t] += v;
    __syncthreads();
  }
  int ex = (t==0) ? 0 : part[t-1];
  #pragma unroll
  for (int i=0;i<32;++i){ base[t*32+i] = ex; cursor[t*32+i] = ex; ex += loc[i]; }
  if (t == 255) base[256*32] = ex;       // nact
}
__global__ void csr_scatter_kernel(const int* __restrict__ edge_index,
                                   const int* __restrict__ rels,
                                   const uint8_t* __restrict__ em,
                                   int* __restrict__ cursor,
                                   int* __restrict__ src_c, int* __restrict__ rel_c,
                                   int* __restrict__ ge_c){
  int gid = blockIdx.x*256 + threadIdx.x;          // B*E
  if (!em[gid]) return;
  int b = gid >> 15, e = gid & (NE-1);
  int tgt = edge_index[(b<<16) + NE + e];
  int src = edge_index[(b<<16) + e];
  int pos = atomicAdd(&cursor[(b<<11) + tgt], 1);
  src_c[pos] = (b<<11) | src;
  rel_c[pos] = rels[gid];
  ge_c[pos]  = gid;
}

// ------------------------- scalar tables (att/beta) + tiny vector rows
__global__ void precomp_tables_kernel(
    const float* __restrict__ relt, const float* __restrict__ rq,
    const float* __restrict__ attW, const float* __restrict__ betaW,
    const float* __restrict__ msgW, const float* __restrict__ denW1,
    const float* __restrict__ denb1,
    float* __restrict__ att_rel, float* __restrict__ att_rq,
    float* __restrict__ beta_rel, float* __restrict__ beta_rq,
    float* __restrict__ denrq, float* __restrict__ initvec,
    float* __restrict__ src0vec)
{
  int wid = (blockIdx.x*256 + threadIdx.x) >> 6;
  int lane = threadIdx.x & 63;
  if (wid >= 4024) return;
  if (wid >= 4016){                       // 8 tiny vector-table rows
    int widx = wid - 4016;
    const float* A = nullptr; const float* W; int K = 128;
    float* outp; const float* bias = nullptr;
    if (widx < 4){ A = rq + widx*128; W = denW1 + 16384; outp = denrq + widx*128; bias = denb1; }
    else if (widx < 7){ int k=widx-4; W = msgW + (size_t)k*81920 + 32768; outp = initvec + k*128; }
    else { W = msgW + 16384; K = 256; outp = src0vec; }
    float a0=0.f, a1=0.f;
    for (int kk=0; kk<K; kk+=8){
      float av[8], w0[8], w1[8];
      #pragma unroll
      for (int u=0;u<8;++u){
        av[u] = A ? A[kk+u] : 1.0f;
        w0[u] = W[(size_t)(kk+u)*128 + lane];
        w1[u] = W[(size_t)(kk+u)*128 + lane + 64];
      }
      #pragma unroll
      for (int u=0;u<8;++u){ a0 = fmaf(av[u], w0[u], a0); a1 = fmaf(av[u], w1[u], a1); }
    }
    if (bias){ a0 += bias[lane]; a1 += bias[lane+64]; }
    outp[lane] = a0; outp[lane+64] = a1;
    return;
  }
  const float* vec; const float* w; float* dst; int di;
  if (wid < 3*NRELS){
    int k = wid/1000, rl = wid%1000;
    vec = relt + rl*DDIM; w = attW + k*384 + 128; dst = att_rel; di = wid;
  } else if (wid < 3*NRELS + 3*BB){
    int idx = wid - 3*NRELS; int k = idx/BB, b = idx%BB;
    vec = rq + b*DDIM; w = attW + k*384 + 256; dst = att_rq; di = idx;
  } else if (wid < 3*NRELS + 3*BB + NRELS){
    int rl = wid - (3*NRELS + 3*BB);
    vec = relt + rl*DDIM; w = betaW; dst = beta_rel; di = rl;
  } else {
    int b = wid - (3*NRELS + 3*BB + NRELS);
    vec = rq + b*DDIM; w = betaW; dst = beta_rq; di = b;
  }
  float s = vec[lane]*w[lane] + vec[lane+64]*w[lane+64];
  #pragma unroll
  for (int off=32; off; off>>=1) s += __shfl_xor(s, off, 64);
  if (lane == 0) dst[di] = s;
}

// ------------------------- weight LDS-images (transposed, swizzled, bf16)
// ids 0..11  img_msg[k][c]: c 0,1 = hh rows 0..127; c 2,3 = conf rows 512..639
// ids 12..13 img_den: denW1 rows 256..383
// ids 14..19 img_tab: msgW[k] rows 384..511 (relmsg B)
// ids 20..21 img_tab: denW1 rows 0..127 (denrel B)
__global__ void build_wimg_kernel(const float* __restrict__ msgW,
                                  const float* __restrict__ denW1,
                                  ushort_t* __restrict__ img_msg,
                                  ushort_t* __restrict__ img_den,
                                  ushort_t* __restrict__ img_tab){
  int e = blockIdx.x*256 + threadIdx.x;      // 22*8192 = 180224
  if (e >= 22*8192) return;
  int img_id = e >> 13;
  int ei = e & 8191;
  int j = ei >> 6;
  int kk = (((ei & 63) << 1) ^ ((j & 7) << 4)) >> 1;
  float v;
  ushort_t* dst;
  if (img_id < 12){
    int k = img_id >> 2, c = img_id & 3;
    int rowbase = (c < 2) ? c*64 : 512 + (c-2)*64;
    v = msgW[(size_t)k*81920 + (rowbase+kk)*128 + j];
    dst = img_msg + (size_t)img_id*8192;
  } else if (img_id < 14){
    int c = img_id - 12;
    v = denW1[(size_t)(256 + c*64 + kk)*128 + j];
    dst = img_den + (size_t)c*8192;
  } else if (img_id < 20){
    int idx = img_id - 14, k = idx >> 1, c = idx & 1;
    v = msgW[(size_t)k*81920 + (384 + c*64 + kk)*128 + j];
    dst = img_tab + (size_t)idx*8192;
  } else {
    int c = img_id - 20;
    v = denW1[(size_t)(c*64 + kk)*128 + j];
    dst = img_tab + (size_t)(6+c)*8192;
  }
  dst[ei] = f2bf(v);
}

// ===================== MFMA table GEMM: {relmsg, relhh0, denrel} = relt @ B
__global__ __launch_bounds__(256,2) void table_gemm_kernel(
    const ushort_t* __restrict__ relt_bf, const ushort_t* __restrict__ img_msg,
    const ushort_t* __restrict__ img_tab, const float* __restrict__ msgb,
    float* __restrict__ relmsg, float* __restrict__ relhh0,
    float* __restrict__ denrel)
{
  __shared__ char lds[32768];
  __shared__ float bias_s[128];
  const int blk = blockIdx.x;      // 40 = 8 row-tiles x 5 jobs
  const int job = blk % 5;
  const int ri0 = (blk/5) << 7;
  const int t = threadIdx.x;
  const uint4* imgb;
  float* outp;
  if (job < 3){ imgb = (const uint4*)(img_tab + (size_t)(2*job)*8192); outp = relmsg + (size_t)job*NRELS*DDIM; }
  else if (job == 3){ imgb = (const uint4*)img_msg; outp = relhh0; }
  else { imgb = (const uint4*)(img_tab + (size_t)6*8192); outp = denrel; }
  if (t < 128) bias_s[t] = (job < 3) ? msgb[job*128 + t] : 0.f;

  const int lane=t&63, wid=t>>6;
  const int wr=wid>>1, wc=wid&1;
  const int rbase=wr<<6, cbase=wc<<6;
  const int lr=lane&15, lk=lane>>4;
  const int swz=(lane&7)<<4;
  const int g=t&7, row0=t>>3;
  const int aswz=(g<<4)^((row0&7)<<4);

  f4 acc[4][4];
  #pragma unroll
  for (int m=0;m<4;++m)
    #pragma unroll
    for (int n=0;n<4;++n) acc[m][n]=(f4){0.f,0.f,0.f,0.f};

  uint4 pa[4], pb[4];
  auto issueA = [&](int ch){
    #pragma unroll
    for (int i=0;i<4;++i){
      int rr = ri0 + row0 + (i<<5);
      rr = (rr < NRELS) ? rr : (NRELS-1);
      pa[i] = *(const uint4*)&relt_bf[(size_t)rr*128 + (ch<<6) + (g<<3)];
    }
    #pragma unroll
    for (int i=0;i<4;++i) pb[i] = imgb[ch*1024 + (i<<8) + t];
  };

  __syncthreads();
  issueA(0);
  #pragma unroll
  for (int ch=0; ch<2; ++ch){
    #pragma unroll
    for (int i=0;i<4;++i){
      int row = row0 + (i<<5);
      *(uint4*)(lds + row*128 + aswz) = pa[i];
    }
    *(uint4*)(lds+16384+(t<<4))        = pb[0];
    *(uint4*)(lds+16384+(t<<4)+4096)   = pb[1];
    *(uint4*)(lds+16384+(t<<4)+8192)   = pb[2];
    *(uint4*)(lds+16384+(t<<4)+12288)  = pb[3];
    __syncthreads();
    if (ch < 1) issueA(ch+1);
    #pragma unroll
    for (int s=0;s<2;++s){
      bfrag af[4], bfr[4];
      #pragma unroll
      for (int m=0;m<4;++m)
        af[m] = *(const bfrag*)(lds + (rbase+(m<<4)+lr)*128 + (((s<<6)+(lk<<4)) ^ swz));
      #pragma unroll
      for (int n=0;n<4;++n)
        bfr[n] = *(const bfrag*)(lds + 16384 + (cbase+(n<<4)+lr)*128 + (((s<<6)+(lk<<4)) ^ swz));
      #pragma unroll
      for (int m=0;m<4;++m)
        #pragma unroll
        for (int n=0;n<4;++n)
          acc[m][n] = __builtin_amdgcn_mfma_f32_16x16x32_bf16(af[m], bfr[n], acc[m][n], 0,0,0);
    }
    __syncthreads();
  }

  #pragma unroll
  for (int m=0;m<4;++m)
    #pragma unroll
    for (int n=0;n<4;++n){
      int col = cbase + (n<<4) + lr;
      float bv = bias_s[col];
      #pragma unroll
      for (int q=0;q<4;++q){
        int gr = ri0 + rbase + (m<<4) + (lk<<2) + q;
        if (gr < NRELS) outp[(size_t)gr*128 + col] = acc[m][n][q] + bv;
      }
    }
}

// ================================================= MFMA coef kernel (K=128, compact)
__global__ __launch_bounds__(256,2) void coef_mfma_kernel(
    const int* __restrict__ nact_p,
    const int* __restrict__ rel_c, const int* __restrict__ ge_c,
    const float* __restrict__ conf, const ushort_t* __restrict__ img_den,
    const float* __restrict__ denrel, const float* __restrict__ denrq,
    const float* __restrict__ denW2, const float* __restrict__ denb2,
    const float* __restrict__ scores, const uint8_t* __restrict__ cm,
    const float* __restrict__ beta_rel, const float* __restrict__ beta_rq,
    const float* __restrict__ betab,
    float* __restrict__ coef_c)
{
  __shared__ char lds[32768];
  __shared__ int rel_s[128], ge_s[128];
  __shared__ float w2_s[128];

  const int blk = blockIdx.x;
  const int ci0 = blk << 7;
  const int nact = *nact_p;
  if (ci0 >= nact) return;
  const int t = threadIdx.x;
  if (t < 128){ rel_s[t]=rel_c[ci0+t]; ge_s[t]=ge_c[ci0+t]; w2_s[t]=denW2[t]; }

  const int lane=t&63, wid=t>>6;
  const int wr=wid>>1, wc=wid&1;
  const int rbase=wr<<6, cbase=wc<<6;
  const int lr=lane&15, lk=lane>>4;
  const int swz=(lane&7)<<4;
  const int g=t&7, row0=t>>3;
  const int aswz=(g<<4)^((row0&7)<<4);

  f4 acc[4][4];
  #pragma unroll
  for (int m=0;m<4;++m)
    #pragma unroll
    for (int n=0;n<4;++n) acc[m][n]=(f4){0.f,0.f,0.f,0.f};

  const uint4* imgp = (const uint4*)img_den;
  float4 pf0[4], pf1[4];
  uint4 pb[4];
  __syncthreads();

  auto issueA = [&](int ch){
    const int d0=(ch&1)<<6;
    #pragma unroll
    for (int i=0;i<4;++i){
      int row=row0+(i<<5);
      const float* cp = conf + (((size_t)ge_s[row])<<7) + d0 + (g<<3);
      pf0[i]=*(const float4*)cp; pf1[i]=*(const float4*)(cp+4);
    }
    #pragma unroll
    for (int i=0;i<4;++i) pb[i]=imgp[ch*1024+(i<<8)+t];
  };

  issueA(0);
  #pragma unroll
  for (int ch=0; ch<2; ++ch){
    #pragma unroll
    for (int i=0;i<4;++i){
      int row=row0+(i<<5);
      uint4 val;
      val.x=packbf(pf0[i].x,pf0[i].y); val.y=packbf(pf0[i].z,pf0[i].w);
      val.z=packbf(pf1[i].x,pf1[i].y); val.w=packbf(pf1[i].z,pf1[i].w);
      *(uint4*)(lds + row*128 + aswz) = val;
    }
    *(uint4*)(lds+16384+(t<<4))        = pb[0];
    *(uint4*)(lds+16384+(t<<4)+4096)   = pb[1];
    *(uint4*)(lds+16384+(t<<4)+8192)   = pb[2];
    *(uint4*)(lds+16384+(t<<4)+12288)  = pb[3];
    __syncthreads();
    if (ch < 1) issueA(ch+1);
    #pragma unroll
    for (int s=0;s<2;++s){
      bfrag af[4], bfr[4];
      #pragma unroll
      for (int m=0;m<4;++m)
        af[m] = *(const bfrag*)(lds + (rbase+(m<<4)+lr)*128 + (((s<<6)+(lk<<4)) ^ swz));
      #pragma unroll
      for (int n=0;n<4;++n)
        bfr[n] = *(const bfrag*)(lds + 16384 + (cbase+(n<<4)+lr)*128 + (((s<<6)+(lk<<4)) ^ swz));
      #pragma unroll
      for (int m=0;m<4;++m)
        #pragma unroll
        for (int n=0;n<4;++n)
          acc[m][n] = __builtin_amdgcn_mfma_f32_16x16x32_bf16(af[m], bfr[n], acc[m][n], 0,0,0);
    }
    __syncthreads();
  }

  // transpose-store acc -> LDS bf16 (bias applied in pass 2)
  #pragma unroll
  for (int m=0;m<4;++m)
    #pragma unroll
    for (int n=0;n<4;++n)
      #pragma unroll
      for (int q=0;q<4;++q){
        int row=rbase+(m<<4)+(lk<<2)+q;
        int col=cbase+(n<<4)+lr;
        *(ushort_t*)(lds+(row<<8)+((col<<1)^((row&7)<<4))) = f2bf(acc[m][n][q]);
      }
  __syncthreads();

  #pragma unroll
  for (int i=0;i<8;++i){
    int u=t+(i<<8), row=u>>4, gg=u&15, c0=gg<<3;
    uint4 v = *(const uint4*)(lds+(row<<8)+((gg<<4)^((row&7)<<4)));
    float vv[8] = {bflo(v.x),bfhi(v.x),bflo(v.y),bfhi(v.y),
                   bflo(v.z),bfhi(v.z),bflo(v.w),bfhi(v.w)};
    int rel=rel_s[row], ge=ge_s[row], b=ge>>15;
    const float* dr = denrel + ((size_t)rel<<7) + c0;
    const float* dq = denrq + (b<<7) + c0;
    float part=0.f;
    #pragma unroll
    for (int j=0;j<8;++j){
      float m = fmaxf(vv[j] + dr[j] + dq[j], 0.f);
      part = fmaf(m, w2_s[c0+j], part);
    }
    #pragma unroll
    for (int off=1; off<16; off<<=1) part += __shfl_xor(part, off, 16);
    if (gg == 0){
      float den = sigf(part + denb2[0]);
      float beta = sigf(beta_rel[rel] + beta_rq[b] + betab[0]);
      float gt = cm[ge] ? sigf((scores[ge]-beta)*10.0f) : 0.5f;
      coef_c[ci0+row] = gt * den;
    }
  }
}

// ================================================= MFMA msg kernel (compact)
template<bool L0>
__global__ __launch_bounds__(256,2) void msg_mfma_kernel(
    const int* __restrict__ nact_p,
    const int* __restrict__ src_c, const int* __restrict__ rel_c,
    const int* __restrict__ ge_c,
    const ushort_t* __restrict__ relt_bf, const float* __restrict__ conf,
    const ushort_t* __restrict__ h_bf, const float* __restrict__ H1,
    const ushort_t* __restrict__ img_msg,
    const float* __restrict__ relmsg, const float* __restrict__ relhh0,
    const float* __restrict__ src0vec, const float* __restrict__ initvec,
    const float* __restrict__ attW, const float* __restrict__ attb,
    const float* __restrict__ att_rel, const float* __restrict__ att_rq,
    ushort_t* __restrict__ raw_c, float* __restrict__ att_c, int layer)
{
  constexpr int NCH = L0 ? 2 : 4;
  __shared__ char lds[32768];
  __shared__ int src_s[128], rel_s[128], ge_s[128];
  __shared__ float attw_s[128];

  const int blk = blockIdx.x;
  const int ci0 = blk << 7;
  const int nact = *nact_p;
  if (ci0 >= nact) return;
  const int t = threadIdx.x;
  if (t < 128){
    src_s[t]=src_c[ci0+t]; rel_s[t]=rel_c[ci0+t]; ge_s[t]=ge_c[ci0+t];
    attw_s[t]=attW[layer*384+t];
  }

  const int lane=t&63, wid=t>>6;
  const int wr=wid>>1, wc=wid&1;
  const int rbase=wr<<6, cbase=wc<<6;
  const int lr=lane&15, lk=lane>>4;
  const int swz=(lane&7)<<4;
  const int g=t&7, row0=t>>3;
  const int aswz=(g<<4)^((row0&7)<<4);

  f4 acc[4][4];
  #pragma unroll
  for (int m=0;m<4;++m)
    #pragma unroll
    for (int n=0;n<4;++n) acc[m][n]=(f4){0.f,0.f,0.f,0.f};

  const uint4* imgp = (const uint4*)(img_msg + (size_t)layer*4*8192);
  uint4 pa[4], pr[4], pb[4];
  float4 pf0[4], pf1[4];
  __syncthreads();

  auto issueA = [&](int ch){
    const int d0=(ch&1)<<6;
    const bool cf = L0 || (ch>=2);
    #pragma unroll
    for (int i=0;i<4;++i){
      int row=row0+(i<<5);
      if (cf){
        const float* cp = conf + (((size_t)ge_s[row])<<7) + d0 + (g<<3);
        pf0[i]=*(const float4*)cp; pf1[i]=*(const float4*)(cp+4);
      } else {
        pa[i]=*(const uint4*)&h_bf[(((size_t)src_s[row])<<7)+d0+(g<<3)];
        pr[i]=*(const uint4*)&relt_bf[(((size_t)rel_s[row])<<7)+d0+(g<<3)];
      }
    }
    int ic = L0 ? ch+2 : ch;
    #pragma unroll
    for (int i=0;i<4;++i) pb[i]=imgp[ic*1024+(i<<8)+t];
  };

  issueA(0);
  #pragma unroll
  for (int ch=0; ch<NCH; ++ch){
    const bool cf = L0 || (ch>=2);
    #pragma unroll
    for (int i=0;i<4;++i){
      int row=row0+(i<<5);
      uint4 val;
      if (cf){
        val.x=packbf(pf0[i].x,pf0[i].y); val.y=packbf(pf0[i].z,pf0[i].w);
        val.z=packbf(pf1[i].x,pf1[i].y); val.w=packbf(pf1[i].z,pf1[i].w);
      } else {
        val.x=pmul_bf(pa[i].x,pr[i].x); val.y=pmul_bf(pa[i].y,pr[i].y);
        val.z=pmul_bf(pa[i].z,pr[i].z); val.w=pmul_bf(pa[i].w,pr[i].w);
      }
      *(uint4*)(lds + row*128 + aswz) = val;
    }
    *(uint4*)(lds+16384+(t<<4))        = pb[0];
    *(uint4*)(lds+16384+(t<<4)+4096)   = pb[1];
    *(uint4*)(lds+16384+(t<<4)+8192)   = pb[2];
    *(uint4*)(lds+16384+(t<<4)+12288)  = pb[3];
    __syncthreads();
    if (ch < NCH-1) issueA(ch+1);
    #pragma unroll
    for (int s=0;s<2;++s){
      bfrag af[4], bfr[4];
      #pragma unroll
      for (int m=0;m<4;++m)
        af[m] = *(const bfrag*)(lds + (rbase+(m<<4)+lr)*128 + (((s<<6)+(lk<<4)) ^ swz));
      #pragma unroll
      for (int n=0;n<4;++n)
        bfr[n] = *(const bfrag*)(lds + 16384 + (cbase+(n<<4)+lr)*128 + (((s<<6)+(lk<<4)) ^ swz));
      #pragma unroll
      for (int m=0;m<4;++m)
        #pragma unroll
        for (int n=0;n<4;++n)
          acc[m][n] = __builtin_amdgcn_mfma_f32_16x16x32_bf16(af[m], bfr[n], acc[m][n], 0,0,0);
    }
    __syncthreads();
  }

  // transpose-store raw GEMM result -> LDS bf16 (bias/relu applied in pass 2)
  #pragma unroll
  for (int m=0;m<4;++m)
    #pragma unroll
    for (int n=0;n<4;++n)
      #pragma unroll
      for (int q=0;q<4;++q){
        int row=rbase+(m<<4)+(lk<<2)+q;
        int col=cbase+(n<<4)+lr;
        *(ushort_t*)(lds+(row<<8)+((col<<1)^((row&7)<<4))) = f2bf(acc[m][n][q]);
      }
  __syncthreads();

  #pragma unroll
  for (int i=0;i<8;++i){
    int u=t+(i<<8), row=u>>4, gg=u&15, c0=gg<<3;
    uint4 v = *(const uint4*)(lds+(row<<8)+((gg<<4)^((row&7)<<4)));
    float vv[8] = {bflo(v.x),bfhi(v.x),bflo(v.y),bfhi(v.y),
                   bflo(v.z),bfhi(v.z),bflo(v.w),bfhi(v.w)};
    int rel=rel_s[row], sc=src_s[row], ge=ge_s[row], b=ge>>15;
    const float* rm = relmsg + (((size_t)(layer*NRELS+rel))<<7) + c0;
    float bias[8];
    #pragma unroll
    for (int j=0;j<8;++j) bias[j] = rm[j];
    if (!L0){
      const float* hp = H1 + (((size_t)sc)<<7) + c0;
      #pragma unroll
      for (int j=0;j<8;++j) bias[j] += hp[j];
      if ((sc & (NNODE-1)) == 0){
        const float* iv = initvec + layer*128 + c0;
        #pragma unroll
        for (int j=0;j<8;++j) bias[j] += iv[j];
      }
    } else {
      if ((sc & (NNODE-1)) == 0){
        const float* rh = relhh0 + ((size_t)rel<<7) + c0;
        const float* sv = src0vec + c0;
        #pragma unroll
        for (int j=0;j<8;++j) bias[j] += rh[j] + sv[j];
      }
    }
    float part=0.f;
    unsigned o0,o1,o2,o3;
    {
      float m0=fmaxf(vv[0]+bias[0],0.f), m1=fmaxf(vv[1]+bias[1],0.f);
      float m2=fmaxf(vv[2]+bias[2],0.f), m3=fmaxf(vv[3]+bias[3],0.f);
      float m4=fmaxf(vv[4]+bias[4],0.f), m5=fmaxf(vv[5]+bias[5],0.f);
      float m6=fmaxf(vv[6]+bias[6],0.f), m7=fmaxf(vv[7]+bias[7],0.f);
      part = m0*attw_s[c0] + m1*attw_s[c0+1] + m2*attw_s[c0+2] + m3*attw_s[c0+3]
           + m4*attw_s[c0+4] + m5*attw_s[c0+5] + m6*attw_s[c0+6] + m7*attw_s[c0+7];
      o0=packbf(m0,m1); o1=packbf(m2,m3); o2=packbf(m4,m5); o3=packbf(m6,m7);
    }
    uint4 ov; ov.x=o0; ov.y=o1; ov.z=o2; ov.w=o3;
    *(uint4*)&raw_c[(((size_t)(ci0+row))<<7) + c0] = ov;
    #pragma unroll
    for (int off=1; off<16; off<<=1) part += __shfl_xor(part, off, 16);
    if (gg == 0){
      float a = part + att_rel[layer*NRELS+rel] + att_rq[layer*BB+b] + attb[layer];
      a = (a >= 0.f) ? a : 0.01f*a;
      att_c[ci0+row] = a;
    }
  }
}

// ------------------------------------- per-layer node GEMM: H1 = h @ W1region
#define FMA4(acc, a, bv) do { \
    acc.x = fmaf(a, bv.x, acc.x); \
    acc.y = fmaf(a, bv.y, acc.y); \
    acc.z = fmaf(a, bv.z, acc.z); \
    acc.w = fmaf(a, bv.w, acc.w); } while(0)

__global__ __launch_bounds__(256,2) void h1_gemm_kernel(
    const float* __restrict__ h, const float* __restrict__ msgW,
    float* __restrict__ H1, int layer)
{
  __shared__ float As[64*65];
  __shared__ float Bs[64*128];
  const int t = threadIdx.x, blk = blockIdx.x;   // 128 blocks
  const int n0 = blk << 6;
  const int c = t & 15, r = t >> 4;
  float4 acc0[4], acc1[4];
  #pragma unroll
  for (int i=0;i<4;++i){ acc0[i]=make_float4(0,0,0,0); acc1[i]=make_float4(0,0,0,0); }
  const float* wbase = msgW + (size_t)layer*81920 + 16384;   // rows 128..255

  for (int ch=0; ch<2; ++ch){
    __syncthreads();
    #pragma unroll
    for (int l=0;l<16;++l){
      int idx=(l<<8)+t, ei=idx>>6, kk=idx&63;
      As[ei*65+kk] = h[(size_t)(n0+ei)*DDIM + (ch<<6) + kk];
    }
    #pragma unroll
    for (int l=0;l<32;++l){
      int idx=(l<<8)+t, kk=idx>>7, j=idx&127;
      Bs[(kk<<7)+j] = wbase[((ch<<6)+kk)*DDIM + j];
    }
    __syncthreads();
    #pragma unroll 4
    for (int kk=0;kk<64;++kk){
      const float4 b0 = *(const float4*)&Bs[(kk<<7) + (c<<2)];
      const float4 b1 = *(const float4*)&Bs[(kk<<7) + 64 + (c<<2)];
      #pragma unroll
      for (int i=0;i<4;++i){
        const float a = As[((r<<2)+i)*65 + kk];
        FMA4(acc0[i], a, b0);
        FMA4(acc1[i], a, b1);
      }
    }
  }
  const int col0 = c << 2;
  #pragma unroll
  for (int i=0;i<4;++i){
    const int row = n0 + (r<<2) + i;
    *(float4*)&H1[(size_t)row*DDIM + col0]      = make_float4(acc0[i].x,acc0[i].y,acc0[i].z,acc0[i].w);
    *(float4*)&H1[(size_t)row*DDIM + 64 + col0] = make_float4(acc1[i].x,acc1[i].y,acc1[i].z,acc1[i].w);
  }
}

// --------------------------- per-node softmax + weighted aggregate (contiguous)
__global__ __launch_bounds__(128) void node_agg_kernel(
    const int* __restrict__ base,
    const float* __restrict__ att_c, const float* __restrict__ coef_c,
    const ushort_t* __restrict__ raw_c, float* __restrict__ aggr)
{
  const int n = blockIdx.x;              // BB*NNODE
  const int t = threadIdx.x;             // 128
  const int b0 = base[n], b1 = base[n+1];
  const int deg = b1 - b0;
  if (deg == 0){ aggr[((size_t)n<<7)+t] = 0.f; return; }
  __shared__ float w_s[128];
  __shared__ float red[4];
  float mx = -3.0e38f;
  for (int j=t; j<deg; j+=128) mx = fmaxf(mx, att_c[b0+j]);
  #pragma unroll
  for (int o=1;o<64;o<<=1) mx = fmaxf(mx, __shfl_xor(mx, o, 64));
  if ((t&63)==0) red[t>>6] = mx;
  __syncthreads();
  mx = fmaxf(red[0], red[1]);
  float s = 0.f;
  for (int j=t; j<deg; j+=128) s += expf(att_c[b0+j]-mx);
  #pragma unroll
  for (int o=1;o<64;o<<=1) s += __shfl_xor(s, o, 64);
  if ((t&63)==0) red[2+(t>>6)] = s;
  __syncthreads();
  const float inv = 1.0f/((red[2]+red[3]) + 1e-8f);
  float accv = 0.f;
  for (int jb=0; jb<deg; jb+=128){
    int jj = jb + t;
    __syncthreads();
    if (jj < deg) w_s[t] = coef_c[b0+jj] * expf(att_c[b0+jj]-mx) * inv;
    __syncthreads();
    int lim = min(128, deg-jb);
    for (int j=0; j<lim; ++j)
      accv = fmaf(w_s[j], bf2f(raw_c[(((size_t)(b0+jb+j))<<7)+t]), accv);
  }
  aggr[((size_t)n<<7)+t] = accv;
}

// --------------------------------------------- h = LN(h + aggr@updW + updb)
__global__ __launch_bounds__(256,2) void update_kernel(
    const float* __restrict__ aggr, const float* __restrict__ updW,
    const float* __restrict__ updb,
    const float* __restrict__ lng, const float* __restrict__ lnb,
    float* __restrict__ h, ushort_t* __restrict__ h_bf,
    float* __restrict__ out, int layer)
{
  __shared__ float As[64*65];
  __shared__ float Bs[64*128];
  const int t = threadIdx.x, blk = blockIdx.x;   // 128 blocks
  const int n0 = blk << 6;
  const int c = t & 15, r = t >> 4;
  float4 acc0[4], acc1[4];
  #pragma unroll
  for (int i=0;i<4;++i){ acc0[i]=make_float4(0,0,0,0); acc1[i]=make_float4(0,0,0,0); }
  const float* wbase = updW + (size_t)layer*DDIM*DDIM;

  for (int ch=0; ch<2; ++ch){
    __syncthreads();
    #pragma unroll
    for (int l=0;l<16;++l){
      int idx=(l<<8)+t, ei=idx>>6, kk=idx&63;
      As[ei*65+kk] = aggr[(size_t)(n0+ei)*DDIM + (ch<<6) + kk];
    }
    #pragma unroll
    for (int l=0;l<32;++l){
      int idx=(l<<8)+t, kk=idx>>7, j=idx&127;
      Bs[(kk<<7)+j] = wbase[((ch<<6)+kk)*DDIM + j];
    }
    __syncthreads();
    #pragma unroll 4
    for (int kk=0;kk<64;++kk){
      const float4 b0 = *(const float4*)&Bs[(kk<<7) + (c<<2)];
      const float4 b1 = *(const float4*)&Bs[(kk<<7) + 64 + (c<<2)];
      #pragma unroll
      for (int i=0;i<4;++i){
        const float a = As[((r<<2)+i)*65 + kk];
        FMA4(acc0[i], a, b0);
        FMA4(acc1[i], a, b1);
      }
    }
  }

  const int col0 = c << 2;
  float ub0[4], ub1[4], g0[4], g1[4], lb0[4], lb1[4];
  #pragma unroll
  for (int q=0;q<4;++q){
    ub0[q] = updb[layer*DDIM + col0+q];  ub1[q] = updb[layer*DDIM + 64+col0+q];
    g0[q]  = lng[col0+q];                g1[q]  = lng[64+col0+q];
    lb0[q] = lnb[col0+q];                lb1[q] = lnb[64+col0+q];
  }

  #pragma unroll
  for (int i=0;i<4;++i){
    const int row = n0 + (r<<2) + i;
    float* hrow = h + (size_t)row*DDIM;
    float4 h0 = *(float4*)&hrow[col0];
    float4 h1 = *(float4*)&hrow[64+col0];
    float x0[4], x1[4];
    x0[0] = h0.x + acc0[i].x + ub0[0];
    x0[1] = h0.y + acc0[i].y + ub0[1];
    x0[2] = h0.z + acc0[i].z + ub0[2];
    x0[3] = h0.w + acc0[i].w + ub0[3];
    x1[0] = h1.x + acc1[i].x + ub1[0];
    x1[1] = h1.y + acc1[i].y + ub1[1];
    x1[2] = h1.z + acc1[i].z + ub1[2];
    x1[3] = h1.w + acc1[i].w + ub1[3];
    float s = 0.f, s2 = 0.f;
    #pragma unroll
    for (int q=0;q<4;++q){ s += x0[q]+x1[q]; s2 += x0[q]*x0[q] + x1[q]*x1[q]; }
    #pragma unroll
    for (int off=1; off<16; off<<=1){
      s  += __shfl_xor(s,  off, 16);
      s2 += __shfl_xor(s2, off, 16);
    }
    const float mu = s * (1.0f/128.0f);
    const float var = s2 * (1.0f/128.0f) - mu*mu;
    const float rstd = rsqrtf(var + 1e-5f);
    float4 y0, y1;
    y0.x = (x0[0]-mu)*rstd*g0[0] + lb0[0];
    y0.y = (x0[1]-mu)*rstd*g0[1] + lb0[1];
    y0.z = (x0[2]-mu)*rstd*g0[2] + lb0[2];
    y0.w = (x0[3]-mu)*rstd*g0[3] + lb0[3];
    y1.x = (x1[0]-mu)*rstd*g1[0] + lb1[0];
    y1.y = (x1[1]-mu)*rstd*g1[1] + lb1[1];
    y1.z = (x1[2]-mu)*rstd*g1[2] + lb1[2];
    y1.w = (x1[3]-mu)*rstd*g1[3] + lb1[3];
    *(float4*)&hrow[col0] = y0;
    *(float4*)&hrow[64+col0] = y1;
    ushort4 z0, z1;
    z0.x=f2bf(y0.x); z0.y=f2bf(y0.y); z0.z=f2bf(y0.z); z0.w=f2bf(y0.w);
    z1.x=f2bf(y1.x); z1.y=f2bf(y1.y); z1.z=f2bf(y1.z); z1.w=f2bf(y1.w);
    *(ushort4*)&h_bf[(size_t)row*DDIM + col0] = z0;
    *(ushort4*)&h_bf[(size_t)row*DDIM + 64 + col0] = z1;
    if ((row & (NNODE-1)) == 0){
      const int bb_ = row >> 11;
      float* op = out + (size_t)(bb_*NL + layer)*DDIM;
      *(float4*)&op[col0] = y0;
      *(float4*)&op[64+col0] = y1;
    }
  }
}

// ------------------------------------------------------------------ launcher
extern "C" void kernel_launch(void* const* d_in, const int* in_sizes, int n_in,
                              void* d_out, int out_size, void* d_ws, size_t ws_size,
                              hipStream_t stream) {
  const int*   edge_index = (const int*)d_in[0];
  const int*   rels       = (const int*)d_in[1];
  const float* scores     = (const float*)d_in[2];
  const void*  cm_raw     = d_in[3];
  const void*  em_raw     = d_in[4];
  const float* rq    = (const float*)d_in[6];
  const float* conf  = (const float*)d_in[7];
  const float* relt  = (const float*)d_in[8];
  const float* betaW = (const float*)d_in[9];
  const float* betab = (const float*)d_in[10];
  const float* msgW  = (const float*)d_in[11];
  const float* msgb  = (const float*)d_in[12];
  const float* updW  = (const float*)d_in[13];
  const float* updb  = (const float*)d_in[14];
  const float* lng   = (const float*)d_in[15];
  const float* lnb   = (const float*)d_in[16];
  const float* attW  = (const float*)d_in[17];
  const float* attb  = (const float*)d_in[18];
  const float* denW1 = (const float*)d_in[19];
  const float* denb1 = (const float*)d_in[20];
  const float* denW2 = (const float*)d_in[21];
  const float* denb2 = (const float*)d_in[22];
  float* out = (float*)d_out;
  char* ws = (char*)d_ws;

  size_t off = 0;
  float* h        = (float*)(ws + off); off += (size_t)BB*NNODE*DDIM*4;      //  4 MB
  ushort_t* h_bf  = (ushort_t*)(ws + off); off += (size_t)BB*NNODE*DDIM*2;   //  2 MB
  float* aggr     = (float*)(ws + off); off += (size_t)BB*NNODE*DDIM*4;      //  4 MB
  float* H1       = (float*)(ws + off); off += (size_t)BB*NNODE*DDIM*4;      //  4 MB
  ushort_t* raw_c = (ushort_t*)(ws + off); off += (size_t)BB*NE*DDIM*2;      // 32 MB
  float* att_c    = (float*)(ws + off); off += (size_t)BB*NE*4;              // 512 KB
  float* coef_c   = (float*)(ws + off); off += (size_t)BB*NE*4;              // 512 KB
  int* src_c      = (int*)(ws + off); off += (size_t)BB*NE*4;
  int* rel_c      = (int*)(ws + off); off += (size_t)BB*NE*4;
  int* ge_c       = (int*)(ws + off); off += (size_t)BB*NE*4;
  int* deg        = (int*)(ws + off); off += (size_t)BB*NNODE*4;
  int* base       = (int*)(ws + off); off += (size_t)(BB*NNODE+16)*4;
  int* cursor     = (int*)(ws + off); off += (size_t)BB*NNODE*4;
  ushort_t* relt_bf = (ushort_t*)(ws + off); off += (size_t)NRELS*DDIM*2 + 64;
  ushort_t* rq_bf   = (ushort_t*)(ws + off); off += (size_t)BB*DDIM*2 + 64;
  ushort_t* img_msg = (ushort_t*)(ws + off); off += (size_t)12*8192*2;       // 192 KB
  ushort_t* img_den = (ushort_t*)(ws + off); off += (size_t)2*8192*2;        //  32 KB
  ushort_t* img_tab = (ushort_t*)(ws + off); off += (size_t)8*8192*2;        // 128 KB
  float* relmsg   = (float*)(ws + off); off += (size_t)3*NRELS*DDIM*4;       // 1.5 MB
  float* relhh0   = (float*)(ws + off); off += (size_t)NRELS*DDIM*4;         // 512 KB
  float* denrel   = (float*)(ws + off); off += (size_t)NRELS*DDIM*4;         // 512 KB
  float* denrq    = (float*)(ws + off); off += (size_t)BB*DDIM*4;
  float* initvec  = (float*)(ws + off); off += 3*DDIM*4;
  float* src0vec  = (float*)(ws + off); off += DDIM*4;
  float* att_rel  = (float*)(ws + off); off += 3*NRELS*4 + 32;
  float* att_rq   = (float*)(ws + off); off += 64;
  float* beta_rel = (float*)(ws + off); off += NRELS*4 + 32;
  float* beta_rq  = (float*)(ws + off); off += 64;
  uint8_t* cm_dec = (uint8_t*)(ws + off); off += (size_t)BB*NE;
  uint8_t* em_dec = (uint8_t*)(ws + off); off += (size_t)BB*NE;

  prep_kernel<<<1024, 256, 0, stream>>>(cm_raw, em_raw, cm_dec, em_dec, deg,
                                        relt, relt_bf, rq, rq_bf,
                                        src_c, rel_c, ge_c, h, h_bf);
  csr_hist_kernel<<<512, 256, 0, stream>>>(edge_index, em_dec, deg);
  csr_scan_kernel<<<1, 256, 0, stream>>>(deg, base, cursor);
  csr_scatter_kernel<<<512, 256, 0, stream>>>(edge_index, rels, em_dec, cursor,
                                              src_c, rel_c, ge_c);
  precomp_tables_kernel<<<1006, 256, 0, stream>>>(relt, rq, attW, betaW,
                                                  msgW, denW1, denb1,
                                                  att_rel, att_rq, beta_rel, beta_rq,
                                                  denrq, initvec, src0vec);
  build_wimg_kernel<<<704, 256, 0, stream>>>(msgW, denW1, img_msg, img_den, img_tab);
  table_gemm_kernel<<<40, 256, 0, stream>>>(relt_bf, img_msg, img_tab, msgb,
                                            relmsg, relhh0, denrel);
  coef_mfma_kernel<<<1024, 256, 0, stream>>>(base + BB*NNODE, rel_c, ge_c, conf, img_den,
                                             denrel, denrq, denW2, denb2,
                                             scores, cm_dec, beta_rel, beta_rq, betab,
                                             coef_c);
  for (int k = 0; k < NL; ++k){
    if (k == 0){
      msg_mfma_kernel<true><<<1024, 256, 0, stream>>>(base + BB*NNODE, src_c, rel_c, ge_c,
          relt_bf, conf, h_bf, H1, img_msg, relmsg, relhh0, src0vec, initvec,
          attW, attb, att_rel, att_rq, raw_c, att_c, k);
    } else {
      h1_gemm_kernel<<<128, 256, 0, stream>>>(h, msgW, H1, k);
      msg_mfma_kernel<false><<<1024, 256, 0, stream>>>(base + BB*NNODE, src_c, rel_c, ge_c,
          relt_bf, conf, h_bf, H1, img_msg, relmsg, relhh0, src0vec, initvec,
          attW, attb, att_rel, att_rq, raw_c, att_c, k);
    }
    node_agg_kernel<<<BB*NNODE, 128, 0, stream>>>(base, att_c, coef_c, raw_c, aggr);
    update_kernel<<<128, 256, 0, stream>>>(aggr, updW, updb, lng, lnb, h, h_bf, out, k);
  }
}

// Round 8
// 366.228 us; speedup vs baseline: 1.6295x; 1.0451x over previous
//
#include <hip/hip_runtime.h>
#include <stdint.h>
#include <math.h>

#define BB 4
#define NNODE 2048
#define NE 32768
#define DDIM 128
#define NL 3
#define NRELS 1000
#define MASKV -1000000000.0f

typedef unsigned short ushort_t;
typedef __attribute__((ext_vector_type(8))) short bfrag;   // 8 bf16 (4 VGPR)
typedef __attribute__((ext_vector_type(4))) float f4;

__device__ __forceinline__ float sigf(float x){ return 1.0f/(1.0f+expf(-x)); }

__device__ __forceinline__ float bf2f(ushort_t u){
  union { unsigned int i; float f; } v; v.i = ((unsigned int)u) << 16; return v.f;
}
__device__ __forceinline__ ushort_t f2bf(float x){
  union { float f; unsigned int u; } v; v.f = x;
  unsigned int r = (v.u + 0x7FFFu + ((v.u >> 16) & 1u)) >> 16;  // RNE
  return (ushort_t)r;
}
__device__ __forceinline__ float bflo(unsigned u){
  union{unsigned i;float f;}v; v.i=u<<16; return v.f;
}
__device__ __forceinline__ float bfhi(unsigned u){
  union{unsigned i;float f;}v; v.i=u&0xFFFF0000u; return v.f;
}
__device__ __forceinline__ unsigned pmul_bf(unsigned a, unsigned b){
  return (unsigned)f2bf(bflo(a)*bflo(b)) | ((unsigned)f2bf(bfhi(a)*bfhi(b))<<16);
}
__device__ __forceinline__ unsigned packbf(float a, float b){
  return (unsigned)f2bf(a) | ((unsigned)f2bf(b)<<16);
}

// ================= mega-prep: probe+masks+defaults, deg=0, relt_bf, h init,
// weight LDS-images, scalar tables, tiny vector tables — all input-only deps.
__global__ void prep_kernel(const void* cm_raw, const void* em_raw,
    uint8_t* __restrict__ cm, uint8_t* __restrict__ em, int* __restrict__ deg,
    const float* __restrict__ relt, ushort_t* __restrict__ relt_bf,
    const float* __restrict__ rq,
    const float* __restrict__ attW, const float* __restrict__ betaW,
    const float* __restrict__ msgW, const float* __restrict__ denW1,
    const float* __restrict__ denb1,
    int* __restrict__ src_c, int* __restrict__ rel_c, int* __restrict__ ge_c,
    float* __restrict__ h, ushort_t* __restrict__ h_bf,
    ushort_t* __restrict__ img_msg, ushort_t* __restrict__ img_den,
    ushort_t* __restrict__ img_tab,
    float* __restrict__ att_rel, float* __restrict__ att_rq,
    float* __restrict__ beta_rel, float* __restrict__ beta_rq,
    float* __restrict__ denrq, float* __restrict__ initvec,
    float* __restrict__ src0vec)
{
  __shared__ int flag_s;
  if (threadIdx.x < 64){
    unsigned v = ((const unsigned*)cm_raw)[threadIdx.x];
    bool i32ok = (v <= 1u);
    bool f32ok = (v == 0u) || (v == 0x3F800000u);
    unsigned long long bi = __ballot(i32ok);
    unsigned long long bf_ = __ballot(f32ok);
    if (threadIdx.x == 0) flag_s = (bi==~0ULL) ? 0 : ((bf_==~0ULL) ? 1 : 2);
  }
  __syncthreads();
  const int f = flag_s;
  const int gid = blockIdx.x*256 + threadIdx.x;    // 1024 blocks = 262144 thr

  // ---- masks + compact-array defaults
  if (gid < BB*NE){
    uint8_t c, e;
    if (f == 0){ c = ((const int*)cm_raw)[gid]!=0;   e = ((const int*)em_raw)[gid]!=0; }
    else if (f == 1){ c = ((const float*)cm_raw)[gid]!=0.0f; e = ((const float*)em_raw)[gid]!=0.0f; }
    else { c = ((const uint8_t*)cm_raw)[gid]!=0; e = ((const uint8_t*)em_raw)[gid]!=0; }
    cm[gid]=c; em[gid]=e;
    src_c[gid]=0; rel_c[gid]=0; ge_c[gid]=0;
  }
  // ---- deg zero
  if (gid < BB*NNODE) deg[gid]=0;
  // ---- relt -> bf16
  if (gid < NRELS*DDIM/4){
    float4 v = *(const float4*)&relt[gid*4];
    ushort4 o; o.x=f2bf(v.x); o.y=f2bf(v.y); o.z=f2bf(v.z); o.w=f2bf(v.w);
    *(ushort4*)&relt_bf[gid*4] = o;
  }
  // ---- h init (all 262144 threads)
  {
    int base = gid*4;
    int nd = base & (NNODE*DDIM - 1);
    bool one = (nd < DDIM);
    float4 hv = one ? (float4){1.f,1.f,1.f,1.f} : (float4){0.f,0.f,0.f,0.f};
    ushort4 hb = one ? (ushort4){0x3F80,0x3F80,0x3F80,0x3F80} : (ushort4){0,0,0,0};
    *(float4*)&h[base] = hv;
    *(ushort4*)&h_bf[base] = hb;
  }
  // ---- weight LDS-images (transposed, swizzled, bf16)
  if (gid < 22*8192){
    int img_id = gid >> 13;
    int ei = gid & 8191;
    int j = ei >> 6;
    int kk = (((ei & 63) << 1) ^ ((j & 7) << 4)) >> 1;
    float v; ushort_t* dst;
    if (img_id < 12){
      int k = img_id >> 2, c = img_id & 3;
      int rowbase = (c < 2) ? c*64 : 512 + (c-2)*64;
      v = msgW[(size_t)k*81920 + (rowbase+kk)*128 + j];
      dst = img_msg + (size_t)img_id*8192;
    } else if (img_id < 14){
      int c = img_id - 12;
      v = denW1[(size_t)(256 + c*64 + kk)*128 + j];
      dst = img_den + (size_t)c*8192;
    } else if (img_id < 20){
      int idx = img_id - 14, k = idx >> 1, c = idx & 1;
      v = msgW[(size_t)k*81920 + (384 + c*64 + kk)*128 + j];
      dst = img_tab + (size_t)idx*8192;
    } else {
      int c = img_id - 20;
      v = denW1[(size_t)(c*64 + kk)*128 + j];
      dst = img_tab + (size_t)(6+c)*8192;
    }
    dst[ei] = f2bf(v);
  }
  // ---- scalar tables (att/beta) + tiny vector rows
  {
    int wid = gid >> 6;
    int lane = threadIdx.x & 63;
    if (wid < 4016){
      const float* vec; const float* w; float* dst; int di;
      if (wid < 3*NRELS){
        int k = wid/1000, rl = wid%1000;
        vec = relt + rl*DDIM; w = attW + k*384 + 128; dst = att_rel; di = wid;
      } else if (wid < 3*NRELS + 3*BB){
        int idx = wid - 3*NRELS; int k = idx/BB, b = idx%BB;
        vec = rq + b*DDIM; w = attW + k*384 + 256; dst = att_rq; di = idx;
      } else if (wid < 3*NRELS + 3*BB + NRELS){
        int rl = wid - (3*NRELS + 3*BB);
        vec = relt + rl*DDIM; w = betaW; dst = beta_rel; di = rl;
      } else {
        int b = wid - (3*NRELS + 3*BB + NRELS);
        vec = rq + b*DDIM; w = betaW; dst = beta_rq; di = b;
      }
      float s = vec[lane]*w[lane] + vec[lane+64]*w[lane+64];
      #pragma unroll
      for (int off=32; off; off>>=1) s += __shfl_xor(s, off, 64);
      if (lane == 0) dst[di] = s;
    } else if (wid < 4024){
      int widx = wid - 4016;
      const float* A = nullptr; const float* W; int K = 128;
      float* outp; const float* bias = nullptr;
      if (widx < 4){ A = rq + widx*128; W = denW1 + 16384; outp = denrq + widx*128; bias = denb1; }
      else if (widx < 7){ int k=widx-4; W = msgW + (size_t)k*81920 + 32768; outp = initvec + k*128; }
      else { W = msgW + 16384; K = 256; outp = src0vec; }
      float a0=0.f, a1=0.f;
      for (int kk=0; kk<K; kk+=8){
        float av[8], w0[8], w1[8];
        #pragma unroll
        for (int u=0;u<8;++u){
          av[u] = A ? A[kk+u] : 1.0f;
          w0[u] = W[(size_t)(kk+u)*128 + lane];
          w1[u] = W[(size_t)(kk+u)*128 + lane + 64];
        }
        #pragma unroll
        for (int u=0;u<8;++u){ a0 = fmaf(av[u], w0[u], a0); a1 = fmaf(av[u], w1[u], a1); }
      }
      if (bias){ a0 += bias[lane]; a1 += bias[lane+64]; }
      outp[lane] = a0; outp[lane+64] = a1;
    }
  }
}

// ------------------------------------------------------------ CSR build (filtered)
__global__ void csr_hist_kernel(const int* __restrict__ edge_index,
                                const uint8_t* __restrict__ em, int* __restrict__ deg){
  int gid = blockIdx.x*256 + threadIdx.x;          // B*E
  if (!em[gid]) return;
  int b = gid >> 15, e = gid & (NE-1);
  int tgt = edge_index[(b<<16) + NE + e];
  atomicAdd(&deg[(b<<11) + tgt], 1);
}
__global__ void csr_scan_kernel(const int* __restrict__ deg,
                                int* __restrict__ base, int* __restrict__ cursor){
  __shared__ int part[256];
  int t = threadIdx.x;                             // 256 threads, 1 block
  int loc[32]; int s = 0;
  #pragma unroll
  for (int i=0;i<32;++i){ loc[i] = deg[t*32+i]; s += loc[i]; }
  part[t] = s; __syncthreads();
  for (int off=1; off<256; off<<=1){
    int v = (t >= off) ? part[t-off] : 0;
    __syncthreads();
    part[t] += v;
    __syncthreads();
  }
  int ex = (t==0) ? 0 : part[t-1];
  #pragma unroll
  for (int i=0;i<32;++i){ base[t*32+i] = ex; cursor[t*32+i] = ex; ex += loc[i]; }
  if (t == 255) base[256*32] = ex;       // nact
}
__global__ void csr_scatter_kernel(const int* __restrict__ edge_index,
                                   const int* __restrict__ rels,
                                   const uint8_t* __restrict__ em,
                                   int* __restrict__ cursor,
                                   int* __restrict__ src_c, int* __restrict__ rel_c,
                                   int* __restrict__ ge_c){
  int gid = blockIdx.x*256 + threadIdx.x;          // B*E
  if (!em[gid]) return;
  int b = gid >> 15, e = gid & (NE-1);
  int tgt = edge_index[(b<<16) + NE + e];
  int src = edge_index[(b<<16) + e];
  int pos = atomicAdd(&cursor[(b<<11) + tgt], 1);
  src_c[pos] = (b<<11) | src;
  rel_c[pos] = rels[gid];
  ge_c[pos]  = gid;
}

// ===================== MFMA table GEMM: {relmsg, relhh0, denrel} = relt @ B
__global__ __launch_bounds__(256,2) void table_gemm_kernel(
    const ushort_t* __restrict__ relt_bf, const ushort_t* __restrict__ img_msg,
    const ushort_t* __restrict__ img_tab, const float* __restrict__ msgb,
    float* __restrict__ relmsg, float* __restrict__ relhh0,
    float* __restrict__ denrel)
{
  __shared__ char lds[32768];
  __shared__ float bias_s[128];
  const int blk = blockIdx.x;      // 40 = 8 row-tiles x 5 jobs
  const int job = blk % 5;
  const int ri0 = (blk/5) << 7;
  const int t = threadIdx.x;
  const uint4* imgb;
  float* outp;
  if (job < 3){ imgb = (const uint4*)(img_tab + (size_t)(2*job)*8192); outp = relmsg + (size_t)job*NRELS*DDIM; }
  else if (job == 3){ imgb = (const uint4*)img_msg; outp = relhh0; }
  else { imgb = (const uint4*)(img_tab + (size_t)6*8192); outp = denrel; }
  if (t < 128) bias_s[t] = (job < 3) ? msgb[job*128 + t] : 0.f;

  const int lane=t&63, wid=t>>6;
  const int wr=wid>>1, wc=wid&1;
  const int rbase=wr<<6, cbase=wc<<6;
  const int lr=lane&15, lk=lane>>4;
  const int swz=(lane&7)<<4;
  const int g=t&7, row0=t>>3;
  const int aswz=(g<<4)^((row0&7)<<4);

  f4 acc[4][4];
  #pragma unroll
  for (int m=0;m<4;++m)
    #pragma unroll
    for (int n=0;n<4;++n) acc[m][n]=(f4){0.f,0.f,0.f,0.f};

  uint4 pa[4], pb[4];
  auto issueA = [&](int ch){
    #pragma unroll
    for (int i=0;i<4;++i){
      int rr = ri0 + row0 + (i<<5);
      rr = (rr < NRELS) ? rr : (NRELS-1);
      pa[i] = *(const uint4*)&relt_bf[(size_t)rr*128 + (ch<<6) + (g<<3)];
    }
    #pragma unroll
    for (int i=0;i<4;++i) pb[i] = imgb[ch*1024 + (i<<8) + t];
  };

  __syncthreads();
  issueA(0);
  #pragma unroll
  for (int ch=0; ch<2; ++ch){
    #pragma unroll
    for (int i=0;i<4;++i){
      int row = row0 + (i<<5);
      *(uint4*)(lds + row*128 + aswz) = pa[i];
    }
    *(uint4*)(lds+16384+(t<<4))        = pb[0];
    *(uint4*)(lds+16384+(t<<4)+4096)   = pb[1];
    *(uint4*)(lds+16384+(t<<4)+8192)   = pb[2];
    *(uint4*)(lds+16384+(t<<4)+12288)  = pb[3];
    __syncthreads();
    if (ch < 1) issueA(ch+1);
    #pragma unroll
    for (int s=0;s<2;++s){
      bfrag af[4], bfr[4];
      #pragma unroll
      for (int m=0;m<4;++m)
        af[m] = *(const bfrag*)(lds + (rbase+(m<<4)+lr)*128 + (((s<<6)+(lk<<4)) ^ swz));
      #pragma unroll
      for (int n=0;n<4;++n)
        bfr[n] = *(const bfrag*)(lds + 16384 + (cbase+(n<<4)+lr)*128 + (((s<<6)+(lk<<4)) ^ swz));
      #pragma unroll
      for (int m=0;m<4;++m)
        #pragma unroll
        for (int n=0;n<4;++n)
          acc[m][n] = __builtin_amdgcn_mfma_f32_16x16x32_bf16(af[m], bfr[n], acc[m][n], 0,0,0);
    }
    __syncthreads();
  }

  #pragma unroll
  for (int m=0;m<4;++m)
    #pragma unroll
    for (int n=0;n<4;++n){
      int col = cbase + (n<<4) + lr;
      float bv = bias_s[col];
      #pragma unroll
      for (int q=0;q<4;++q){
        int gr = ri0 + rbase + (m<<4) + (lk<<2) + q;
        if (gr < NRELS) outp[(size_t)gr*128 + col] = acc[m][n][q] + bv;
      }
    }
}

// ================================================= MFMA coef kernel (K=128, compact)
__global__ __launch_bounds__(256,2) void coef_mfma_kernel(
    const int* __restrict__ nact_p,
    const int* __restrict__ rel_c, const int* __restrict__ ge_c,
    const float* __restrict__ conf, const ushort_t* __restrict__ img_den,
    const float* __restrict__ denrel, const float* __restrict__ denrq,
    const float* __restrict__ denW2, const float* __restrict__ denb2,
    const float* __restrict__ scores, const uint8_t* __restrict__ cm,
    const float* __restrict__ beta_rel, const float* __restrict__ beta_rq,
    const float* __restrict__ betab,
    float* __restrict__ coef_c)
{
  __shared__ char lds[32768];
  __shared__ int rel_s[128], ge_s[128];
  __shared__ float w2_s[128];

  const int blk = blockIdx.x;
  const int ci0 = blk << 7;
  const int nact = *nact_p;
  if (ci0 >= nact) return;
  const int t = threadIdx.x;
  if (t < 128){ rel_s[t]=rel_c[ci0+t]; ge_s[t]=ge_c[ci0+t]; w2_s[t]=denW2[t]; }

  const int lane=t&63, wid=t>>6;
  const int wr=wid>>1, wc=wid&1;
  const int rbase=wr<<6, cbase=wc<<6;
  const int lr=lane&15, lk=lane>>4;
  const int swz=(lane&7)<<4;
  const int g=t&7, row0=t>>3;
  const int aswz=(g<<4)^((row0&7)<<4);

  f4 acc[4][4];
  #pragma unroll
  for (int m=0;m<4;++m)
    #pragma unroll
    for (int n=0;n<4;++n) acc[m][n]=(f4){0.f,0.f,0.f,0.f};

  const uint4* imgp = (const uint4*)img_den;
  float4 pf0[4], pf1[4];
  uint4 pb[4];
  __syncthreads();

  auto issueA = [&](int ch){
    const int d0=(ch&1)<<6;
    #pragma unroll
    for (int i=0;i<4;++i){
      int row=row0+(i<<5);
      const float* cp = conf + (((size_t)ge_s[row])<<7) + d0 + (g<<3);
      pf0[i]=*(const float4*)cp; pf1[i]=*(const float4*)(cp+4);
    }
    #pragma unroll
    for (int i=0;i<4;++i) pb[i]=imgp[ch*1024+(i<<8)+t];
  };

  issueA(0);
  #pragma unroll
  for (int ch=0; ch<2; ++ch){
    #pragma unroll
    for (int i=0;i<4;++i){
      int row=row0+(i<<5);
      uint4 val;
      val.x=packbf(pf0[i].x,pf0[i].y); val.y=packbf(pf0[i].z,pf0[i].w);
      val.z=packbf(pf1[i].x,pf1[i].y); val.w=packbf(pf1[i].z,pf1[i].w);
      *(uint4*)(lds + row*128 + aswz) = val;
    }
    *(uint4*)(lds+16384+(t<<4))        = pb[0];
    *(uint4*)(lds+16384+(t<<4)+4096)   = pb[1];
    *(uint4*)(lds+16384+(t<<4)+8192)   = pb[2];
    *(uint4*)(lds+16384+(t<<4)+12288)  = pb[3];
    __syncthreads();
    if (ch < 1) issueA(ch+1);
    #pragma unroll
    for (int s=0;s<2;++s){
      bfrag af[4], bfr[4];
      #pragma unroll
      for (int m=0;m<4;++m)
        af[m] = *(const bfrag*)(lds + (rbase+(m<<4)+lr)*128 + (((s<<6)+(lk<<4)) ^ swz));
      #pragma unroll
      for (int n=0;n<4;++n)
        bfr[n] = *(const bfrag*)(lds + 16384 + (cbase+(n<<4)+lr)*128 + (((s<<6)+(lk<<4)) ^ swz));
      #pragma unroll
      for (int m=0;m<4;++m)
        #pragma unroll
        for (int n=0;n<4;++n)
          acc[m][n] = __builtin_amdgcn_mfma_f32_16x16x32_bf16(af[m], bfr[n], acc[m][n], 0,0,0);
    }
    __syncthreads();
  }

  // transpose-store acc -> LDS bf16 (bias applied in pass 2)
  #pragma unroll
  for (int m=0;m<4;++m)
    #pragma unroll
    for (int n=0;n<4;++n)
      #pragma unroll
      for (int q=0;q<4;++q){
        int row=rbase+(m<<4)+(lk<<2)+q;
        int col=cbase+(n<<4)+lr;
        *(ushort_t*)(lds+(row<<8)+((col<<1)^((row&7)<<4))) = f2bf(acc[m][n][q]);
      }
  __syncthreads();

  #pragma unroll
  for (int i=0;i<8;++i){
    int u=t+(i<<8), row=u>>4, gg=u&15, c0=gg<<3;
    uint4 v = *(const uint4*)(lds+(row<<8)+((gg<<4)^((row&7)<<4)));
    float vv[8] = {bflo(v.x),bfhi(v.x),bflo(v.y),bfhi(v.y),
                   bflo(v.z),bfhi(v.z),bflo(v.w),bfhi(v.w)};
    int rel=rel_s[row], ge=ge_s[row], b=ge>>15;
    const float* dr = denrel + ((size_t)rel<<7) + c0;
    const float* dq = denrq + (b<<7) + c0;
    float part=0.f;
    #pragma unroll
    for (int j=0;j<8;++j){
      float m = fmaxf(vv[j] + dr[j] + dq[j], 0.f);
      part = fmaf(m, w2_s[c0+j], part);
    }
    #pragma unroll
    for (int off=1; off<16; off<<=1) part += __shfl_xor(part, off, 16);
    if (gg == 0){
      float den = sigf(part + denb2[0]);
      float beta = sigf(beta_rel[rel] + beta_rq[b] + betab[0]);
      float gt = cm[ge] ? sigf((scores[ge]-beta)*10.0f) : 0.5f;
      coef_c[ci0+row] = gt * den;
    }
  }
}

// ================================================= MFMA msg kernel (compact)
template<bool L0>
__global__ __launch_bounds__(256,2) void msg_mfma_kernel(
    const int* __restrict__ nact_p,
    const int* __restrict__ src_c, const int* __restrict__ rel_c,
    const int* __restrict__ ge_c,
    const ushort_t* __restrict__ relt_bf, const float* __restrict__ conf,
    const ushort_t* __restrict__ h_bf, const float* __restrict__ H1,
    const ushort_t* __restrict__ img_msg,
    const float* __restrict__ relmsg, const float* __restrict__ relhh0,
    const float* __restrict__ src0vec, const float* __restrict__ initvec,
    const float* __restrict__ attW, const float* __restrict__ attb,
    const float* __restrict__ att_rel, const float* __restrict__ att_rq,
    ushort_t* __restrict__ raw_c, float* __restrict__ att_c, int layer)
{
  constexpr int NCH = L0 ? 2 : 4;
  __shared__ char lds[32768];
  __shared__ int src_s[128], rel_s[128], ge_s[128];
  __shared__ float attw_s[128];

  const int blk = blockIdx.x;
  const int ci0 = blk << 7;
  const int nact = *nact_p;
  if (ci0 >= nact) return;
  const int t = threadIdx.x;
  if (t < 128){
    src_s[t]=src_c[ci0+t]; rel_s[t]=rel_c[ci0+t]; ge_s[t]=ge_c[ci0+t];
    attw_s[t]=attW[layer*384+t];
  }

  const int lane=t&63, wid=t>>6;
  const int wr=wid>>1, wc=wid&1;
  const int rbase=wr<<6, cbase=wc<<6;
  const int lr=lane&15, lk=lane>>4;
  const int swz=(lane&7)<<4;
  const int g=t&7, row0=t>>3;
  const int aswz=(g<<4)^((row0&7)<<4);

  f4 acc[4][4];
  #pragma unroll
  for (int m=0;m<4;++m)
    #pragma unroll
    for (int n=0;n<4;++n) acc[m][n]=(f4){0.f,0.f,0.f,0.f};

  const uint4* imgp = (const uint4*)(img_msg + (size_t)layer*4*8192);
  uint4 pa[4], pr[4], pb[4];
  float4 pf0[4], pf1[4];
  __syncthreads();

  auto issueA = [&](int ch){
    const int d0=(ch&1)<<6;
    const bool cf = L0 || (ch>=2);
    #pragma unroll
    for (int i=0;i<4;++i){
      int row=row0+(i<<5);
      if (cf){
        const float* cp = conf + (((size_t)ge_s[row])<<7) + d0 + (g<<3);
        pf0[i]=*(const float4*)cp; pf1[i]=*(const float4*)(cp+4);
      } else {
        pa[i]=*(const uint4*)&h_bf[(((size_t)src_s[row])<<7)+d0+(g<<3)];
        pr[i]=*(const uint4*)&relt_bf[(((size_t)rel_s[row])<<7)+d0+(g<<3)];
      }
    }
    int ic = L0 ? ch+2 : ch;
    #pragma unroll
    for (int i=0;i<4;++i) pb[i]=imgp[ic*1024+(i<<8)+t];
  };

  issueA(0);
  #pragma unroll
  for (int ch=0; ch<NCH; ++ch){
    const bool cf = L0 || (ch>=2);
    #pragma unroll
    for (int i=0;i<4;++i){
      int row=row0+(i<<5);
      uint4 val;
      if (cf){
        val.x=packbf(pf0[i].x,pf0[i].y); val.y=packbf(pf0[i].z,pf0[i].w);
        val.z=packbf(pf1[i].x,pf1[i].y); val.w=packbf(pf1[i].z,pf1[i].w);
      } else {
        val.x=pmul_bf(pa[i].x,pr[i].x); val.y=pmul_bf(pa[i].y,pr[i].y);
        val.z=pmul_bf(pa[i].z,pr[i].z); val.w=pmul_bf(pa[i].w,pr[i].w);
      }
      *(uint4*)(lds + row*128 + aswz) = val;
    }
    *(uint4*)(lds+16384+(t<<4))        = pb[0];
    *(uint4*)(lds+16384+(t<<4)+4096)   = pb[1];
    *(uint4*)(lds+16384+(t<<4)+8192)   = pb[2];
    *(uint4*)(lds+16384+(t<<4)+12288)  = pb[3];
    __syncthreads();
    if (ch < NCH-1) issueA(ch+1);
    #pragma unroll
    for (int s=0;s<2;++s){
      bfrag af[4], bfr[4];
      #pragma unroll
      for (int m=0;m<4;++m)
        af[m] = *(const bfrag*)(lds + (rbase+(m<<4)+lr)*128 + (((s<<6)+(lk<<4)) ^ swz));
      #pragma unroll
      for (int n=0;n<4;++n)
        bfr[n] = *(const bfrag*)(lds + 16384 + (cbase+(n<<4)+lr)*128 + (((s<<6)+(lk<<4)) ^ swz));
      #pragma unroll
      for (int m=0;m<4;++m)
        #pragma unroll
        for (int n=0;n<4;++n)
          acc[m][n] = __builtin_amdgcn_mfma_f32_16x16x32_bf16(af[m], bfr[n], acc[m][n], 0,0,0);
    }
    __syncthreads();
  }

  // transpose-store raw GEMM result -> LDS bf16 (bias/relu applied in pass 2)
  #pragma unroll
  for (int m=0;m<4;++m)
    #pragma unroll
    for (int n=0;n<4;++n)
      #pragma unroll
      for (int q=0;q<4;++q){
        int row=rbase+(m<<4)+(lk<<2)+q;
        int col=cbase+(n<<4)+lr;
        *(ushort_t*)(lds+(row<<8)+((col<<1)^((row&7)<<4))) = f2bf(acc[m][n][q]);
      }
  __syncthreads();

  #pragma unroll
  for (int i=0;i<8;++i){
    int u=t+(i<<8), row=u>>4, gg=u&15, c0=gg<<3;
    uint4 v = *(const uint4*)(lds+(row<<8)+((gg<<4)^((row&7)<<4)));
    float vv[8] = {bflo(v.x),bfhi(v.x),bflo(v.y),bfhi(v.y),
                   bflo(v.z),bfhi(v.z),bflo(v.w),bfhi(v.w)};
    int rel=rel_s[row], sc=src_s[row], ge=ge_s[row], b=ge>>15;
    const float* rm = relmsg + (((size_t)(layer*NRELS+rel))<<7) + c0;
    float bias[8];
    #pragma unroll
    for (int j=0;j<8;++j) bias[j] = rm[j];
    if (!L0){
      const float* hp = H1 + (((size_t)sc)<<7) + c0;
      #pragma unroll
      for (int j=0;j<8;++j) bias[j] += hp[j];
      if ((sc & (NNODE-1)) == 0){
        const float* iv = initvec + layer*128 + c0;
        #pragma unroll
        for (int j=0;j<8;++j) bias[j] += iv[j];
      }
    } else {
      if ((sc & (NNODE-1)) == 0){
        const float* rh = relhh0 + ((size_t)rel<<7) + c0;
        const float* sv = src0vec + c0;
        #pragma unroll
        for (int j=0;j<8;++j) bias[j] += rh[j] + sv[j];
      }
    }
    float part=0.f;
    unsigned o0,o1,o2,o3;
    {
      float m0=fmaxf(vv[0]+bias[0],0.f), m1=fmaxf(vv[1]+bias[1],0.f);
      float m2=fmaxf(vv[2]+bias[2],0.f), m3=fmaxf(vv[3]+bias[3],0.f);
      float m4=fmaxf(vv[4]+bias[4],0.f), m5=fmaxf(vv[5]+bias[5],0.f);
      float m6=fmaxf(vv[6]+bias[6],0.f), m7=fmaxf(vv[7]+bias[7],0.f);
      part = m0*attw_s[c0] + m1*attw_s[c0+1] + m2*attw_s[c0+2] + m3*attw_s[c0+3]
           + m4*attw_s[c0+4] + m5*attw_s[c0+5] + m6*attw_s[c0+6] + m7*attw_s[c0+7];
      o0=packbf(m0,m1); o1=packbf(m2,m3); o2=packbf(m4,m5); o3=packbf(m6,m7);
    }
    uint4 ov; ov.x=o0; ov.y=o1; ov.z=o2; ov.w=o3;
    *(uint4*)&raw_c[(((size_t)(ci0+row))<<7) + c0] = ov;
    #pragma unroll
    for (int off=1; off<16; off<<=1) part += __shfl_xor(part, off, 16);
    if (gg == 0){
      float a = part + att_rel[layer*NRELS+rel] + att_rq[layer*BB+b] + attb[layer];
      a = (a >= 0.f) ? a : 0.01f*a;
      att_c[ci0+row] = a;
    }
  }
}

// --------------------------- per-node softmax + weighted aggregate (contiguous)
__global__ __launch_bounds__(128) void node_agg_kernel(
    const int* __restrict__ base,
    const float* __restrict__ att_c, const float* __restrict__ coef_c,
    const ushort_t* __restrict__ raw_c, float* __restrict__ aggr)
{
  const int n = blockIdx.x;              // BB*NNODE
  const int t = threadIdx.x;             // 128
  const int b0 = base[n], b1 = base[n+1];
  const int deg = b1 - b0;
  if (deg == 0){ aggr[((size_t)n<<7)+t] = 0.f; return; }
  __shared__ float w_s[128];
  __shared__ float red[4];
  float mx = -3.0e38f;
  for (int j=t; j<deg; j+=128) mx = fmaxf(mx, att_c[b0+j]);
  #pragma unroll
  for (int o=1;o<64;o<<=1) mx = fmaxf(mx, __shfl_xor(mx, o, 64));
  if ((t&63)==0) red[t>>6] = mx;
  __syncthreads();
  mx = fmaxf(red[0], red[1]);
  float s = 0.f;
  for (int j=t; j<deg; j+=128) s += expf(att_c[b0+j]-mx);
  #pragma unroll
  for (int o=1;o<64;o<<=1) s += __shfl_xor(s, o, 64);
  if ((t&63)==0) red[2+(t>>6)] = s;
  __syncthreads();
  const float inv = 1.0f/((red[2]+red[3]) + 1e-8f);
  float accv = 0.f;
  for (int jb=0; jb<deg; jb+=128){
    int jj = jb + t;
    __syncthreads();
    if (jj < deg) w_s[t] = coef_c[b0+jj] * expf(att_c[b0+jj]-mx) * inv;
    __syncthreads();
    int lim = min(128, deg-jb);
    int j = 0;
    for (; j+3 < lim; j += 4){
      float v0 = bf2f(raw_c[(((size_t)(b0+jb+j  ))<<7)+t]);
      float v1 = bf2f(raw_c[(((size_t)(b0+jb+j+1))<<7)+t]);
      float v2 = bf2f(raw_c[(((size_t)(b0+jb+j+2))<<7)+t]);
      float v3 = bf2f(raw_c[(((size_t)(b0+jb+j+3))<<7)+t]);
      accv = fmaf(w_s[j],v0,accv);
      accv = fmaf(w_s[j+1],v1,accv);
      accv = fmaf(w_s[j+2],v2,accv);
      accv = fmaf(w_s[j+3],v3,accv);
    }
    for (; j<lim; ++j)
      accv = fmaf(w_s[j], bf2f(raw_c[(((size_t)(b0+jb+j))<<7)+t]), accv);
  }
  aggr[((size_t)n<<7)+t] = accv;
}

// ---------------- h = LN(h + aggr@updW + updb); fused next-layer H1 = h@W1
#define FMA4(acc, a, bv) do { \
    acc.x = fmaf(a, bv.x, acc.x); \
    acc.y = fmaf(a, bv.y, acc.y); \
    acc.z = fmaf(a, bv.z, acc.z); \
    acc.w = fmaf(a, bv.w, acc.w); } while(0)

__global__ __launch_bounds__(256,2) void update_kernel(
    const float* __restrict__ aggr, const float* __restrict__ updW,
    const float* __restrict__ updb,
    const float* __restrict__ lng, const float* __restrict__ lnb,
    const float* __restrict__ msgW,
    float* __restrict__ h, ushort_t* __restrict__ h_bf,
    float* __restrict__ H1, float* __restrict__ out, int layer)
{
  __shared__ float As[64*65];
  __shared__ float Bs[64*128];
  const int t = threadIdx.x, blk = blockIdx.x;   // 128 blocks
  const int n0 = blk << 6;
  const int c = t & 15, r = t >> 4;
  float4 acc0[4], acc1[4];
  #pragma unroll
  for (int i=0;i<4;++i){ acc0[i]=make_float4(0,0,0,0); acc1[i]=make_float4(0,0,0,0); }
  const float* wbase = updW + (size_t)layer*DDIM*DDIM;

  for (int ch=0; ch<2; ++ch){
    __syncthreads();
    #pragma unroll
    for (int l=0;l<16;++l){
      int idx=(l<<8)+t, ei=idx>>6, kk=idx&63;
      As[ei*65+kk] = aggr[(size_t)(n0+ei)*DDIM + (ch<<6) + kk];
    }
    #pragma unroll
    for (int l=0;l<32;++l){
      int idx=(l<<8)+t, kk=idx>>7, j=idx&127;
      Bs[(kk<<7)+j] = wbase[((ch<<6)+kk)*DDIM + j];
    }
    __syncthreads();
    #pragma unroll 4
    for (int kk=0;kk<64;++kk){
      const float4 b0 = *(const float4*)&Bs[(kk<<7) + (c<<2)];
      const float4 b1 = *(const float4*)&Bs[(kk<<7) + 64 + (c<<2)];
      #pragma unroll
      for (int i=0;i<4;++i){
        const float a = As[((r<<2)+i)*65 + kk];
        FMA4(acc0[i], a, b0);
        FMA4(acc1[i], a, b1);
      }
    }
  }

  const int col0 = c << 2;
  float ub0[4], ub1[4], g0[4], g1[4], lb0[4], lb1[4];
  #pragma unroll
  for (int q=0;q<4;++q){
    ub0[q] = updb[layer*DDIM + col0+q];  ub1[q] = updb[layer*DDIM + 64+col0+q];
    g0[q]  = lng[col0+q];                g1[q]  = lng[64+col0+q];
    lb0[q] = lnb[col0+q];                lb1[q] = lnb[64+col0+q];
  }

  float4 yv0[4], yv1[4];
  #pragma unroll
  for (int i=0;i<4;++i){
    const int row = n0 + (r<<2) + i;
    float* hrow = h + (size_t)row*DDIM;
    float4 h0 = *(float4*)&hrow[col0];
    float4 h1 = *(float4*)&hrow[64+col0];
    float x0[4], x1[4];
    x0[0] = h0.x + acc0[i].x + ub0[0];
    x0[1] = h0.y + acc0[i].y + ub0[1];
    x0[2] = h0.z + acc0[i].z + ub0[2];
    x0[3] = h0.w + acc0[i].w + ub0[3];
    x1[0] = h1.x + acc1[i].x + ub1[0];
    x1[1] = h1.y + acc1[i].y + ub1[1];
    x1[2] = h1.z + acc1[i].z + ub1[2];
    x1[3] = h1.w + acc1[i].w + ub1[3];
    float s = 0.f, s2 = 0.f;
    #pragma unroll
    for (int q=0;q<4;++q){ s += x0[q]+x1[q]; s2 += x0[q]*x0[q] + x1[q]*x1[q]; }
    #pragma unroll
    for (int off=1; off<16; off<<=1){
      s  += __shfl_xor(s,  off, 16);
      s2 += __shfl_xor(s2, off, 16);
    }
    const float mu = s * (1.0f/128.0f);
    const float var = s2 * (1.0f/128.0f) - mu*mu;
    const float rstd = rsqrtf(var + 1e-5f);
    float4 y0, y1;
    y0.x = (x0[0]-mu)*rstd*g0[0] + lb0[0];
    y0.y = (x0[1]-mu)*rstd*g0[1] + lb0[1];
    y0.z = (x0[2]-mu)*rstd*g0[2] + lb0[2];
    y0.w = (x0[3]-mu)*rstd*g0[3] + lb0[3];
    y1.x = (x1[0]-mu)*rstd*g1[0] + lb1[0];
    y1.y = (x1[1]-mu)*rstd*g1[1] + lb1[1];
    y1.z = (x1[2]-mu)*rstd*g1[2] + lb1[2];
    y1.w = (x1[3]-mu)*rstd*g1[3] + lb1[3];
    *(float4*)&hrow[col0] = y0;
    *(float4*)&hrow[64+col0] = y1;
    ushort4 z0, z1;
    z0.x=f2bf(y0.x); z0.y=f2bf(y0.y); z0.z=f2bf(y0.z); z0.w=f2bf(y0.w);
    z1.x=f2bf(y1.x); z1.y=f2bf(y1.y); z1.z=f2bf(y1.z); z1.w=f2bf(y1.w);
    *(ushort4*)&h_bf[(size_t)row*DDIM + col0] = z0;
    *(ushort4*)&h_bf[(size_t)row*DDIM + 64 + col0] = z1;
    yv0[i] = y0; yv1[i] = y1;
    if ((row & (NNODE-1)) == 0){
      const int bb_ = row >> 11;
      float* op = out + (size_t)(bb_*NL + layer)*DDIM;
      *(float4*)&op[col0] = y0;
      *(float4*)&op[64+col0] = y1;
    }
  }

  // ---- fused next-layer H1 = h_new @ msgW[layer+1][128:256] (skip last layer)
  if (layer < NL-1){
    const float* w1 = msgW + (size_t)(layer+1)*81920 + 16384;
    float4 k0[4], k1[4];
    #pragma unroll
    for (int i=0;i<4;++i){ k0[i]=make_float4(0,0,0,0); k1[i]=make_float4(0,0,0,0); }
    for (int ch=0; ch<2; ++ch){
      __syncthreads();
      #pragma unroll
      for (int i=0;i<4;++i){
        const int ei = (r<<2)+i;
        float4 v = (ch==0) ? yv0[i] : yv1[i];
        As[ei*65 + col0 + 0] = v.x;
        As[ei*65 + col0 + 1] = v.y;
        As[ei*65 + col0 + 2] = v.z;
        As[ei*65 + col0 + 3] = v.w;
      }
      #pragma unroll
      for (int l=0;l<32;++l){
        int idx=(l<<8)+t, kk=idx>>7, j=idx&127;
        Bs[(kk<<7)+j] = w1[((ch<<6)+kk)*DDIM + j];
      }
      __syncthreads();
      #pragma unroll 4
      for (int kk=0;kk<64;++kk){
        const float4 b0 = *(const float4*)&Bs[(kk<<7) + col0];
        const float4 b1 = *(const float4*)&Bs[(kk<<7) + 64 + col0];
        #pragma unroll
        for (int i=0;i<4;++i){
          const float a = As[((r<<2)+i)*65 + kk];
          FMA4(k0[i], a, b0);
          FMA4(k1[i], a, b1);
        }
      }
    }
    #pragma unroll
    for (int i=0;i<4;++i){
      const int row = n0 + (r<<2) + i;
      *(float4*)&H1[(size_t)row*DDIM + col0]      = k0[i];
      *(float4*)&H1[(size_t)row*DDIM + 64 + col0] = k1[i];
    }
  }
}

// ------------------------------------------------------------------ launcher
extern "C" void kernel_launch(void* const* d_in, const int* in_sizes, int n_in,
                              void* d_out, int out_size, void* d_ws, size_t ws_size,
                              hipStream_t stream) {
  const int*   edge_index = (const int*)d_in[0];
  const int*   rels       = (const int*)d_in[1];
  const float* scores     = (const float*)d_in[2];
  const void*  cm_raw     = d_in[3];
  const void*  em_raw     = d_in[4];
  const float* rq    = (const float*)d_in[6];
  const float* conf  = (const float*)d_in[7];
  const float* relt  = (const float*)d_in[8];
  const float* betaW = (const float*)d_in[9];
  const float* betab = (const float*)d_in[10];
  const float* msgW  = (const float*)d_in[11];
  const float* msgb  = (const float*)d_in[12];
  const float* updW  = (const float*)d_in[13];
  const float* updb  = (const float*)d_in[14];
  const float* lng   = (const float*)d_in[15];
  const float* lnb   = (const float*)d_in[16];
  const float* attW  = (const float*)d_in[17];
  const float* attb  = (const float*)d_in[18];
  const float* denW1 = (const float*)d_in[19];
  const float* denb1 = (const float*)d_in[20];
  const float* denW2 = (const float*)d_in[21];
  const float* denb2 = (const float*)d_in[22];
  float* out = (float*)d_out;
  char* ws = (char*)d_ws;

  size_t off = 0;
  float* h        = (float*)(ws + off); off += (size_t)BB*NNODE*DDIM*4;      //  4 MB
  ushort_t* h_bf  = (ushort_t*)(ws + off); off += (size_t)BB*NNODE*DDIM*2;   //  2 MB
  float* aggr     = (float*)(ws + off); off += (size_t)BB*NNODE*DDIM*4;      //  4 MB
  float* H1       = (float*)(ws + off); off += (size_t)BB*NNODE*DDIM*4;      //  4 MB
  ushort_t* raw_c = (ushort_t*)(ws + off); off += (size_t)BB*NE*DDIM*2;      // 32 MB
  float* att_c    = (float*)(ws + off); off += (size_t)BB*NE*4;              // 512 KB
  float* coef_c   = (float*)(ws + off); off += (size_t)BB*NE*4;              // 512 KB
  int* src_c      = (int*)(ws + off); off += (size_t)BB*NE*4;
  int* rel_c      = (int*)(ws + off); off += (size_t)BB*NE*4;
  int* ge_c       = (int*)(ws + off); off += (size_t)BB*NE*4;
  int* deg        = (int*)(ws + off); off += (size_t)BB*NNODE*4;
  int* base       = (int*)(ws + off); off += (size_t)(BB*NNODE+16)*4;
  int* cursor     = (int*)(ws + off); off += (size_t)BB*NNODE*4;
  ushort_t* relt_bf = (ushort_t*)(ws + off); off += (size_t)NRELS*DDIM*2 + 64;
  ushort_t* img_msg = (ushort_t*)(ws + off); off += (size_t)12*8192*2;       // 192 KB
  ushort_t* img_den = (ushort_t*)(ws + off); off += (size_t)2*8192*2;        //  32 KB
  ushort_t* img_tab = (ushort_t*)(ws + off); off += (size_t)8*8192*2;        // 128 KB
  float* relmsg   = (float*)(ws + off); off += (size_t)3*NRELS*DDIM*4;       // 1.5 MB
  float* relhh0   = (float*)(ws + off); off += (size_t)NRELS*DDIM*4;         // 512 KB
  float* denrel   = (float*)(ws + off); off += (size_t)NRELS*DDIM*4;         // 512 KB
  float* denrq    = (float*)(ws + off); off += (size_t)BB*DDIM*4;
  float* initvec  = (float*)(ws + off); off += 3*DDIM*4;
  float* src0vec  = (float*)(ws + off); off += DDIM*4;
  float* att_rel  = (float*)(ws + off); off += 3*NRELS*4 + 32;
  float* att_rq   = (float*)(ws + off); off += 64;
  float* beta_rel = (float*)(ws + off); off += NRELS*4 + 32;
  float* beta_rq  = (float*)(ws + off); off += 64;
  uint8_t* cm_dec = (uint8_t*)(ws + off); off += (size_t)BB*NE;
  uint8_t* em_dec = (uint8_t*)(ws + off); off += (size_t)BB*NE;

  prep_kernel<<<1024, 256, 0, stream>>>(cm_raw, em_raw, cm_dec, em_dec, deg,
                                        relt, relt_bf, rq, attW, betaW,
                                        msgW, denW1, denb1,
                                        src_c, rel_c, ge_c, h, h_bf,
                                        img_msg, img_den, img_tab,
                                        att_rel, att_rq, beta_rel, beta_rq,
                                        denrq, initvec, src0vec);
  csr_hist_kernel<<<512, 256, 0, stream>>>(edge_index, em_dec, deg);
  csr_scan_kernel<<<1, 256, 0, stream>>>(deg, base, cursor);
  csr_scatter_kernel<<<512, 256, 0, stream>>>(edge_index, rels, em_dec, cursor,
                                              src_c, rel_c, ge_c);
  table_gemm_kernel<<<40, 256, 0, stream>>>(relt_bf, img_msg, img_tab, msgb,
                                            relmsg, relhh0, denrel);
  coef_mfma_kernel<<<1024, 256, 0, stream>>>(base + BB*NNODE, rel_c, ge_c, conf, img_den,
                                             denrel, denrq, denW2, denb2,
                                             scores, cm_dec, beta_rel, beta_rq, betab,
                                             coef_c);
  for (int k = 0; k < NL; ++k){
    if (k == 0){
      msg_mfma_kernel<true><<<1024, 256, 0, stream>>>(base + BB*NNODE, src_c, rel_c, ge_c,
          relt_bf, conf, h_bf, H1, img_msg, relmsg, relhh0, src0vec, initvec,
          attW, attb, att_rel, att_rq, raw_c, att_c, k);
    } else {
      msg_mfma_kernel<false><<<1024, 256, 0, stream>>>(base + BB*NNODE, src_c, rel_c, ge_c,
          relt_bf, conf, h_bf, H1, img_msg, relmsg, relhh0, src0vec, initvec,
          attW, attb, att_rel, att_rq, raw_c, att_c, k);
    }
    node_agg_kernel<<<BB*NNODE, 128, 0, stream>>>(base, att_c, coef_c, raw_c, aggr);
    update_kernel<<<128, 256, 0, stream>>>(aggr, updW, updb, lng, lnb, msgW,
                                           h, h_bf, H1, out, k);
  }
}

// Round 11
// 361.553 us; speedup vs baseline: 1.6505x; 1.0129x over previous
//
#include <hip/hip_runtime.h>
#include <stdint.h>
#include <math.h>

#define BB 4
#define NNODE 2048
#define NE 32768
#define DDIM 128
#define NL 3
#define NRELS 1000
#define MASKV -1000000000.0f

typedef unsigned short ushort_t;
typedef __attribute__((ext_vector_type(8))) short bfrag;   // 8 bf16 (4 VGPR)
typedef __attribute__((ext_vector_type(4))) float f4;

__device__ __forceinline__ float sigf(float x){ return 1.0f/(1.0f+expf(-x)); }

__device__ __forceinline__ float bf2f(ushort_t u){
  union { unsigned int i; float f; } v; v.i = ((unsigned int)u) << 16; return v.f;
}
__device__ __forceinline__ ushort_t f2bf(float x){
  union { float f; unsigned int u; } v; v.f = x;
  unsigned int r = (v.u + 0x7FFFu + ((v.u >> 16) & 1u)) >> 16;  // RNE
  return (ushort_t)r;
}
__device__ __forceinline__ float bflo(unsigned u){
  union{unsigned i;float f;}v; v.i=u<<16; return v.f;
}
__device__ __forceinline__ float bfhi(unsigned u){
  union{unsigned i;float f;}v; v.i=u&0xFFFF0000u; return v.f;
}
__device__ __forceinline__ unsigned pmul_bf(unsigned a, unsigned b){
  return (unsigned)f2bf(bflo(a)*bflo(b)) | ((unsigned)f2bf(bfhi(a)*bfhi(b))<<16);
}
__device__ __forceinline__ unsigned packbf(float a, float b){
  return (unsigned)f2bf(a) | ((unsigned)f2bf(b)<<16);
}

// ================= mega-prep: probe+masks+defaults, CSR hist (deg pre-zeroed
// by memset node), relt_bf, h init, weight images, scalar+tiny tables.
__global__ void prep_kernel(const void* cm_raw, const void* em_raw,
    const int* __restrict__ edge_index,
    uint8_t* __restrict__ cm, uint8_t* __restrict__ em, int* __restrict__ deg,
    const float* __restrict__ relt, ushort_t* __restrict__ relt_bf,
    const float* __restrict__ rq,
    const float* __restrict__ attW, const float* __restrict__ betaW,
    const float* __restrict__ msgW, const float* __restrict__ denW1,
    const float* __restrict__ denb1,
    int* __restrict__ src_c, int* __restrict__ rel_c, int* __restrict__ ge_c,
    float* __restrict__ h, ushort_t* __restrict__ h_bf,
    ushort_t* __restrict__ img_msg, ushort_t* __restrict__ img_den,
    ushort_t* __restrict__ img_tab,
    float* __restrict__ att_rel, float* __restrict__ att_rq,
    float* __restrict__ beta_rel, float* __restrict__ beta_rq,
    float* __restrict__ denrq, float* __restrict__ initvec,
    float* __restrict__ src0vec)
{
  __shared__ int flag_s;
  if (threadIdx.x < 64){
    unsigned v = ((const unsigned*)cm_raw)[threadIdx.x];
    bool i32ok = (v <= 1u);
    bool f32ok = (v == 0u) || (v == 0x3F800000u);
    unsigned long long bi = __ballot(i32ok);
    unsigned long long bf_ = __ballot(f32ok);
    if (threadIdx.x == 0) flag_s = (bi==~0ULL) ? 0 : ((bf_==~0ULL) ? 1 : 2);
  }
  __syncthreads();
  const int f = flag_s;
  const int gid = blockIdx.x*256 + threadIdx.x;    // 1024 blocks = 262144 thr

  // ---- masks + compact-array defaults + CSR histogram
  if (gid < BB*NE){
    uint8_t c, e;
    if (f == 0){ c = ((const int*)cm_raw)[gid]!=0;   e = ((const int*)em_raw)[gid]!=0; }
    else if (f == 1){ c = ((const float*)cm_raw)[gid]!=0.0f; e = ((const float*)em_raw)[gid]!=0.0f; }
    else { c = ((const uint8_t*)cm_raw)[gid]!=0; e = ((const uint8_t*)em_raw)[gid]!=0; }
    cm[gid]=c; em[gid]=e;
    src_c[gid]=0; rel_c[gid]=0; ge_c[gid]=0;
    if (e){
      int b = gid >> 15, ee = gid & (NE-1);
      int tgt = edge_index[(b<<16) + NE + ee];
      atomicAdd(&deg[(b<<11) + tgt], 1);
    }
  }
  // ---- relt -> bf16
  if (gid < NRELS*DDIM/4){
    float4 v = *(const float4*)&relt[gid*4];
    ushort4 o; o.x=f2bf(v.x); o.y=f2bf(v.y); o.z=f2bf(v.z); o.w=f2bf(v.w);
    *(ushort4*)&relt_bf[gid*4] = o;
  }
  // ---- h init (all 262144 threads)
  {
    int base = gid*4;
    int nd = base & (NNODE*DDIM - 1);
    bool one = (nd < DDIM);
    float4 hv = one ? (float4){1.f,1.f,1.f,1.f} : (float4){0.f,0.f,0.f,0.f};
    ushort4 hb = one ? (ushort4){0x3F80,0x3F80,0x3F80,0x3F80} : (ushort4){0,0,0,0};
    *(float4*)&h[base] = hv;
    *(ushort4*)&h_bf[base] = hb;
  }
  // ---- weight LDS-images (transposed, swizzled, bf16)
  if (gid < 22*8192){
    int img_id = gid >> 13;
    int ei = gid & 8191;
    int j = ei >> 6;
    int kk = (((ei & 63) << 1) ^ ((j & 7) << 4)) >> 1;
    float v; ushort_t* dst;
    if (img_id < 12){
      int k = img_id >> 2, c = img_id & 3;
      int rowbase = (c < 2) ? c*64 : 512 + (c-2)*64;
      v = msgW[(size_t)k*81920 + (rowbase+kk)*128 + j];
      dst = img_msg + (size_t)img_id*8192;
    } else if (img_id < 14){
      int c = img_id - 12;
      v = denW1[(size_t)(256 + c*64 + kk)*128 + j];
      dst = img_den + (size_t)c*8192;
    } else if (img_id < 20){
      int idx = img_id - 14, k = idx >> 1, c = idx & 1;
      v = msgW[(size_t)k*81920 + (384 + c*64 + kk)*128 + j];
      dst = img_tab + (size_t)idx*8192;
    } else {
      int c = img_id - 20;
      v = denW1[(size_t)(c*64 + kk)*128 + j];
      dst = img_tab + (size_t)(6+c)*8192;
    }
    dst[ei] = f2bf(v);
  }
  // ---- scalar tables (att/beta) + tiny vector rows
  {
    int wid = gid >> 6;
    int lane = threadIdx.x & 63;
    if (wid < 4016){
      const float* vec; const float* w; float* dst; int di;
      if (wid < 3*NRELS){
        int k = wid/1000, rl = wid%1000;
        vec = relt + rl*DDIM; w = attW + k*384 + 128; dst = att_rel; di = wid;
      } else if (wid < 3*NRELS + 3*BB){
        int idx = wid - 3*NRELS; int k = idx/BB, b = idx%BB;
        vec = rq + b*DDIM; w = attW + k*384 + 256; dst = att_rq; di = idx;
      } else if (wid < 3*NRELS + 3*BB + NRELS){
        int rl = wid - (3*NRELS + 3*BB);
        vec = relt + rl*DDIM; w = betaW; dst = beta_rel; di = rl;
      } else {
        int b = wid - (3*NRELS + 3*BB + NRELS);
        vec = rq + b*DDIM; w = betaW; dst = beta_rq; di = b;
      }
      float s = vec[lane]*w[lane] + vec[lane+64]*w[lane+64];
      #pragma unroll
      for (int off=32; off; off>>=1) s += __shfl_xor(s, off, 64);
      if (lane == 0) dst[di] = s;
    } else if (wid < 4024){
      int widx = wid - 4016;
      const float* A = nullptr; const float* W; int K = 128;
      float* outp; const float* bias = nullptr;
      if (widx < 4){ A = rq + widx*128; W = denW1 + 16384; outp = denrq + widx*128; bias = denb1; }
      else if (widx < 7){ int k=widx-4; W = msgW + (size_t)k*81920 + 32768; outp = initvec + k*128; }
      else { W = msgW + 16384; K = 256; outp = src0vec; }
      float a0=0.f, a1=0.f;
      for (int kk=0; kk<K; kk+=8){
        float av[8], w0[8], w1[8];
        #pragma unroll
        for (int u=0;u<8;++u){
          av[u] = A ? A[kk+u] : 1.0f;
          w0[u] = W[(size_t)(kk+u)*128 + lane];
          w1[u] = W[(size_t)(kk+u)*128 + lane + 64];
        }
        #pragma unroll
        for (int u=0;u<8;++u){ a0 = fmaf(av[u], w0[u], a0); a1 = fmaf(av[u], w1[u], a1); }
      }
      if (bias){ a0 += bias[lane]; a1 += bias[lane+64]; }
      outp[lane] = a0; outp[lane+64] = a1;
    }
  }
}

// ------------------------------------------------------------ CSR scan
__global__ void csr_scan_kernel(const int* __restrict__ deg,
                                int* __restrict__ base, int* __restrict__ cursor){
  __shared__ int part[256];
  int t = threadIdx.x;                             // 256 threads, 1 block
  int loc[32]; int s = 0;
  #pragma unroll
  for (int i=0;i<32;++i){ loc[i] = deg[t*32+i]; s += loc[i]; }
  part[t] = s; __syncthreads();
  for (int off=1; off<256; off<<=1){
    int v = (t >= off) ? part[t-off] : 0;
    __syncthreads();
    part[t] += v;
    __syncthreads();
  }
  int ex = (t==0) ? 0 : part[t-1];
  #pragma unroll
  for (int i=0;i<32;++i){ base[t*32+i] = ex; cursor[t*32+i] = ex; ex += loc[i]; }
  if (t == 255) base[256*32] = ex;       // nact
}

// ============ fused: CSR scatter (blocks 0..511) + table GEMM (blocks 512..551)
__global__ __launch_bounds__(256,2) void scatter_tab_kernel(
    const int* __restrict__ edge_index, const int* __restrict__ rels,
    const uint8_t* __restrict__ em, int* __restrict__ cursor,
    int* __restrict__ src_c, int* __restrict__ rel_c, int* __restrict__ ge_c,
    const ushort_t* __restrict__ relt_bf, const ushort_t* __restrict__ img_msg,
    const ushort_t* __restrict__ img_tab, const float* __restrict__ msgb,
    float* __restrict__ relmsg, float* __restrict__ relhh0,
    float* __restrict__ denrel)
{
  __shared__ char lds[32768];
  __shared__ float fs0[128];
  const int t = threadIdx.x;

  if (blockIdx.x < 512){
    int gid = blockIdx.x*256 + t;                  // B*E
    if (!em[gid]) return;
    int b = gid >> 15, e = gid & (NE-1);
    int tgt = edge_index[(b<<16) + NE + e];
    int src = edge_index[(b<<16) + e];
    int pos = atomicAdd(&cursor[(b<<11) + tgt], 1);
    src_c[pos] = (b<<11) | src;
    rel_c[pos] = rels[gid];
    ge_c[pos]  = gid;
    return;
  }

  // ---- table GEMM: {relmsg, relhh0, denrel} = relt @ B
  const int blk = blockIdx.x - 512;      // 40 = 8 row-tiles x 5 jobs
  const int job = blk % 5;
  const int ri0 = (blk/5) << 7;
  const uint4* imgb;
  float* outp;
  if (job < 3){ imgb = (const uint4*)(img_tab + (size_t)(2*job)*8192); outp = relmsg + (size_t)job*NRELS*DDIM; }
  else if (job == 3){ imgb = (const uint4*)img_msg; outp = relhh0; }
  else { imgb = (const uint4*)(img_tab + (size_t)6*8192); outp = denrel; }
  if (t < 128) fs0[t] = (job < 3) ? msgb[job*128 + t] : 0.f;

  const int lane=t&63, wid=t>>6;
  const int wr=wid>>1, wc=wid&1;
  const int rbase=wr<<6, cbase=wc<<6;
  const int lr=lane&15, lk=lane>>4;
  const int swz=(lane&7)<<4;
  const int g=t&7, row0=t>>3;
  const int aswz=(g<<4)^((row0&7)<<4);

  f4 acc[4][4];
  #pragma unroll
  for (int m=0;m<4;++m)
    #pragma unroll
    for (int n=0;n<4;++n) acc[m][n]=(f4){0.f,0.f,0.f,0.f};

  uint4 pa[4], pb[4];
  auto issueA = [&](int ch){
    #pragma unroll
    for (int i=0;i<4;++i){
      int rr = ri0 + row0 + (i<<5);
      rr = (rr < NRELS) ? rr : (NRELS-1);
      pa[i] = *(const uint4*)&relt_bf[(size_t)rr*128 + (ch<<6) + (g<<3)];
    }
    #pragma unroll
    for (int i=0;i<4;++i) pb[i] = imgb[ch*1024 + (i<<8) + t];
  };

  __syncthreads();
  issueA(0);
  #pragma unroll
  for (int ch=0; ch<2; ++ch){
    #pragma unroll
    for (int i=0;i<4;++i){
      int row = row0 + (i<<5);
      *(uint4*)(lds + row*128 + aswz) = pa[i];
    }
    *(uint4*)(lds+16384+(t<<4))        = pb[0];
    *(uint4*)(lds+16384+(t<<4)+4096)   = pb[1];
    *(uint4*)(lds+16384+(t<<4)+8192)   = pb[2];
    *(uint4*)(lds+16384+(t<<4)+12288)  = pb[3];
    __syncthreads();
    if (ch < 1) issueA(ch+1);
    #pragma unroll
    for (int s=0;s<2;++s){
      bfrag af[4], bfr[4];
      #pragma unroll
      for (int m=0;m<4;++m)
        af[m] = *(const bfrag*)(lds + (rbase+(m<<4)+lr)*128 + (((s<<6)+(lk<<4)) ^ swz));
      #pragma unroll
      for (int n=0;n<4;++n)
        bfr[n] = *(const bfrag*)(lds + 16384 + (cbase+(n<<4)+lr)*128 + (((s<<6)+(lk<<4)) ^ swz));
      #pragma unroll
      for (int m=0;m<4;++m)
        #pragma unroll
        for (int n=0;n<4;++n)
          acc[m][n] = __builtin_amdgcn_mfma_f32_16x16x32_bf16(af[m], bfr[n], acc[m][n], 0,0,0);
    }
    __syncthreads();
  }

  #pragma unroll
  for (int m=0;m<4;++m)
    #pragma unroll
    for (int n=0;n<4;++n){
      int col = cbase + (n<<4) + lr;
      float bv = fs0[col];
      #pragma unroll
      for (int q=0;q<4;++q){
        int gr = ri0 + rbase + (m<<4) + (lk<<2) + q;
        if (gr < NRELS) outp[(size_t)gr*128 + col] = acc[m][n][q] + bv;
      }
    }
}

// ============ fused: msg MFMA layer-0 (blocks 0..1023) + coef (blocks 1024..2047)
// and standalone msg for layers 1,2.
template<bool FUSED_L0>
__global__ __launch_bounds__(256,2) void msg_mfma_kernel(
    const int* __restrict__ nact_p,
    const int* __restrict__ src_c, const int* __restrict__ rel_c,
    const int* __restrict__ ge_c,
    const ushort_t* __restrict__ relt_bf, const float* __restrict__ conf,
    const ushort_t* __restrict__ h_bf, const float* __restrict__ H1,
    const ushort_t* __restrict__ img_msg, const ushort_t* __restrict__ img_den,
    const float* __restrict__ relmsg, const float* __restrict__ relhh0,
    const float* __restrict__ src0vec, const float* __restrict__ initvec,
    const float* __restrict__ attW, const float* __restrict__ attb,
    const float* __restrict__ att_rel, const float* __restrict__ att_rq,
    const float* __restrict__ denrel, const float* __restrict__ denrq,
    const float* __restrict__ denW2, const float* __restrict__ denb2,
    const float* __restrict__ scores, const uint8_t* __restrict__ cm,
    const float* __restrict__ beta_rel, const float* __restrict__ beta_rq,
    const float* __restrict__ betab,
    ushort_t* __restrict__ raw_c, float* __restrict__ att_c,
    float* __restrict__ coef_c, int layer)
{
  __shared__ char lds[32768];
  __shared__ int is0[128], is1[128], is2[128];
  __shared__ float fs0[128];

  const int t = threadIdx.x;
  const int nact = *nact_p;
  const bool is_coef = FUSED_L0 && (blockIdx.x >= 1024);
  const int blk = is_coef ? (blockIdx.x - 1024) : blockIdx.x;
  const int ci0 = blk << 7;
  if (ci0 >= nact) return;

  const int lane=t&63, wid=t>>6;
  const int wr=wid>>1, wc=wid&1;
  const int rbase=wr<<6, cbase=wc<<6;
  const int lr=lane&15, lk=lane>>4;
  const int swz=(lane&7)<<4;
  const int g=t&7, row0=t>>3;
  const int aswz=(g<<4)^((row0&7)<<4);

  f4 acc[4][4];
  #pragma unroll
  for (int m=0;m<4;++m)
    #pragma unroll
    for (int n=0;n<4;++n) acc[m][n]=(f4){0.f,0.f,0.f,0.f};

  if (is_coef){
    // ================= coef body: K=128 conf GEMM + den/gate epilogue
    if (t < 128){ is1[t]=rel_c[ci0+t]; is2[t]=ge_c[ci0+t]; fs0[t]=denW2[t]; }
    const uint4* imgp = (const uint4*)img_den;
    float4 pf0[4], pf1[4];
    uint4 pb[4];
    __syncthreads();

    auto issueA = [&](int ch){
      const int d0=(ch&1)<<6;
      #pragma unroll
      for (int i=0;i<4;++i){
        int row=row0+(i<<5);
        const float* cp = conf + (((size_t)is2[row])<<7) + d0 + (g<<3);
        pf0[i]=*(const float4*)cp; pf1[i]=*(const float4*)(cp+4);
      }
      #pragma unroll
      for (int i=0;i<4;++i) pb[i]=imgp[ch*1024+(i<<8)+t];
    };

    issueA(0);
    #pragma unroll
    for (int ch=0; ch<2; ++ch){
      #pragma unroll
      for (int i=0;i<4;++i){
        int row=row0+(i<<5);
        uint4 val;
        val.x=packbf(pf0[i].x,pf0[i].y); val.y=packbf(pf0[i].z,pf0[i].w);
        val.z=packbf(pf1[i].x,pf1[i].y); val.w=packbf(pf1[i].z,pf1[i].w);
        *(uint4*)(lds + row*128 + aswz) = val;
      }
      *(uint4*)(lds+16384+(t<<4))        = pb[0];
      *(uint4*)(lds+16384+(t<<4)+4096)   = pb[1];
      *(uint4*)(lds+16384+(t<<4)+8192)   = pb[2];
      *(uint4*)(lds+16384+(t<<4)+12288)  = pb[3];
      __syncthreads();
      if (ch < 1) issueA(ch+1);
      #pragma unroll
      for (int s=0;s<2;++s){
        bfrag af[4], bfr[4];
        #pragma unroll
        for (int m=0;m<4;++m)
          af[m] = *(const bfrag*)(lds + (rbase+(m<<4)+lr)*128 + (((s<<6)+(lk<<4)) ^ swz));
        #pragma unroll
        for (int n=0;n<4;++n)
          bfr[n] = *(const bfrag*)(lds + 16384 + (cbase+(n<<4)+lr)*128 + (((s<<6)+(lk<<4)) ^ swz));
        #pragma unroll
        for (int m=0;m<4;++m)
          #pragma unroll
          for (int n=0;n<4;++n)
            acc[m][n] = __builtin_amdgcn_mfma_f32_16x16x32_bf16(af[m], bfr[n], acc[m][n], 0,0,0);
      }
      __syncthreads();
    }

    #pragma unroll
    for (int m=0;m<4;++m)
      #pragma unroll
      for (int n=0;n<4;++n)
        #pragma unroll
        for (int q=0;q<4;++q){
          int row=rbase+(m<<4)+(lk<<2)+q;
          int col=cbase+(n<<4)+lr;
          *(ushort_t*)(lds+(row<<8)+((col<<1)^((row&7)<<4))) = f2bf(acc[m][n][q]);
        }
    __syncthreads();

    #pragma unroll
    for (int i=0;i<8;++i){
      int u=t+(i<<8), row=u>>4, gg=u&15, c0=gg<<3;
      uint4 v = *(const uint4*)(lds+(row<<8)+((gg<<4)^((row&7)<<4)));
      float vv[8] = {bflo(v.x),bfhi(v.x),bflo(v.y),bfhi(v.y),
                     bflo(v.z),bfhi(v.z),bflo(v.w),bfhi(v.w)};
      int rel=is1[row], ge=is2[row], b=ge>>15;
      const float* dr = denrel + ((size_t)rel<<7) + c0;
      const float* dq = denrq + (b<<7) + c0;
      float part=0.f;
      #pragma unroll
      for (int j=0;j<8;++j){
        float m = fmaxf(vv[j] + dr[j] + dq[j], 0.f);
        part = fmaf(m, fs0[c0+j], part);
      }
      #pragma unroll
      for (int off=1; off<16; off<<=1) part += __shfl_xor(part, off, 16);
      if (gg == 0){
        float den = sigf(part + denb2[0]);
        float beta = sigf(beta_rel[rel] + beta_rq[b] + betab[0]);
        float gt = cm[ge] ? sigf((scores[ge]-beta)*10.0f) : 0.5f;
        coef_c[ci0+row] = gt * den;
      }
    }
    return;
  }

  // ================= msg body (L0: K=128 conf-only; else K=256)
  const bool L0 = FUSED_L0;
  const int NCH = L0 ? 2 : 4;
  if (t < 128){
    is0[t]=src_c[ci0+t]; is1[t]=rel_c[ci0+t]; is2[t]=ge_c[ci0+t];
    fs0[t]=attW[layer*384+t];
  }
  const uint4* imgp = (const uint4*)(img_msg + (size_t)layer*4*8192);
  uint4 pa[4], pr[4], pb[4];
  float4 pf0[4], pf1[4];
  __syncthreads();

  auto issueA = [&](int ch){
    const int d0=(ch&1)<<6;
    const bool cf = L0 || (ch>=2);
    #pragma unroll
    for (int i=0;i<4;++i){
      int row=row0+(i<<5);
      if (cf){
        const float* cp = conf + (((size_t)is2[row])<<7) + d0 + (g<<3);
        pf0[i]=*(const float4*)cp; pf1[i]=*(const float4*)(cp+4);
      } else {
        pa[i]=*(const uint4*)&h_bf[(((size_t)is0[row])<<7)+d0+(g<<3)];
        pr[i]=*(const uint4*)&relt_bf[(((size_t)is1[row])<<7)+d0+(g<<3)];
      }
    }
    int ic = L0 ? ch+2 : ch;
    #pragma unroll
    for (int i=0;i<4;++i) pb[i]=imgp[ic*1024+(i<<8)+t];
  };

  issueA(0);
  for (int ch=0; ch<NCH; ++ch){
    const bool cf = L0 || (ch>=2);
    #pragma unroll
    for (int i=0;i<4;++i){
      int row=row0+(i<<5);
      uint4 val;
      if (cf){
        val.x=packbf(pf0[i].x,pf0[i].y); val.y=packbf(pf0[i].z,pf0[i].w);
        val.z=packbf(pf1[i].x,pf1[i].y); val.w=packbf(pf1[i].z,pf1[i].w);
      } else {
        val.x=pmul_bf(pa[i].x,pr[i].x); val.y=pmul_bf(pa[i].y,pr[i].y);
        val.z=pmul_bf(pa[i].z,pr[i].z); val.w=pmul_bf(pa[i].w,pr[i].w);
      }
      *(uint4*)(lds + row*128 + aswz) = val;
    }
    *(uint4*)(lds+16384+(t<<4))        = pb[0];
    *(uint4*)(lds+16384+(t<<4)+4096)   = pb[1];
    *(uint4*)(lds+16384+(t<<4)+8192)   = pb[2];
    *(uint4*)(lds+16384+(t<<4)+12288)  = pb[3];
    __syncthreads();
    if (ch < NCH-1) issueA(ch+1);
    #pragma unroll
    for (int s=0;s<2;++s){
      bfrag af[4], bfr[4];
      #pragma unroll
      for (int m=0;m<4;++m)
        af[m] = *(const bfrag*)(lds + (rbase+(m<<4)+lr)*128 + (((s<<6)+(lk<<4)) ^ swz));
      #pragma unroll
      for (int n=0;n<4;++n)
        bfr[n] = *(const bfrag*)(lds + 16384 + (cbase+(n<<4)+lr)*128 + (((s<<6)+(lk<<4)) ^ swz));
      #pragma unroll
      for (int m=0;m<4;++m)
        #pragma unroll
        for (int n=0;n<4;++n)
          acc[m][n] = __builtin_amdgcn_mfma_f32_16x16x32_bf16(af[m], bfr[n], acc[m][n], 0,0,0);
    }
    __syncthreads();
  }

  #pragma unroll
  for (int m=0;m<4;++m)
    #pragma unroll
    for (int n=0;n<4;++n)
      #pragma unroll
      for (int q=0;q<4;++q){
        int row=rbase+(m<<4)+(lk<<2)+q;
        int col=cbase+(n<<4)+lr;
        *(ushort_t*)(lds+(row<<8)+((col<<1)^((row&7)<<4))) = f2bf(acc[m][n][q]);
      }
  __syncthreads();

  #pragma unroll
  for (int i=0;i<8;++i){
    int u=t+(i<<8), row=u>>4, gg=u&15, c0=gg<<3;
    uint4 v = *(const uint4*)(lds+(row<<8)+((gg<<4)^((row&7)<<4)));
    float vv[8] = {bflo(v.x),bfhi(v.x),bflo(v.y),bfhi(v.y),
                   bflo(v.z),bfhi(v.z),bflo(v.w),bfhi(v.w)};
    int rel=is1[row], sc=is0[row], ge=is2[row], b=ge>>15;
    const float* rm = relmsg + (((size_t)(layer*NRELS+rel))<<7) + c0;
    float bias[8];
    #pragma unroll
    for (int j=0;j<8;++j) bias[j] = rm[j];
    if (!L0){
      const float* hp = H1 + (((size_t)sc)<<7) + c0;
      #pragma unroll
      for (int j=0;j<8;++j) bias[j] += hp[j];
      if ((sc & (NNODE-1)) == 0){
        const float* iv = initvec + layer*128 + c0;
        #pragma unroll
        for (int j=0;j<8;++j) bias[j] += iv[j];
      }
    } else {
      if ((sc & (NNODE-1)) == 0){
        const float* rh = relhh0 + ((size_t)rel<<7) + c0;
        const float* sv = src0vec + c0;
        #pragma unroll
        for (int j=0;j<8;++j) bias[j] += rh[j] + sv[j];
      }
    }
    float part=0.f;
    unsigned o0,o1,o2,o3;
    {
      float m0=fmaxf(vv[0]+bias[0],0.f), m1=fmaxf(vv[1]+bias[1],0.f);
      float m2=fmaxf(vv[2]+bias[2],0.f), m3=fmaxf(vv[3]+bias[3],0.f);
      float m4=fmaxf(vv[4]+bias[4],0.f), m5=fmaxf(vv[5]+bias[5],0.f);
      float m6=fmaxf(vv[6]+bias[6],0.f), m7=fmaxf(vv[7]+bias[7],0.f);
      part = m0*fs0[c0] + m1*fs0[c0+1] + m2*fs0[c0+2] + m3*fs0[c0+3]
           + m4*fs0[c0+4] + m5*fs0[c0+5] + m6*fs0[c0+6] + m7*fs0[c0+7];
      o0=packbf(m0,m1); o1=packbf(m2,m3); o2=packbf(m4,m5); o3=packbf(m6,m7);
    }
    uint4 ov; ov.x=o0; ov.y=o1; ov.z=o2; ov.w=o3;
    *(uint4*)&raw_c[(((size_t)(ci0+row))<<7) + c0] = ov;
    #pragma unroll
    for (int off=1; off<16; off<<=1) part += __shfl_xor(part, off, 16);
    if (gg == 0){
      float a = part + att_rel[layer*NRELS+rel] + att_rq[layer*BB+b] + attb[layer];
      a = (a >= 0.f) ? a : 0.01f*a;
      att_c[ci0+row] = a;
    }
  }
}

// --------------------------- per-node softmax + weighted aggregate (contiguous)
__global__ __launch_bounds__(128) void node_agg_kernel(
    const int* __restrict__ base,
    const float* __restrict__ att_c, const float* __restrict__ coef_c,
    const ushort_t* __restrict__ raw_c, float* __restrict__ aggr)
{
  const int n = blockIdx.x;              // BB*NNODE
  const int t = threadIdx.x;             // 128
  const int b0 = base[n], b1 = base[n+1];
  const int deg = b1 - b0;
  if (deg == 0){ aggr[((size_t)n<<7)+t] = 0.f; return; }
  __shared__ float w_s[128];
  __shared__ float red[4];
  float mx = -3.0e38f;
  for (int j=t; j<deg; j+=128) mx = fmaxf(mx, att_c[b0+j]);
  #pragma unroll
  for (int o=1;o<64;o<<=1) mx = fmaxf(mx, __shfl_xor(mx, o, 64));
  if ((t&63)==0) red[t>>6] = mx;
  __syncthreads();
  mx = fmaxf(red[0], red[1]);
  float s = 0.f;
  for (int j=t; j<deg; j+=128) s += expf(att_c[b0+j]-mx);
  #pragma unroll
  for (int o=1;o<64;o<<=1) s += __shfl_xor(s, o, 64);
  if ((t&63)==0) red[2+(t>>6)] = s;
  __syncthreads();
  const float inv = 1.0f/((red[2]+red[3]) + 1e-8f);
  float accv = 0.f;
  for (int jb=0; jb<deg; jb+=128){
    int jj = jb + t;
    __syncthreads();
    if (jj < deg) w_s[t] = coef_c[b0+jj] * expf(att_c[b0+jj]-mx) * inv;
    __syncthreads();
    int lim = min(128, deg-jb);
    int j = 0;
    for (; j+3 < lim; j += 4){
      float v0 = bf2f(raw_c[(((size_t)(b0+jb+j  ))<<7)+t]);
      float v1 = bf2f(raw_c[(((size_t)(b0+jb+j+1))<<7)+t]);
      float v2 = bf2f(raw_c[(((size_t)(b0+jb+j+2))<<7)+t]);
      float v3 = bf2f(raw_c[(((size_t)(b0+jb+j+3))<<7)+t]);
      accv = fmaf(w_s[j],v0,accv);
      accv = fmaf(w_s[j+1],v1,accv);
      accv = fmaf(w_s[j+2],v2,accv);
      accv = fmaf(w_s[j+3],v3,accv);
    }
    for (; j<lim; ++j)
      accv = fmaf(w_s[j], bf2f(raw_c[(((size_t)(b0+jb+j))<<7)+t]), accv);
  }
  aggr[((size_t)n<<7)+t] = accv;
}

// ---------------- h = LN(h + aggr@updW + updb); fused next-layer H1 = h@W1
#define FMA4(acc, a, bv) do { \
    acc.x = fmaf(a, bv.x, acc.x); \
    acc.y = fmaf(a, bv.y, acc.y); \
    acc.z = fmaf(a, bv.z, acc.z); \
    acc.w = fmaf(a, bv.w, acc.w); } while(0)

__global__ __launch_bounds__(256,2) void update_kernel(
    const float* __restrict__ aggr, const float* __restrict__ updW,
    const float* __restrict__ updb,
    const float* __restrict__ lng, const float* __restrict__ lnb,
    const float* __restrict__ msgW,
    float* __restrict__ h, ushort_t* __restrict__ h_bf,
    float* __restrict__ H1, float* __restrict__ out, int layer)
{
  __shared__ float As[64*65];
  __shared__ float Bs[64*128];
  const int t = threadIdx.x, blk = blockIdx.x;   // 128 blocks
  const int n0 = blk << 6;
  const int c = t & 15, r = t >> 4;
  float4 acc0[4], acc1[4];
  #pragma unroll
  for (int i=0;i<4;++i){ acc0[i]=make_float4(0,0,0,0); acc1[i]=make_float4(0,0,0,0); }
  const float* wbase = updW + (size_t)layer*DDIM*DDIM;

  for (int ch=0; ch<2; ++ch){
    __syncthreads();
    #pragma unroll
    for (int l=0;l<16;++l){
      int idx=(l<<8)+t, ei=idx>>6, kk=idx&63;
      As[ei*65+kk] = aggr[(size_t)(n0+ei)*DDIM + (ch<<6) + kk];
    }
    #pragma unroll
    for (int l=0;l<32;++l){
      int idx=(l<<8)+t, kk=idx>>7, j=idx&127;
      Bs[(kk<<7)+j] = wbase[((ch<<6)+kk)*DDIM + j];
    }
    __syncthreads();
    #pragma unroll 4
    for (int kk=0;kk<64;++kk){
      const float4 b0 = *(const float4*)&Bs[(kk<<7) + (c<<2)];
      const float4 b1 = *(const float4*)&Bs[(kk<<7) + 64 + (c<<2)];
      #pragma unroll
      for (int i=0;i<4;++i){
        const float a = As[((r<<2)+i)*65 + kk];
        FMA4(acc0[i], a, b0);
        FMA4(acc1[i], a, b1);
      }
    }
  }

  const int col0 = c << 2;
  float ub0[4], ub1[4], g0[4], g1[4], lb0[4], lb1[4];
  #pragma unroll
  for (int q=0;q<4;++q){
    ub0[q] = updb[layer*DDIM + col0+q];  ub1[q] = updb[layer*DDIM + 64+col0+q];
    g0[q]  = lng[col0+q];                g1[q]  = lng[64+col0+q];
    lb0[q] = lnb[col0+q];                lb1[q] = lnb[64+col0+q];
  }

  float4 yv0[4], yv1[4];
  #pragma unroll
  for (int i=0;i<4;++i){
    const int row = n0 + (r<<2) + i;
    float* hrow = h + (size_t)row*DDIM;
    float4 h0 = *(float4*)&hrow[col0];
    float4 h1 = *(float4*)&hrow[64+col0];
    float x0[4], x1[4];
    x0[0] = h0.x + acc0[i].x + ub0[0];
    x0[1] = h0.y + acc0[i].y + ub0[1];
    x0[2] = h0.z + acc0[i].z + ub0[2];
    x0[3] = h0.w + acc0[i].w + ub0[3];
    x1[0] = h1.x + acc1[i].x + ub1[0];
    x1[1] = h1.y + acc1[i].y + ub1[1];
    x1[2] = h1.z + acc1[i].z + ub1[2];
    x1[3] = h1.w + acc1[i].w + ub1[3];
    float s = 0.f, s2 = 0.f;
    #pragma unroll
    for (int q=0;q<4;++q){ s += x0[q]+x1[q]; s2 += x0[q]*x0[q] + x1[q]*x1[q]; }
    #pragma unroll
    for (int off=1; off<16; off<<=1){
      s  += __shfl_xor(s,  off, 16);
      s2 += __shfl_xor(s2, off, 16);
    }
    const float mu = s * (1.0f/128.0f);
    const float var = s2 * (1.0f/128.0f) - mu*mu;
    const float rstd = rsqrtf(var + 1e-5f);
    float4 y0, y1;
    y0.x = (x0[0]-mu)*rstd*g0[0] + lb0[0];
    y0.y = (x0[1]-mu)*rstd*g0[1] + lb0[1];
    y0.z = (x0[2]-mu)*rstd*g0[2] + lb0[2];
    y0.w = (x0[3]-mu)*rstd*g0[3] + lb0[3];
    y1.x = (x1[0]-mu)*rstd*g1[0] + lb1[0];
    y1.y = (x1[1]-mu)*rstd*g1[1] + lb1[1];
    y1.z = (x1[2]-mu)*rstd*g1[2] + lb1[2];
    y1.w = (x1[3]-mu)*rstd*g1[3] + lb1[3];
    *(float4*)&hrow[col0] = y0;
    *(float4*)&hrow[64+col0] = y1;
    ushort4 z0, z1;
    z0.x=f2bf(y0.x); z0.y=f2bf(y0.y); z0.z=f2bf(y0.z); z0.w=f2bf(y0.w);
    z1.x=f2bf(y1.x); z1.y=f2bf(y1.y); z1.z=f2bf(y1.z); z1.w=f2bf(y1.w);
    *(ushort4*)&h_bf[(size_t)row*DDIM + col0] = z0;
    *(ushort4*)&h_bf[(size_t)row*DDIM + 64 + col0] = z1;
    yv0[i] = y0; yv1[i] = y1;
    if ((row & (NNODE-1)) == 0){
      const int bb_ = row >> 11;
      float* op = out + (size_t)(bb_*NL + layer)*DDIM;
      *(float4*)&op[col0] = y0;
      *(float4*)&op[64+col0] = y1;
    }
  }

  // ---- fused next-layer H1 = h_new @ msgW[layer+1][128:256] (skip last layer)
  if (layer < NL-1){
    const float* w1 = msgW + (size_t)(layer+1)*81920 + 16384;
    float4 k0[4], k1[4];
    #pragma unroll
    for (int i=0;i<4;++i){ k0[i]=make_float4(0,0,0,0); k1[i]=make_float4(0,0,0,0); }
    for (int ch=0; ch<2; ++ch){
      __syncthreads();
      #pragma unroll
      for (int i=0;i<4;++i){
        const int ei = (r<<2)+i;
        float4 v = (ch==0) ? yv0[i] : yv1[i];
        As[ei*65 + col0 + 0] = v.x;
        As[ei*65 + col0 + 1] = v.y;
        As[ei*65 + col0 + 2] = v.z;
        As[ei*65 + col0 + 3] = v.w;
      }
      #pragma unroll
      for (int l=0;l<32;++l){
        int idx=(l<<8)+t, kk=idx>>7, j=idx&127;
        Bs[(kk<<7)+j] = w1[((ch<<6)+kk)*DDIM + j];
      }
      __syncthreads();
      #pragma unroll 4
      for (int kk=0;kk<64;++kk){
        const float4 b0 = *(const float4*)&Bs[(kk<<7) + col0];
        const float4 b1 = *(const float4*)&Bs[(kk<<7) + 64 + col0];
        #pragma unroll
        for (int i=0;i<4;++i){
          const float a = As[((r<<2)+i)*65 + kk];
          FMA4(k0[i], a, b0);
          FMA4(k1[i], a, b1);
        }
      }
    }
    #pragma unroll
    for (int i=0;i<4;++i){
      const int row = n0 + (r<<2) + i;
      *(float4*)&H1[(size_t)row*DDIM + col0]      = k0[i];
      *(float4*)&H1[(size_t)row*DDIM + 64 + col0] = k1[i];
    }
  }
}

// ------------------------------------------------------------------ launcher
extern "C" void kernel_launch(void* const* d_in, const int* in_sizes, int n_in,
                              void* d_out, int out_size, void* d_ws, size_t ws_size,
                              hipStream_t stream) {
  const int*   edge_index = (const int*)d_in[0];
  const int*   rels       = (const int*)d_in[1];
  const float* scores     = (const float*)d_in[2];
  const void*  cm_raw     = d_in[3];
  const void*  em_raw     = d_in[4];
  const float* rq    = (const float*)d_in[6];
  const float* conf  = (const float*)d_in[7];
  const float* relt  = (const float*)d_in[8];
  const float* betaW = (const float*)d_in[9];
  const float* betab = (const float*)d_in[10];
  const float* msgW  = (const float*)d_in[11];
  const float* msgb  = (const float*)d_in[12];
  const float* updW  = (const float*)d_in[13];
  const float* updb  = (const float*)d_in[14];
  const float* lng   = (const float*)d_in[15];
  const float* lnb   = (const float*)d_in[16];
  const float* attW  = (const float*)d_in[17];
  const float* attb  = (const float*)d_in[18];
  const float* denW1 = (const float*)d_in[19];
  const float* denb1 = (const float*)d_in[20];
  const float* denW2 = (const float*)d_in[21];
  const float* denb2 = (const float*)d_in[22];
  float* out = (float*)d_out;
  char* ws = (char*)d_ws;

  size_t off = 0;
  float* h        = (float*)(ws + off); off += (size_t)BB*NNODE*DDIM*4;      //  4 MB
  ushort_t* h_bf  = (ushort_t*)(ws + off); off += (size_t)BB*NNODE*DDIM*2;   //  2 MB
  float* aggr     = (float*)(ws + off); off += (size_t)BB*NNODE*DDIM*4;      //  4 MB
  float* H1       = (float*)(ws + off); off += (size_t)BB*NNODE*DDIM*4;      //  4 MB
  ushort_t* raw_c = (ushort_t*)(ws + off); off += (size_t)BB*NE*DDIM*2;      // 32 MB
  float* att_c    = (float*)(ws + off); off += (size_t)BB*NE*4;              // 512 KB
  float* coef_c   = (float*)(ws + off); off += (size_t)BB*NE*4;              // 512 KB
  int* src_c      = (int*)(ws + off); off += (size_t)BB*NE*4;
  int* rel_c      = (int*)(ws + off); off += (size_t)BB*NE*4;
  int* ge_c       = (int*)(ws + off); off += (size_t)BB*NE*4;
  int* deg        = (int*)(ws + off); off += (size_t)BB*NNODE*4;
  int* base       = (int*)(ws + off); off += (size_t)(BB*NNODE+16)*4;
  int* cursor     = (int*)(ws + off); off += (size_t)BB*NNODE*4;
  ushort_t* relt_bf = (ushort_t*)(ws + off); off += (size_t)NRELS*DDIM*2 + 64;
  ushort_t* img_msg = (ushort_t*)(ws + off); off += (size_t)12*8192*2;       // 192 KB
  ushort_t* img_den = (ushort_t*)(ws + off); off += (size_t)2*8192*2;        //  32 KB
  ushort_t* img_tab = (ushort_t*)(ws + off); off += (size_t)8*8192*2;        // 128 KB
  float* relmsg   = (float*)(ws + off); off += (size_t)3*NRELS*DDIM*4;       // 1.5 MB
  float* relhh0   = (float*)(ws + off); off += (size_t)NRELS*DDIM*4;         // 512 KB
  float* denrel   = (float*)(ws + off); off += (size_t)NRELS*DDIM*4;         // 512 KB
  float* denrq    = (float*)(ws + off); off += (size_t)BB*DDIM*4;
  float* initvec  = (float*)(ws + off); off += 3*DDIM*4;
  float* src0vec  = (float*)(ws + off); off += DDIM*4;
  float* att_rel  = (float*)(ws + off); off += 3*NRELS*4 + 32;
  float* att_rq   = (float*)(ws + off); off += 64;
  float* beta_rel = (float*)(ws + off); off += NRELS*4 + 32;
  float* beta_rq  = (float*)(ws + off); off += 64;
  uint8_t* cm_dec = (uint8_t*)(ws + off); off += (size_t)BB*NE;
  uint8_t* em_dec = (uint8_t*)(ws + off); off += (size_t)BB*NE;

  hipMemsetAsync(deg, 0, (size_t)BB*NNODE*4, stream);
  prep_kernel<<<1024, 256, 0, stream>>>(cm_raw, em_raw, edge_index,
                                        cm_dec, em_dec, deg,
                                        relt, relt_bf, rq, attW, betaW,
                                        msgW, denW1, denb1,
                                        src_c, rel_c, ge_c, h, h_bf,
                                        img_msg, img_den, img_tab,
                                        att_rel, att_rq, beta_rel, beta_rq,
                                        denrq, initvec, src0vec);
  csr_scan_kernel<<<1, 256, 0, stream>>>(deg, base, cursor);
  scatter_tab_kernel<<<552, 256, 0, stream>>>(edge_index, rels, em_dec, cursor,
                                              src_c, rel_c, ge_c,
                                              relt_bf, img_msg, img_tab, msgb,
                                              relmsg, relhh0, denrel);
  for (int k = 0; k < NL; ++k){
    if (k == 0){
      msg_mfma_kernel<true><<<2048, 256, 0, stream>>>(base + BB*NNODE, src_c, rel_c, ge_c,
          relt_bf, conf, h_bf, H1, img_msg, img_den, relmsg, relhh0, src0vec, initvec,
          attW, attb, att_rel, att_rq,
          denrel, denrq, denW2, denb2, scores, cm_dec, beta_rel, beta_rq, betab,
          raw_c, att_c, coef_c, k);
    } else {
      msg_mfma_kernel<false><<<1024, 256, 0, stream>>>(base + BB*NNODE, src_c, rel_c, ge_c,
          relt_bf, conf, h_bf, H1, img_msg, img_den, relmsg, relhh0, src0vec, initvec,
          attW, attb, att_rel, att_rq,
          denrel, denrq, denW2, denb2, scores, cm_dec, beta_rel, beta_rq, betab,
          raw_c, att_c, coef_c, k);
    }
    node_agg_kernel<<<BB*NNODE, 128, 0, stream>>>(base, att_c, coef_c, raw_c, aggr);
    update_kernel<<<128, 256, 0, stream>>>(aggr, updW, updb, lng, lnb, msgW,
                                           h, h_bf, H1, out, k);
  }
}